// Round 1
// baseline (1119.285 us; speedup 1.0000x reference)
//
#include <hip/hip_runtime.h>
#include <math.h>

#define S 4096
#define DM 256
#define NH 8
#define HD 32

static constexpr float QK_SCALE = 0.17677669529663687f;  // 1/sqrt(32)

// out[k*O + o] = in[o*K + k]
__global__ __launch_bounds__(256) void k_transpose(const float* __restrict__ in,
                                                   float* __restrict__ out,
                                                   int O, int K) {
  int idx = blockIdx.x * 256 + threadIdx.x;
  if (idx >= O * K) return;
  int o = idx / K, kk = idx - o * K;
  out[kk * O + o] = in[idx];
}

// conv1: x[64][16][16][16] -> h0[s][256], 8 w-positions per block, 256 o per block
__global__ __launch_bounds__(256) void k_conv1(const float* __restrict__ x,
                                               const float* __restrict__ wt,   // [1728][256]
                                               const float* __restrict__ bias,
                                               float* __restrict__ h0) {
  __shared__ float xs[64][9][12];
  int bid = blockIdx.x;                 // 512 blocks
  int dd = bid >> 5, hh = (bid >> 1) & 15, w0 = (bid & 1) << 3;
  int tid = threadIdx.x;
  for (int idx = tid; idx < 64 * 90; idx += 256) {
    int i = idx / 90, r = idx - i * 90;
    int rr = r / 10, wo = r - rr * 10;
    int kd = rr / 3, kh = rr - kd * 3;
    int zd = dd - 1 + kd, zh = hh - 1 + kh, zw = w0 - 1 + wo;
    float v = 0.f;
    if (((unsigned)zd < 16u) && ((unsigned)zh < 16u) && ((unsigned)zw < 16u))
      v = x[((i * 16 + zd) * 16 + zh) * 16 + zw];
    xs[i][rr][wo] = v;
  }
  __syncthreads();
  int o = tid;
  float acc[8];
#pragma unroll
  for (int p = 0; p < 8; ++p) acc[p] = 0.f;
  for (int i = 0; i < 64; ++i) {
#pragma unroll
    for (int rr = 0; rr < 9; ++rr) {
      float xr[10];
#pragma unroll
      for (int j = 0; j < 10; ++j) xr[j] = xs[i][rr][j];
      const float* wp = wt + (i * 27 + rr * 3) * 256 + o;
#pragma unroll
      for (int kw = 0; kw < 3; ++kw) {
        float wv = wp[kw * 256];
#pragma unroll
        for (int p = 0; p < 8; ++p) acc[p] = fmaf(xr[p + kw], wv, acc[p]);
      }
    }
  }
  float bo = bias[o];
  int s0 = (dd * 16 + hh) * 16 + w0;
#pragma unroll
  for (int p = 0; p < 8; ++p) h0[(s0 + p) * 256 + o] = acc[p] + bo;
}

__global__ __launch_bounds__(256) void k_layernorm(const float* __restrict__ in,
                                                   const float* __restrict__ g,
                                                   const float* __restrict__ b,
                                                   float* __restrict__ out) {
  int s = blockIdx.x, tid = threadIdx.x;
  float xv = in[s * 256 + tid];
  float s1 = xv, s2 = xv * xv;
#pragma unroll
  for (int off = 32; off > 0; off >>= 1) {
    s1 += __shfl_down(s1, off);
    s2 += __shfl_down(s2, off);
  }
  __shared__ float w1[4], w2[4], mb[2];
  int wid = tid >> 6;
  if ((tid & 63) == 0) { w1[wid] = s1; w2[wid] = s2; }
  __syncthreads();
  if (tid == 0) {
    float t1 = w1[0] + w1[1] + w1[2] + w1[3];
    float t2 = w2[0] + w2[1] + w2[2] + w2[3];
    float m = t1 * (1.f / 256.f);
    float var = t2 * (1.f / 256.f) - m * m;
    mb[0] = m;
    mb[1] = rsqrtf(var + 1e-5f);
  }
  __syncthreads();
  out[s * 256 + tid] = (xv - mb[0]) * mb[1] * g[tid] + b[tid];
}

// generic 256->256 linear, 8 rows per block.
// mode 0: out[s][o]; mode 1: head-split (scaled); mode 2: relu + residual add
__global__ __launch_bounds__(256) void k_linear8(const float* __restrict__ in,
                                                 const float* __restrict__ wt,  // [i][o]
                                                 const float* __restrict__ bias,
                                                 const float* __restrict__ res,
                                                 float* __restrict__ out,
                                                 int mode, float scale) {
  __shared__ float xs[8][256];
  int s0 = blockIdx.x * 8, tid = threadIdx.x;
#pragma unroll
  for (int p = 0; p < 8; ++p) xs[p][tid] = in[(s0 + p) * 256 + tid];
  __syncthreads();
  float acc[8];
#pragma unroll
  for (int p = 0; p < 8; ++p) acc[p] = 0.f;
  int o = tid;
  for (int i = 0; i < 256; i += 4) {
    float wv0 = wt[(i + 0) * 256 + o];
    float wv1 = wt[(i + 1) * 256 + o];
    float wv2 = wt[(i + 2) * 256 + o];
    float wv3 = wt[(i + 3) * 256 + o];
#pragma unroll
    for (int p = 0; p < 8; ++p) {
      const float4 xv = *reinterpret_cast<const float4*>(&xs[p][i]);
      acc[p] = fmaf(xv.x, wv0, acc[p]);
      acc[p] = fmaf(xv.y, wv1, acc[p]);
      acc[p] = fmaf(xv.z, wv2, acc[p]);
      acc[p] = fmaf(xv.w, wv3, acc[p]);
    }
  }
  float bo = bias[o];
  if (mode == 1) {
    int h = o >> 5, dj = o & 31;
#pragma unroll
    for (int p = 0; p < 8; ++p)
      out[((h * S) + (s0 + p)) * 32 + dj] = (acc[p] + bo) * scale;
  } else if (mode == 2) {
#pragma unroll
    for (int p = 0; p < 8; ++p) {
      float v = acc[p] + bo;
      v = v > 0.f ? v : 0.f;
      out[(s0 + p) * 256 + o] = v + res[(s0 + p) * 256 + o];
    }
  } else {
#pragma unroll
    for (int p = 0; p < 8; ++p) out[(s0 + p) * 256 + o] = acc[p] + bo;
  }
}

// pass 1: l[h][k] = sum_q exp(q[h,q,:] . k[h,k,:])   (scale folded into q)
__global__ __launch_bounds__(256) void k_attn_lsum(const float* __restrict__ q,
                                                   const float* __restrict__ k,
                                                   float* __restrict__ l) {
  int h = blockIdx.x >> 6;
  int c0 = (blockIdx.x & 63) << 6;
  int tid = threadIdx.x;
  int cofs = tid & 63, quarter = tid >> 6;
  int col = c0 + cofs;
  float kreg[32];
  const float* kp = k + (size_t)(h * S + col) * 32;
#pragma unroll
  for (int d = 0; d < 32; ++d) kreg[d] = kp[d];
  __shared__ float qs[64][32];
  __shared__ float part[256];
  float lsum = 0.f;
  for (int q0 = 0; q0 < S; q0 += 64) {
    __syncthreads();
    for (int idx = tid; idx < 64 * 32; idx += 256)
      qs[idx >> 5][idx & 31] = q[(size_t)(h * S + q0 + (idx >> 5)) * 32 + (idx & 31)];
    __syncthreads();
    for (int r = 0; r < 16; ++r) {
      int qq = quarter * 16 + r;
      float d0 = 0.f, d1 = 0.f, d2 = 0.f, d3 = 0.f;
#pragma unroll
      for (int dd = 0; dd < 32; dd += 4) {
        float4 qv = *reinterpret_cast<const float4*>(&qs[qq][dd]);
        d0 = fmaf(qv.x, kreg[dd + 0], d0);
        d1 = fmaf(qv.y, kreg[dd + 1], d1);
        d2 = fmaf(qv.z, kreg[dd + 2], d2);
        d3 = fmaf(qv.w, kreg[dd + 3], d3);
      }
      lsum += __expf((d0 + d1) + (d2 + d3));
    }
  }
  part[tid] = lsum;
  __syncthreads();
  if (tid < 64)
    l[h * S + c0 + tid] =
        part[tid] + part[tid + 64] + part[tid + 128] + part[tid + 192];
}

__global__ __launch_bounds__(256) void k_scale_v(float* __restrict__ v,
                                                 const float* __restrict__ l) {
  int idx = blockIdx.x * 256 + threadIdx.x;  // 8*4096*32 total
  float inv = 1.f / l[idx >> 5];
  v[idx] = v[idx] * inv;
}

// pass 2: xt[s][h*32+d] = sum_k exp(q[s].k[k]) * vn[k][d]  + hn  (residual fused)
__global__ __launch_bounds__(256) void k_attn_out(const float* __restrict__ q,
                                                  const float* __restrict__ k,
                                                  const float* __restrict__ vn,
                                                  const float* __restrict__ hn,
                                                  float* __restrict__ xt) {
  int h = blockIdx.x >> 6;
  int q0 = (blockIdx.x & 63) << 6;
  int tid = threadIdx.x;
  __shared__ float qs[64][32];
  __shared__ float kst[32][66];
  __shared__ float vs[64][32];
  __shared__ float es[64][64];
  for (int idx = tid; idx < 64 * 32; idx += 256)
    qs[idx >> 5][idx & 31] = q[(size_t)(h * S + q0 + (idx >> 5)) * 32 + (idx & 31)];
  float acc[8];
#pragma unroll
  for (int r = 0; r < 8; ++r) acc[r] = 0.f;
  int kcol = tid & 63, qg2 = tid >> 6;  // phase a roles
  int dph = tid & 31, qg = tid >> 5;    // phase b roles
  for (int k0 = 0; k0 < S; k0 += 64) {
    __syncthreads();
    for (int idx = tid; idx < 64 * 32; idx += 256) {
      int kk = idx >> 5, dd = idx & 31;
      float kvv = k[(size_t)(h * S + k0 + kk) * 32 + dd];
      float vvv = vn[(size_t)(h * S + k0 + kk) * 32 + dd];
      kst[dd][kk] = kvv;
      vs[kk][dd] = vvv;
    }
    __syncthreads();
    // phase a: scores -> exp -> es
    float kreg[32];
#pragma unroll
    for (int dd = 0; dd < 32; ++dd) kreg[dd] = kst[dd][kcol];
    for (int r = 0; r < 16; ++r) {
      int qq = qg2 * 16 + r;
      float d0 = 0.f, d1 = 0.f, d2 = 0.f, d3 = 0.f;
#pragma unroll
      for (int dd = 0; dd < 32; dd += 4) {
        float4 qv = *reinterpret_cast<const float4*>(&qs[qq][dd]);
        d0 = fmaf(qv.x, kreg[dd + 0], d0);
        d1 = fmaf(qv.y, kreg[dd + 1], d1);
        d2 = fmaf(qv.z, kreg[dd + 2], d2);
        d3 = fmaf(qv.w, kreg[dd + 3], d3);
      }
      es[qq][kcol] = __expf((d0 + d1) + (d2 + d3));
    }
    __syncthreads();
    // phase b: acc += es @ vs
#pragma unroll 4
    for (int k4 = 0; k4 < 16; ++k4) {
      float v0 = vs[k4 * 4 + 0][dph];
      float v1 = vs[k4 * 4 + 1][dph];
      float v2 = vs[k4 * 4 + 2][dph];
      float v3 = vs[k4 * 4 + 3][dph];
#pragma unroll
      for (int r = 0; r < 8; ++r) {
        float4 ev = *reinterpret_cast<const float4*>(&es[qg * 8 + r][k4 * 4]);
        acc[r] = fmaf(ev.x, v0, acc[r]);
        acc[r] = fmaf(ev.y, v1, acc[r]);
        acc[r] = fmaf(ev.z, v2, acc[r]);
        acc[r] = fmaf(ev.w, v3, acc[r]);
      }
    }
  }
  int ch = h * 32 + dph;
#pragma unroll
  for (int r = 0; r < 8; ++r) {
    int s = q0 + qg * 8 + r;
    xt[s * 256 + ch] = acc[r] + hn[s * 256 + ch];
  }
}

// conv2: h3[s][256] -> out[64][s]
__global__ __launch_bounds__(256) void k_conv2(const float* __restrict__ h3,
                                               const float* __restrict__ wt,  // [6912][64]
                                               const float* __restrict__ bias,
                                               float* __restrict__ out) {
  __shared__ float hs[64][9][12];
  int bid = blockIdx.x;
  int dd = bid >> 5, hh = (bid >> 1) & 15, w0 = (bid & 1) << 3;
  int tid = threadIdx.x;
  int o = tid & 63, pp = tid >> 6;
  float acc[2] = {0.f, 0.f};
  for (int chunk = 0; chunk < 4; ++chunk) {
    __syncthreads();
    for (int idx = tid; idx < 64 * 90; idx += 256) {
      int ch = idx & 63, r = idx >> 6;
      int rr = r / 10, wo = r - rr * 10;
      int kd = rr / 3, kh = rr - kd * 3;
      int zd = dd - 1 + kd, zh = hh - 1 + kh, zw = w0 - 1 + wo;
      float v = 0.f;
      if (((unsigned)zd < 16u) && ((unsigned)zh < 16u) && ((unsigned)zw < 16u))
        v = h3[(size_t)((zd * 16 + zh) * 16 + zw) * 256 + chunk * 64 + ch];
      hs[ch][rr][wo] = v;
    }
    __syncthreads();
    for (int i = 0; i < 64; ++i) {
      int ic = chunk * 64 + i;
#pragma unroll
      for (int rr = 0; rr < 9; ++rr) {
        float xr[4];
#pragma unroll
        for (int j = 0; j < 4; ++j) xr[j] = hs[i][rr][pp * 2 + j];
        const float* wp = wt + (ic * 27 + rr * 3) * 64 + o;
#pragma unroll
        for (int kw = 0; kw < 3; ++kw) {
          float wv = wp[kw * 64];
          acc[0] = fmaf(xr[kw + 0], wv, acc[0]);
          acc[1] = fmaf(xr[kw + 1], wv, acc[1]);
        }
      }
    }
  }
  float bo = bias[o];
  int s0 = (dd * 16 + hh) * 16 + w0 + pp * 2;
  out[o * 4096 + s0 + 0] = acc[0] + bo;
  out[o * 4096 + s0 + 1] = acc[1] + bo;
}

extern "C" void kernel_launch(void* const* d_in, const int* in_sizes, int n_in,
                              void* d_out, int out_size, void* d_ws, size_t ws_size,
                              hipStream_t stream) {
  const float* x   = (const float*)d_in[0];
  const float* c1w = (const float*)d_in[1];
  const float* c1b = (const float*)d_in[2];
  const float* lng = (const float*)d_in[3];
  const float* lnb = (const float*)d_in[4];
  const float* qw  = (const float*)d_in[5];
  const float* qbi = (const float*)d_in[6];
  const float* kw  = (const float*)d_in[7];
  const float* kbi = (const float*)d_in[8];
  const float* vw  = (const float*)d_in[9];
  const float* vbi = (const float*)d_in[10];
  const float* fw  = (const float*)d_in[11];
  const float* fbi = (const float*)d_in[12];
  const float* c2w = (const float*)d_in[13];
  const float* c2b = (const float*)d_in[14];
  float* out = (float*)d_out;
  float* ws = (float*)d_ws;

  const size_t SD = (size_t)S * DM;  // 1048576
  float* h0   = ws;
  float* hn   = h0 + SD;
  float* qbuf = hn + SD;
  float* kbuf = qbuf + SD;
  float* vbuf = kbuf + SD;
  float* lsum = vbuf + SD;            // NH*S = 32768
  float* xt   = lsum + (size_t)NH * S;
  float* h2   = xt + SD;
  float* h3   = h2 + SD;
  float* wt1  = h3 + SD;              // 442368
  float* wtq  = wt1 + 442368;
  float* wtk  = wtq + 65536;
  float* wtv  = wtk + 65536;
  float* wtf  = wtv + 65536;
  float* wt2  = wtf + 65536;          // 442368

  // weight transposes
  k_transpose<<<1728, 256, 0, stream>>>(c1w, wt1, 256, 1728);
  k_transpose<<<256, 256, 0, stream>>>(qw, wtq, 256, 256);
  k_transpose<<<256, 256, 0, stream>>>(kw, wtk, 256, 256);
  k_transpose<<<256, 256, 0, stream>>>(vw, wtv, 256, 256);
  k_transpose<<<256, 256, 0, stream>>>(fw, wtf, 256, 256);
  k_transpose<<<1728, 256, 0, stream>>>(c2w, wt2, 64, 6912);

  k_conv1<<<512, 256, 0, stream>>>(x, wt1, c1b, h0);
  k_layernorm<<<4096, 256, 0, stream>>>(h0, lng, lnb, hn);

  k_linear8<<<512, 256, 0, stream>>>(hn, wtq, qbi, nullptr, qbuf, 1, QK_SCALE);
  k_linear8<<<512, 256, 0, stream>>>(hn, wtk, kbi, nullptr, kbuf, 1, 1.f);
  k_linear8<<<512, 256, 0, stream>>>(hn, wtv, vbi, nullptr, vbuf, 1, 1.f);

  k_attn_lsum<<<512, 256, 0, stream>>>(qbuf, kbuf, lsum);
  k_scale_v<<<4096, 256, 0, stream>>>(vbuf, lsum);
  k_attn_out<<<512, 256, 0, stream>>>(qbuf, kbuf, vbuf, hn, xt);

  k_layernorm<<<4096, 256, 0, stream>>>(xt, lng, lnb, h2);
  k_linear8<<<512, 256, 0, stream>>>(h2, wtf, fbi, xt, h3, 2, 1.f);
  k_conv2<<<512, 256, 0, stream>>>(h3, wt2, c2b, out);
}

// Round 2
// 462.969 us; speedup vs baseline: 2.4176x; 2.4176x over previous
//
#include <hip/hip_runtime.h>
#include <math.h>

#define S 4096
#define DM 256

using short8 = __attribute__((ext_vector_type(8))) short;
using f32x4 = __attribute__((ext_vector_type(4))) float;

static constexpr float QK_SCALE = 0.17677669529663687f;  // 1/sqrt(32)

__device__ __forceinline__ short f2bf(float f) {
  union { float f; unsigned u; } v;
  v.f = f;
  unsigned r = (v.u + 0x7FFFu + ((v.u >> 16) & 1u)) >> 16;
  return (short)r;
}

// out[k*O + o] = in[o*K + k]
__global__ __launch_bounds__(256) void k_transpose(const float* __restrict__ in,
                                                   float* __restrict__ out,
                                                   int O, int K) {
  int idx = blockIdx.x * 256 + threadIdx.x;
  if (idx >= O * K) return;
  int o = idx / K, kk = idx - o * K;
  out[kk * O + o] = in[idx];
}

// conv1: x[64][16][16][16] -> h0[s][256]
__global__ __launch_bounds__(256) void k_conv1(const float* __restrict__ x,
                                               const float* __restrict__ wt,   // [1728][256]
                                               const float* __restrict__ bias,
                                               float* __restrict__ h0) {
  __shared__ float xs[64][9][12];
  int bid = blockIdx.x;                 // 512 blocks
  int dd = bid >> 5, hh = (bid >> 1) & 15, w0 = (bid & 1) << 3;
  int tid = threadIdx.x;
  for (int idx = tid; idx < 64 * 90; idx += 256) {
    int i = idx / 90, r = idx - i * 90;
    int rr = r / 10, wo = r - rr * 10;
    int kd = rr / 3, kh = rr - kd * 3;
    int zd = dd - 1 + kd, zh = hh - 1 + kh, zw = w0 - 1 + wo;
    float v = 0.f;
    if (((unsigned)zd < 16u) && ((unsigned)zh < 16u) && ((unsigned)zw < 16u))
      v = x[((i * 16 + zd) * 16 + zh) * 16 + zw];
    xs[i][rr][wo] = v;
  }
  __syncthreads();
  int o = tid;
  float acc[8];
#pragma unroll
  for (int p = 0; p < 8; ++p) acc[p] = 0.f;
  for (int i = 0; i < 64; ++i) {
#pragma unroll
    for (int rr = 0; rr < 9; ++rr) {
      float xr[10];
#pragma unroll
      for (int j = 0; j < 10; ++j) xr[j] = xs[i][rr][j];
      const float* wp = wt + (i * 27 + rr * 3) * 256 + o;
#pragma unroll
      for (int kw = 0; kw < 3; ++kw) {
        float wv = wp[kw * 256];
#pragma unroll
        for (int p = 0; p < 8; ++p) acc[p] = fmaf(xr[p + kw], wv, acc[p]);
      }
    }
  }
  float bo = bias[o];
  int s0 = (dd * 16 + hh) * 16 + w0;
#pragma unroll
  for (int p = 0; p < 8; ++p) h0[(s0 + p) * 256 + o] = acc[p] + bo;
}

__global__ __launch_bounds__(256) void k_layernorm(const float* __restrict__ in,
                                                   const float* __restrict__ g,
                                                   const float* __restrict__ b,
                                                   float* __restrict__ out) {
  int s = blockIdx.x, tid = threadIdx.x;
  float xv = in[s * 256 + tid];
  float s1 = xv, s2 = xv * xv;
#pragma unroll
  for (int off = 32; off > 0; off >>= 1) {
    s1 += __shfl_down(s1, off);
    s2 += __shfl_down(s2, off);
  }
  __shared__ float w1[4], w2[4], mb[2];
  int wid = tid >> 6;
  if ((tid & 63) == 0) { w1[wid] = s1; w2[wid] = s2; }
  __syncthreads();
  if (tid == 0) {
    float t1 = w1[0] + w1[1] + w1[2] + w1[3];
    float t2 = w2[0] + w2[1] + w2[2] + w2[3];
    float m = t1 * (1.f / 256.f);
    float var = t2 * (1.f / 256.f) - m * m;
    mb[0] = m;
    mb[1] = rsqrtf(var + 1e-5f);
  }
  __syncthreads();
  out[s * 256 + tid] = (xv - mb[0]) * mb[1] * g[tid] + b[tid];
}

// generic 256->256 linear, 8 rows per block.
// mode 1: bf16 head-split scaled (q); mode 3: bf16 head-split (k);
// mode 4: bf16 transposed [256][S] (v); mode 2: relu + residual (fp32)
__global__ __launch_bounds__(256) void k_linear8(const float* __restrict__ in,
                                                 const float* __restrict__ wt,  // [i][o]
                                                 const float* __restrict__ bias,
                                                 const float* __restrict__ res,
                                                 float* __restrict__ outf,
                                                 short* __restrict__ outb,
                                                 int mode, float scale) {
  __shared__ float xs[8][256];
  int s0 = blockIdx.x * 8, tid = threadIdx.x;
#pragma unroll
  for (int p = 0; p < 8; ++p) xs[p][tid] = in[(s0 + p) * 256 + tid];
  __syncthreads();
  float acc[8];
#pragma unroll
  for (int p = 0; p < 8; ++p) acc[p] = 0.f;
  int o = tid;
  for (int i = 0; i < 256; i += 4) {
    float wv0 = wt[(i + 0) * 256 + o];
    float wv1 = wt[(i + 1) * 256 + o];
    float wv2 = wt[(i + 2) * 256 + o];
    float wv3 = wt[(i + 3) * 256 + o];
#pragma unroll
    for (int p = 0; p < 8; ++p) {
      const float4 xv = *reinterpret_cast<const float4*>(&xs[p][i]);
      acc[p] = fmaf(xv.x, wv0, acc[p]);
      acc[p] = fmaf(xv.y, wv1, acc[p]);
      acc[p] = fmaf(xv.z, wv2, acc[p]);
      acc[p] = fmaf(xv.w, wv3, acc[p]);
    }
  }
  float bo = bias[o];
  if (mode == 1 || mode == 3) {
    int h = o >> 5, dj = o & 31;
#pragma unroll
    for (int p = 0; p < 8; ++p)
      outb[((size_t)h * S + s0 + p) * 32 + dj] = f2bf((acc[p] + bo) * scale);
  } else if (mode == 4) {
    short8 vv;
#pragma unroll
    for (int p = 0; p < 8; ++p) vv[p] = f2bf(acc[p] + bo);
    *(short8*)(outb + (size_t)o * S + s0) = vv;
  } else {  // mode 2
#pragma unroll
    for (int p = 0; p < 8; ++p) {
      float v = acc[p] + bo;
      v = v > 0.f ? v : 0.f;
      outf[(s0 + p) * 256 + o] = v + res[(s0 + p) * 256 + o];
    }
  }
}

// pass 1: linv[h][k] = 1 / sum_q exp(q[h,q,:] . k[h,k,:])
// St = K·Q^T via mfma; A-frag = K rows, B-frag = Q rows (both 16B contiguous).
__global__ __launch_bounds__(256) void k_attn1(const short* __restrict__ qb,
                                               const short* __restrict__ kb,
                                               float* __restrict__ linv) {
  int tid = threadIdx.x;
  int h = blockIdx.x >> 6;
  int w = tid >> 6, lane = tid & 63, g = lane >> 4, c = lane & 15;
  int k0 = ((blockIdx.x & 63) << 6) + (w << 4);
  const size_t hb = (size_t)h * S;
  short8 af = *(const short8*)(kb + (hb + k0 + c) * 32 + 8 * g);
  const f32x4 z4 = {0.f, 0.f, 0.f, 0.f};
  float ls[4] = {0.f, 0.f, 0.f, 0.f};
  for (int q0 = 0; q0 < S; q0 += 32) {
    short8 b0 = *(const short8*)(qb + (hb + q0 + c) * 32 + 8 * g);
    short8 b1 = *(const short8*)(qb + (hb + q0 + 16 + c) * 32 + 8 * g);
    f32x4 a0 = __builtin_amdgcn_mfma_f32_16x16x32_bf16(af, b0, z4, 0, 0, 0);
    f32x4 a1 = __builtin_amdgcn_mfma_f32_16x16x32_bf16(af, b1, z4, 0, 0, 0);
#pragma unroll
    for (int i = 0; i < 4; ++i) ls[i] += __expf(a0[i]) + __expf(a1[i]);
  }
#pragma unroll
  for (int i = 0; i < 4; ++i) {
    ls[i] += __shfl_xor(ls[i], 1);
    ls[i] += __shfl_xor(ls[i], 2);
    ls[i] += __shfl_xor(ls[i], 4);
    ls[i] += __shfl_xor(ls[i], 8);
  }
  if (c == 0) {
#pragma unroll
    for (int i = 0; i < 4; ++i) linv[h * S + k0 + 4 * g + i] = 1.0f / ls[i];
  }
}

// pass 2: xt[s][h*32+d] = sum_k exp(S[q,k])*linv[k]*V[k][d]  + hn
// Per wave: 16 q-rows. QK via mfma (acc: St[q=4g+i][k=c]); exp*linv; LDS
// transpose (padded pitch 20) to P A-frag; PV via mfma with Vt B-frags.
__global__ __launch_bounds__(256) void k_attn2(const short* __restrict__ qb,
                                               const short* __restrict__ kb,
                                               const short* __restrict__ vt,
                                               const float* __restrict__ linv,
                                               const float* __restrict__ hn,
                                               float* __restrict__ xt) {
  __shared__ alignas(16) float pts[4][16 * 20];
  int tid = threadIdx.x;
  int h = blockIdx.x >> 6;
  int w = tid >> 6, lane = tid & 63, g = lane >> 4, c = lane & 15;
  int q0 = ((blockIdx.x & 63) << 6) + (w << 4);
  const size_t hb = (size_t)h * S;
  short8 qf = *(const short8*)(qb + (hb + q0 + c) * 32 + 8 * g);
  const f32x4 z4 = {0.f, 0.f, 0.f, 0.f};
  f32x4 acc0 = {0.f, 0.f, 0.f, 0.f}, acc1 = {0.f, 0.f, 0.f, 0.f};
  float* pw = &pts[w][0];
  const float* lp = linv + h * S;
  for (int k0 = 0; k0 < S; k0 += 32) {
    short8 kf0 = *(const short8*)(kb + (hb + k0 + c) * 32 + 8 * g);
    short8 kf1 = *(const short8*)(kb + (hb + k0 + 16 + c) * 32 + 8 * g);
    f32x4 s0 = __builtin_amdgcn_mfma_f32_16x16x32_bf16(qf, kf0, z4, 0, 0, 0);
    f32x4 s1 = __builtin_amdgcn_mfma_f32_16x16x32_bf16(qf, kf1, z4, 0, 0, 0);
    float li0 = lp[k0 + c];
    float li1 = lp[k0 + 16 + c];
#pragma unroll
    for (int i = 0; i < 4; ++i) {
      pw[(4 * g + i) * 20 + c] = __expf(s0[i]) * li0;
      pw[(4 * g + i) * 20 + 16 + c] = __expf(s1[i]) * li1;
    }
    float4 p0 = *(const float4*)(pw + c * 20 + 8 * g);
    float4 p1 = *(const float4*)(pw + c * 20 + 8 * g + 4);
    short8 pa;
    pa[0] = f2bf(p0.x); pa[1] = f2bf(p0.y); pa[2] = f2bf(p0.z); pa[3] = f2bf(p0.w);
    pa[4] = f2bf(p1.x); pa[5] = f2bf(p1.y); pa[6] = f2bf(p1.z); pa[7] = f2bf(p1.w);
    short8 vf0 = *(const short8*)(vt + ((size_t)h * 32 + c) * S + k0 + 8 * g);
    short8 vf1 = *(const short8*)(vt + ((size_t)h * 32 + 16 + c) * S + k0 + 8 * g);
    acc0 = __builtin_amdgcn_mfma_f32_16x16x32_bf16(pa, vf0, acc0, 0, 0, 0);
    acc1 = __builtin_amdgcn_mfma_f32_16x16x32_bf16(pa, vf1, acc1, 0, 0, 0);
  }
#pragma unroll
  for (int i = 0; i < 4; ++i) {
    int row = q0 + 4 * g + i;
    int col = h * 32 + c;
    xt[row * 256 + col] = acc0[i] + hn[row * 256 + col];
    xt[row * 256 + col + 16] = acc1[i] + hn[row * 256 + col + 16];
  }
}

// conv2: h3[s][256] -> out[64][s]
__global__ __launch_bounds__(256) void k_conv2(const float* __restrict__ h3,
                                               const float* __restrict__ wt,  // [6912][64]
                                               const float* __restrict__ bias,
                                               float* __restrict__ out) {
  __shared__ float hs[64][9][12];
  int bid = blockIdx.x;
  int dd = bid >> 5, hh = (bid >> 1) & 15, w0 = (bid & 1) << 3;
  int tid = threadIdx.x;
  int o = tid & 63, pp = tid >> 6;
  float acc[2] = {0.f, 0.f};
  for (int chunk = 0; chunk < 4; ++chunk) {
    __syncthreads();
    for (int idx = tid; idx < 64 * 90; idx += 256) {
      int ch = idx & 63, r = idx >> 6;
      int rr = r / 10, wo = r - rr * 10;
      int kd = rr / 3, kh = rr - kd * 3;
      int zd = dd - 1 + kd, zh = hh - 1 + kh, zw = w0 - 1 + wo;
      float v = 0.f;
      if (((unsigned)zd < 16u) && ((unsigned)zh < 16u) && ((unsigned)zw < 16u))
        v = h3[(size_t)((zd * 16 + zh) * 16 + zw) * 256 + chunk * 64 + ch];
      hs[ch][rr][wo] = v;
    }
    __syncthreads();
    for (int i = 0; i < 64; ++i) {
      int ic = chunk * 64 + i;
#pragma unroll
      for (int rr = 0; rr < 9; ++rr) {
        float xr[4];
#pragma unroll
        for (int j = 0; j < 4; ++j) xr[j] = hs[i][rr][pp * 2 + j];
        const float* wp = wt + (ic * 27 + rr * 3) * 64 + o;
#pragma unroll
        for (int kw = 0; kw < 3; ++kw) {
          float wv = wp[kw * 64];
          acc[0] = fmaf(xr[kw + 0], wv, acc[0]);
          acc[1] = fmaf(xr[kw + 1], wv, acc[1]);
        }
      }
    }
  }
  float bo = bias[o];
  int s0 = (dd * 16 + hh) * 16 + w0 + pp * 2;
  out[o * 4096 + s0 + 0] = acc[0] + bo;
  out[o * 4096 + s0 + 1] = acc[1] + bo;
}

extern "C" void kernel_launch(void* const* d_in, const int* in_sizes, int n_in,
                              void* d_out, int out_size, void* d_ws, size_t ws_size,
                              hipStream_t stream) {
  const float* x   = (const float*)d_in[0];
  const float* c1w = (const float*)d_in[1];
  const float* c1b = (const float*)d_in[2];
  const float* lng = (const float*)d_in[3];
  const float* lnb = (const float*)d_in[4];
  const float* qw  = (const float*)d_in[5];
  const float* qbi = (const float*)d_in[6];
  const float* kw  = (const float*)d_in[7];
  const float* kbi = (const float*)d_in[8];
  const float* vw  = (const float*)d_in[9];
  const float* vbi = (const float*)d_in[10];
  const float* fw  = (const float*)d_in[11];
  const float* fbi = (const float*)d_in[12];
  const float* c2w = (const float*)d_in[13];
  const float* c2b = (const float*)d_in[14];
  float* out = (float*)d_out;
  float* ws = (float*)d_ws;

  const size_t SD = (size_t)S * DM;  // 1048576
  float* h0   = ws;
  float* hn   = h0 + SD;
  float* xt   = hn + SD;
  float* h2   = xt + SD;
  float* h3   = h2 + SD;
  float* wt1  = h3 + SD;              // 442368
  float* wtq  = wt1 + 442368;
  float* wtk  = wtq + 65536;
  float* wtv  = wtk + 65536;
  float* wtf  = wtv + 65536;
  float* wt2  = wtf + 65536;          // 442368
  float* linv = wt2 + 442368;         // 32768
  short* qb   = (short*)(linv + 32768);      // 1048576 shorts
  short* kb   = qb + SD;
  short* vt   = kb + SD;

  k_transpose<<<1728, 256, 0, stream>>>(c1w, wt1, 256, 1728);
  k_transpose<<<256, 256, 0, stream>>>(qw, wtq, 256, 256);
  k_transpose<<<256, 256, 0, stream>>>(kw, wtk, 256, 256);
  k_transpose<<<256, 256, 0, stream>>>(vw, wtv, 256, 256);
  k_transpose<<<256, 256, 0, stream>>>(fw, wtf, 256, 256);
  k_transpose<<<1728, 256, 0, stream>>>(c2w, wt2, 64, 6912);

  k_conv1<<<512, 256, 0, stream>>>(x, wt1, c1b, h0);
  k_layernorm<<<4096, 256, 0, stream>>>(h0, lng, lnb, hn);

  k_linear8<<<512, 256, 0, stream>>>(hn, wtq, qbi, nullptr, nullptr, qb, 1, QK_SCALE);
  k_linear8<<<512, 256, 0, stream>>>(hn, wtk, kbi, nullptr, nullptr, kb, 3, 1.f);
  k_linear8<<<512, 256, 0, stream>>>(hn, wtv, vbi, nullptr, nullptr, vt, 4, 1.f);

  k_attn1<<<512, 256, 0, stream>>>(qb, kb, linv);
  k_attn2<<<512, 256, 0, stream>>>(qb, kb, vt, linv, hn, xt);

  k_layernorm<<<4096, 256, 0, stream>>>(xt, lng, lnb, h2);
  k_linear8<<<512, 256, 0, stream>>>(h2, wtf, fbi, xt, h3, nullptr, 2, 1.f);
  k_conv2<<<512, 256, 0, stream>>>(h3, wt2, c2b, out);
}

// Round 3
// 281.328 us; speedup vs baseline: 3.9786x; 1.6457x over previous
//
#include <hip/hip_runtime.h>
#include <math.h>

#define S 4096
#define DM 256
#define PADV 5832  // 18*18*18

using short8 = __attribute__((ext_vector_type(8))) short;
using short4v = __attribute__((ext_vector_type(4))) short;
using f32x4 = __attribute__((ext_vector_type(4))) float;

static constexpr float QK_SCALE = 0.17677669529663687f;  // 1/sqrt(32)

__device__ __forceinline__ short f2bf(float f) {
  union { float f; unsigned u; } v;
  v.f = f;
  unsigned r = (v.u + 0x7FFFu + ((v.u >> 16) & 1u)) >> 16;
  return (short)r;
}

__device__ __forceinline__ int pad_idx(int s) {
  int d = s >> 8, h = (s >> 4) & 15, w = s & 15;
  return ((d + 1) * 18 + (h + 1)) * 18 + (w + 1);
}

// ---------- prep kernels ----------
__global__ __launch_bounds__(256) void k_fillz(short* __restrict__ p, int n) {
  int i = (blockIdx.x * 256 + threadIdx.x) * 8;
  if (i < n) {
    short8 z = {0, 0, 0, 0, 0, 0, 0, 0};
    *(short8*)(p + i) = z;
  }
}

// x[64][4096] -> xpad[pad(s)][64] bf16
__global__ __launch_bounds__(256) void k_prepx(const float* __restrict__ x,
                                               short* __restrict__ xpad) {
  int idx = blockIdx.x * 256 + threadIdx.x;  // 262144
  int s = idx >> 6, c = idx & 63;
  xpad[pad_idx(s) * 64 + c] = f2bf(x[c * 4096 + s]);
}

// c1w [256][64][27] -> w1t [256][27*64]  ([o][off][ic])
__global__ __launch_bounds__(256) void k_prepw1(const float* __restrict__ w,
                                                short* __restrict__ wt) {
  int idx = blockIdx.x * 256 + threadIdx.x;  // 442368
  int o = idx / 1728, r = idx - o * 1728;
  int off = r >> 6, ic = r & 63;
  wt[idx] = f2bf(w[(o * 64 + ic) * 27 + off]);
}

// c2w [64][256][27] -> w2t [64][27*256]
__global__ __launch_bounds__(256) void k_prepw2(const float* __restrict__ w,
                                                short* __restrict__ wt) {
  int idx = blockIdx.x * 256 + threadIdx.x;  // 442368
  int o = idx / 6912, r = idx - o * 6912;
  int off = r >> 8, ic = r & 255;
  wt[idx] = f2bf(w[(o * 256 + ic) * 27 + off]);
}

__global__ __launch_bounds__(256) void k_castbf(const float* __restrict__ in,
                                                short* __restrict__ out, int n) {
  int i = blockIdx.x * 256 + threadIdx.x;
  if (i < n) out[i] = f2bf(in[i]);
}

// ---------- conv1 via MFMA: xpad[5832][64] x w1t[256][1728] -> h0[4096][256] ----------
__global__ __launch_bounds__(256) void k_conv1m(const short* __restrict__ xpad,
                                                const short* __restrict__ wt,
                                                const float* __restrict__ bias,
                                                float* __restrict__ h0) {
  int bid = blockIdx.x;  // 512
  int mt = bid >> 1, ch = bid & 1;
  int tid = threadIdx.x, w = tid >> 6, lane = tid & 63, g = lane >> 4, c = lane & 15;
  int d = mt >> 4, h = mt & 15;
  int nb = ch * 128 + w * 32;
  f32x4 acc0 = {0.f, 0.f, 0.f, 0.f}, acc1 = {0.f, 0.f, 0.f, 0.f};
  for (int off = 0; off < 27; ++off) {
    int kd = off / 9, r = off - kd * 9, kh = r / 3, kw = r - kh * 3;
    int rowb = ((d + kd) * 18 + h + kh) * 18 + kw + c;
#pragma unroll
    for (int kc = 0; kc < 2; ++kc) {
      short8 af = *(const short8*)(xpad + rowb * 64 + kc * 32 + 8 * g);
      int kidx = off * 64 + kc * 32 + 8 * g;
      short8 b0 = *(const short8*)(wt + (nb + c) * 1728 + kidx);
      short8 b1 = *(const short8*)(wt + (nb + 16 + c) * 1728 + kidx);
      acc0 = __builtin_amdgcn_mfma_f32_16x16x32_bf16(af, b0, acc0, 0, 0, 0);
      acc1 = __builtin_amdgcn_mfma_f32_16x16x32_bf16(af, b1, acc1, 0, 0, 0);
    }
  }
  int o0 = nb + c, o1 = nb + 16 + c;
  float bv0 = bias[o0], bv1 = bias[o1];
#pragma unroll
  for (int i = 0; i < 4; ++i) {
    int s = mt * 16 + 4 * g + i;
    h0[s * 256 + o0] = acc0[i] + bv0;
    h0[s * 256 + o1] = acc1[i] + bv1;
  }
}

// ---------- conv2 via MFMA: hpad[5832][256] x w2t[64][6912] -> out[64][4096] ----------
__global__ __launch_bounds__(256) void k_conv2m(const short* __restrict__ hpad,
                                                const short* __restrict__ wt,
                                                const float* __restrict__ bias,
                                                float* __restrict__ out) {
  __shared__ float red[3][16][65];
  int mt = blockIdx.x;  // 256
  int tid = threadIdx.x, w = tid >> 6, lane = tid & 63, g = lane >> 4, c = lane & 15;
  int d = mt >> 4, h = mt & 15;
  f32x4 acc[4];
#pragma unroll
  for (int n = 0; n < 4; ++n) acc[n] = {0.f, 0.f, 0.f, 0.f};
  int off0 = w * 7;
  int offn = (w == 3) ? 6 : 7;
  for (int oi = 0; oi < offn; ++oi) {
    int off = off0 + oi;
    int kd = off / 9, rr = off - kd * 9, kh = rr / 3, kw = rr - kh * 3;
    int rowb = ((d + kd) * 18 + h + kh) * 18 + kw + c;
    const short* arow = hpad + rowb * 256;
    const short* wrow = wt + off * 256;
#pragma unroll 2
    for (int kc = 0; kc < 8; ++kc) {
      short8 af = *(const short8*)(arow + kc * 32 + 8 * g);
#pragma unroll
      for (int n = 0; n < 4; ++n) {
        short8 bf = *(const short8*)(wrow + (16 * n + c) * 6912 + kc * 32 + 8 * g);
        acc[n] = __builtin_amdgcn_mfma_f32_16x16x32_bf16(af, bf, acc[n], 0, 0, 0);
      }
    }
  }
  if (w > 0) {
#pragma unroll
    for (int n = 0; n < 4; ++n)
#pragma unroll
      for (int i = 0; i < 4; ++i) red[w - 1][n * 4 + i][lane] = acc[n][i];
  }
  __syncthreads();
  if (w == 0) {
#pragma unroll
    for (int n = 0; n < 4; ++n) {
      int o = 16 * n + c;
      float bv = bias[o];
      float4 st;
      st.x = acc[n][0] + red[0][n * 4 + 0][lane] + red[1][n * 4 + 0][lane] + red[2][n * 4 + 0][lane] + bv;
      st.y = acc[n][1] + red[0][n * 4 + 1][lane] + red[1][n * 4 + 1][lane] + red[2][n * 4 + 1][lane] + bv;
      st.z = acc[n][2] + red[0][n * 4 + 2][lane] + red[1][n * 4 + 2][lane] + red[2][n * 4 + 2][lane] + bv;
      st.w = acc[n][3] + red[0][n * 4 + 3][lane] + red[1][n * 4 + 3][lane] + red[2][n * 4 + 3][lane] + bv;
      *(float4*)(out + o * 4096 + mt * 16 + 4 * g) = st;
    }
  }
}

// ---------- layernorm: fp32 out (optional) + bf16 out ----------
__global__ __launch_bounds__(256) void k_layernorm(const float* __restrict__ in,
                                                   const float* __restrict__ g,
                                                   const float* __restrict__ b,
                                                   float* __restrict__ outf,
                                                   short* __restrict__ outb) {
  int s = blockIdx.x, tid = threadIdx.x;
  float xv = in[s * 256 + tid];
  float s1 = xv, s2 = xv * xv;
#pragma unroll
  for (int off = 32; off > 0; off >>= 1) {
    s1 += __shfl_down(s1, off);
    s2 += __shfl_down(s2, off);
  }
  __shared__ float w1[4], w2[4], mb[2];
  int wid = tid >> 6;
  if ((tid & 63) == 0) { w1[wid] = s1; w2[wid] = s2; }
  __syncthreads();
  if (tid == 0) {
    float t1 = w1[0] + w1[1] + w1[2] + w1[3];
    float t2 = w2[0] + w2[1] + w2[2] + w2[3];
    float m = t1 * (1.f / 256.f);
    float var = t2 * (1.f / 256.f) - m * m;
    mb[0] = m;
    mb[1] = rsqrtf(var + 1e-5f);
  }
  __syncthreads();
  float y = (xv - mb[0]) * mb[1] * g[tid] + b[tid];
  if (outf) outf[s * 256 + tid] = y;
  outb[s * 256 + tid] = f2bf(y);
}

// ---------- fused QKV GEMM: hnb[4096][256] x w[256][256] ----------
__global__ __launch_bounds__(256) void k_gemm_qkv(const short* __restrict__ ab,
                                                  const short* __restrict__ wqb,
                                                  const short* __restrict__ wkb,
                                                  const short* __restrict__ wvb,
                                                  const float* __restrict__ qbi,
                                                  const float* __restrict__ kbi,
                                                  const float* __restrict__ vbi,
                                                  short* __restrict__ qb,
                                                  short* __restrict__ kb,
                                                  short* __restrict__ vt) {
  int y = blockIdx.y;
  const short* wb = (y == 0) ? wqb : ((y == 1) ? wkb : wvb);
  int tid = threadIdx.x, w = tid >> 6, lane = tid & 63, g = lane >> 4, c = lane & 15;
  int m0 = blockIdx.x * 32 + (w >> 1) * 16;
  int nb = (w & 1) * 128;
  f32x4 acc[8];
#pragma unroll
  for (int n = 0; n < 8; ++n) acc[n] = {0.f, 0.f, 0.f, 0.f};
#pragma unroll 2
  for (int k0 = 0; k0 < 256; k0 += 32) {
    short8 af = *(const short8*)(ab + (m0 + c) * 256 + k0 + 8 * g);
#pragma unroll
    for (int n = 0; n < 8; ++n) {
      short8 bf = *(const short8*)(wb + (nb + 16 * n + c) * 256 + k0 + 8 * g);
      acc[n] = __builtin_amdgcn_mfma_f32_16x16x32_bf16(af, bf, acc[n], 0, 0, 0);
    }
  }
  if (y < 2) {
    const float* bi = (y == 0) ? qbi : kbi;
    float sc = (y == 0) ? QK_SCALE : 1.f;
    short* ob = (y == 0) ? qb : kb;
#pragma unroll
    for (int n = 0; n < 8; ++n) {
      int o = nb + 16 * n + c;
      float bv = bi[o];
      int hh = o >> 5, dj = o & 31;
#pragma unroll
      for (int i = 0; i < 4; ++i) {
        int s = m0 + 4 * g + i;
        ob[((size_t)hh * S + s) * 32 + dj] = f2bf((acc[n][i] + bv) * sc);
      }
    }
  } else {
#pragma unroll
    for (int n = 0; n < 8; ++n) {
      int o = nb + 16 * n + c;
      float bv = vbi[o];
      short4v st;
#pragma unroll
      for (int i = 0; i < 4; ++i) st[i] = f2bf(acc[n][i] + bv);
      *(short4v*)(vt + (size_t)o * S + m0 + 4 * g) = st;
    }
  }
}

// ---------- FFN GEMM: h2b x wf -> relu+bias, +xt, -> hpad (padded bf16) ----------
__global__ __launch_bounds__(256) void k_gemm_ffn(const short* __restrict__ ab,
                                                  const short* __restrict__ wb,
                                                  const float* __restrict__ bi,
                                                  const float* __restrict__ xt,
                                                  short* __restrict__ hpad) {
  int tid = threadIdx.x, w = tid >> 6, lane = tid & 63, g = lane >> 4, c = lane & 15;
  int m0 = blockIdx.x * 32 + (w >> 1) * 16;
  int nb = (w & 1) * 128;
  f32x4 acc[8];
#pragma unroll
  for (int n = 0; n < 8; ++n) acc[n] = {0.f, 0.f, 0.f, 0.f};
#pragma unroll 2
  for (int k0 = 0; k0 < 256; k0 += 32) {
    short8 af = *(const short8*)(ab + (m0 + c) * 256 + k0 + 8 * g);
#pragma unroll
    for (int n = 0; n < 8; ++n) {
      short8 bf = *(const short8*)(wb + (nb + 16 * n + c) * 256 + k0 + 8 * g);
      acc[n] = __builtin_amdgcn_mfma_f32_16x16x32_bf16(af, bf, acc[n], 0, 0, 0);
    }
  }
  int pr[4];
#pragma unroll
  for (int i = 0; i < 4; ++i) pr[i] = pad_idx(m0 + 4 * g + i) * 256;
#pragma unroll
  for (int n = 0; n < 8; ++n) {
    int o = nb + 16 * n + c;
    float bv = bi[o];
#pragma unroll
    for (int i = 0; i < 4; ++i) {
      int s = m0 + 4 * g + i;
      float v = acc[n][i] + bv;
      v = v > 0.f ? v : 0.f;
      hpad[pr[i] + o] = f2bf(v + xt[s * 256 + o]);
    }
  }
}

// ---------- attention (unchanged from round 1) ----------
__global__ __launch_bounds__(256) void k_attn1(const short* __restrict__ qb,
                                               const short* __restrict__ kb,
                                               float* __restrict__ linv) {
  int tid = threadIdx.x;
  int h = blockIdx.x >> 6;
  int w = tid >> 6, lane = tid & 63, g = lane >> 4, c = lane & 15;
  int k0 = ((blockIdx.x & 63) << 6) + (w << 4);
  const size_t hb = (size_t)h * S;
  short8 af = *(const short8*)(kb + (hb + k0 + c) * 32 + 8 * g);
  const f32x4 z4 = {0.f, 0.f, 0.f, 0.f};
  float ls[4] = {0.f, 0.f, 0.f, 0.f};
  for (int q0 = 0; q0 < S; q0 += 32) {
    short8 b0 = *(const short8*)(qb + (hb + q0 + c) * 32 + 8 * g);
    short8 b1 = *(const short8*)(qb + (hb + q0 + 16 + c) * 32 + 8 * g);
    f32x4 a0 = __builtin_amdgcn_mfma_f32_16x16x32_bf16(af, b0, z4, 0, 0, 0);
    f32x4 a1 = __builtin_amdgcn_mfma_f32_16x16x32_bf16(af, b1, z4, 0, 0, 0);
#pragma unroll
    for (int i = 0; i < 4; ++i) ls[i] += __expf(a0[i]) + __expf(a1[i]);
  }
#pragma unroll
  for (int i = 0; i < 4; ++i) {
    ls[i] += __shfl_xor(ls[i], 1);
    ls[i] += __shfl_xor(ls[i], 2);
    ls[i] += __shfl_xor(ls[i], 4);
    ls[i] += __shfl_xor(ls[i], 8);
  }
  if (c == 0) {
#pragma unroll
    for (int i = 0; i < 4; ++i) linv[h * S + k0 + 4 * g + i] = 1.0f / ls[i];
  }
}

__global__ __launch_bounds__(256) void k_attn2(const short* __restrict__ qb,
                                               const short* __restrict__ kb,
                                               const short* __restrict__ vt,
                                               const float* __restrict__ linv,
                                               const float* __restrict__ hn,
                                               float* __restrict__ xt) {
  __shared__ alignas(16) float pts[4][16 * 20];
  int tid = threadIdx.x;
  int h = blockIdx.x >> 6;
  int w = tid >> 6, lane = tid & 63, g = lane >> 4, c = lane & 15;
  int q0 = ((blockIdx.x & 63) << 6) + (w << 4);
  const size_t hb = (size_t)h * S;
  short8 qf = *(const short8*)(qb + (hb + q0 + c) * 32 + 8 * g);
  const f32x4 z4 = {0.f, 0.f, 0.f, 0.f};
  f32x4 acc0 = {0.f, 0.f, 0.f, 0.f}, acc1 = {0.f, 0.f, 0.f, 0.f};
  float* pw = &pts[w][0];
  const float* lp = linv + h * S;
  for (int k0 = 0; k0 < S; k0 += 32) {
    short8 kf0 = *(const short8*)(kb + (hb + k0 + c) * 32 + 8 * g);
    short8 kf1 = *(const short8*)(kb + (hb + k0 + 16 + c) * 32 + 8 * g);
    f32x4 s0 = __builtin_amdgcn_mfma_f32_16x16x32_bf16(qf, kf0, z4, 0, 0, 0);
    f32x4 s1 = __builtin_amdgcn_mfma_f32_16x16x32_bf16(qf, kf1, z4, 0, 0, 0);
    float li0 = lp[k0 + c];
    float li1 = lp[k0 + 16 + c];
#pragma unroll
    for (int i = 0; i < 4; ++i) {
      pw[(4 * g + i) * 20 + c] = __expf(s0[i]) * li0;
      pw[(4 * g + i) * 20 + 16 + c] = __expf(s1[i]) * li1;
    }
    float4 p0 = *(const float4*)(pw + c * 20 + 8 * g);
    float4 p1 = *(const float4*)(pw + c * 20 + 8 * g + 4);
    short8 pa;
    pa[0] = f2bf(p0.x); pa[1] = f2bf(p0.y); pa[2] = f2bf(p0.z); pa[3] = f2bf(p0.w);
    pa[4] = f2bf(p1.x); pa[5] = f2bf(p1.y); pa[6] = f2bf(p1.z); pa[7] = f2bf(p1.w);
    short8 vf0 = *(const short8*)(vt + ((size_t)h * 32 + c) * S + k0 + 8 * g);
    short8 vf1 = *(const short8*)(vt + ((size_t)h * 32 + 16 + c) * S + k0 + 8 * g);
    acc0 = __builtin_amdgcn_mfma_f32_16x16x32_bf16(pa, vf0, acc0, 0, 0, 0);
    acc1 = __builtin_amdgcn_mfma_f32_16x16x32_bf16(pa, vf1, acc1, 0, 0, 0);
  }
#pragma unroll
  for (int i = 0; i < 4; ++i) {
    int row = q0 + 4 * g + i;
    int col = h * 32 + c;
    xt[row * 256 + col] = acc0[i] + hn[row * 256 + col];
    xt[row * 256 + col + 16] = acc1[i] + hn[row * 256 + col + 16];
  }
}

extern "C" void kernel_launch(void* const* d_in, const int* in_sizes, int n_in,
                              void* d_out, int out_size, void* d_ws, size_t ws_size,
                              hipStream_t stream) {
  const float* x   = (const float*)d_in[0];
  const float* c1w = (const float*)d_in[1];
  const float* c1b = (const float*)d_in[2];
  const float* lng = (const float*)d_in[3];
  const float* lnb = (const float*)d_in[4];
  const float* qw  = (const float*)d_in[5];
  const float* qbi = (const float*)d_in[6];
  const float* kw  = (const float*)d_in[7];
  const float* kbi = (const float*)d_in[8];
  const float* vw  = (const float*)d_in[9];
  const float* vbi = (const float*)d_in[10];
  const float* fw  = (const float*)d_in[11];
  const float* fbi = (const float*)d_in[12];
  const float* c2w = (const float*)d_in[13];
  const float* c2b = (const float*)d_in[14];
  float* out = (float*)d_out;
  float* ws = (float*)d_ws;

  const size_t SD = (size_t)S * DM;  // 1048576
  float* h0   = ws;
  float* hn   = h0 + SD;
  float* xt   = hn + SD;
  float* linv = xt + SD;                  // 32768
  short* hnb  = (short*)(linv + 32768);   // SD shorts each below
  short* h2b  = hnb + SD;
  short* qb   = h2b + SD;
  short* kb   = qb + SD;
  short* vt   = kb + SD;
  short* xpad = vt + SD;                  // 373248
  short* hpad = xpad + 373248;            // 1492992
  short* w1t  = hpad + 1492992;           // 442368
  short* w2t  = w1t + 442368;             // 442368
  short* wqb  = w2t + 442368;             // 65536 each
  short* wkb  = wqb + 65536;
  short* wvb  = wkb + 65536;
  short* wfb  = wvb + 65536;

  k_fillz<<<183, 256, 0, stream>>>(xpad, 373248);
  k_fillz<<<729, 256, 0, stream>>>(hpad, 1492992);
  k_prepx<<<1024, 256, 0, stream>>>(x, xpad);
  k_prepw1<<<1728, 256, 0, stream>>>(c1w, w1t);
  k_prepw2<<<1728, 256, 0, stream>>>(c2w, w2t);
  k_castbf<<<256, 256, 0, stream>>>(qw, wqb, 65536);
  k_castbf<<<256, 256, 0, stream>>>(kw, wkb, 65536);
  k_castbf<<<256, 256, 0, stream>>>(vw, wvb, 65536);
  k_castbf<<<256, 256, 0, stream>>>(fw, wfb, 65536);

  k_conv1m<<<512, 256, 0, stream>>>(xpad, w1t, c1b, h0);
  k_layernorm<<<4096, 256, 0, stream>>>(h0, lng, lnb, hn, hnb);

  k_gemm_qkv<<<dim3(128, 3), 256, 0, stream>>>(hnb, wqb, wkb, wvb, qbi, kbi, vbi,
                                               qb, kb, vt);

  k_attn1<<<512, 256, 0, stream>>>(qb, kb, linv);
  k_attn2<<<512, 256, 0, stream>>>(qb, kb, vt, linv, hn, xt);

  k_layernorm<<<4096, 256, 0, stream>>>(xt, lng, lnb, nullptr, h2b);
  k_gemm_ffn<<<128, 256, 0, stream>>>(h2b, wfb, fbi, xt, hpad);
  k_conv2m<<<256, 256, 0, stream>>>(hpad, w2t, c2b, out);
}

// Round 4
// 272.407 us; speedup vs baseline: 4.1089x; 1.0327x over previous
//
#include <hip/hip_runtime.h>
#include <math.h>

#define S 4096
#define DM 256

using short8 = __attribute__((ext_vector_type(8))) short;
using short4v = __attribute__((ext_vector_type(4))) short;
using f32x4 = __attribute__((ext_vector_type(4))) float;

// 1/sqrt(32) * log2(e): fold into q so scores feed v_exp_f32 (2^x) directly
static constexpr float QK_SCALE_LOG2E = 0.17677669529663687f * 1.4426950408889634f;

__device__ __forceinline__ short f2bf(float f) {
  union { float f; unsigned u; } v;
  v.f = f;
  unsigned r = (v.u + 0x7FFFu + ((v.u >> 16) & 1u)) >> 16;
  return (short)r;
}

__device__ __forceinline__ float bf2f(short s) {
  union { unsigned u; float f; } v;
  v.u = ((unsigned)(unsigned short)s) << 16;
  return v.f;
}

__device__ __forceinline__ unsigned cvt_pk_bf16(float lo, float hi) {
  unsigned r;
  asm("v_cvt_pk_bf16_f32 %0, %1, %2" : "=v"(r) : "v"(lo), "v"(hi));
  return r;
}

__device__ __forceinline__ float fexp2(float x) {
  float r;
  asm("v_exp_f32 %0, %1" : "=v"(r) : "v"(x));
  return r;
}

__device__ __forceinline__ int pad_idx(int s) {
  int d = s >> 8, h = (s >> 4) & 15, w = s & 15;
  return ((d + 1) * 18 + (h + 1)) * 18 + (w + 1);
}

// ---------- prep kernels ----------
__global__ __launch_bounds__(256) void k_fillz(short* __restrict__ p, int n) {
  int i = (blockIdx.x * 256 + threadIdx.x) * 8;
  if (i < n) {
    short8 z = {0, 0, 0, 0, 0, 0, 0, 0};
    *(short8*)(p + i) = z;
  }
}

// x[64][4096] -> xpad[pad(s)][64] bf16
__global__ __launch_bounds__(256) void k_prepx(const float* __restrict__ x,
                                               short* __restrict__ xpad) {
  int idx = blockIdx.x * 256 + threadIdx.x;  // 262144
  int s = idx >> 6, c = idx & 63;
  xpad[pad_idx(s) * 64 + c] = f2bf(x[c * 4096 + s]);
}

// c1w [256][64][27] -> w1t [256][27*64]  ([o][off][ic])
__global__ __launch_bounds__(256) void k_prepw1(const float* __restrict__ w,
                                                short* __restrict__ wt) {
  int idx = blockIdx.x * 256 + threadIdx.x;  // 442368
  int o = idx / 1728, r = idx - o * 1728;
  int off = r >> 6, ic = r & 63;
  wt[idx] = f2bf(w[(o * 64 + ic) * 27 + off]);
}

// c2w [64][256][27] -> w2t [64][27*256]
__global__ __launch_bounds__(256) void k_prepw2(const float* __restrict__ w,
                                                short* __restrict__ wt) {
  int idx = blockIdx.x * 256 + threadIdx.x;  // 442368
  int o = idx / 6912, r = idx - o * 6912;
  int off = r >> 8, ic = r & 255;
  wt[idx] = f2bf(w[(o * 256 + ic) * 27 + off]);
}

// 4 contiguous 256x256 weight casts in one launch
__global__ __launch_bounds__(256) void k_castbf4(const float* __restrict__ a,
                                                 const float* __restrict__ b,
                                                 const float* __restrict__ c,
                                                 const float* __restrict__ d,
                                                 short* __restrict__ out) {
  int idx = blockIdx.x * 256 + threadIdx.x;  // 262144
  int which = idx >> 16, r = idx & 65535;
  const float* src = (which == 0) ? a : (which == 1) ? b : (which == 2) ? c : d;
  out[idx] = f2bf(src[r]);
}

// ---------- conv1 via MFMA: xpad[5832][64] x w1t[256][1728] -> h0[4096][256] ----------
__global__ __launch_bounds__(256) void k_conv1m(const short* __restrict__ xpad,
                                                const short* __restrict__ wt,
                                                const float* __restrict__ bias,
                                                float* __restrict__ h0) {
  int bid = blockIdx.x;  // 512
  int mt = bid >> 1, ch = bid & 1;
  int tid = threadIdx.x, w = tid >> 6, lane = tid & 63, g = lane >> 4, c = lane & 15;
  int d = mt >> 4, h = mt & 15;
  int nb = ch * 128 + w * 32;
  f32x4 acc0 = {0.f, 0.f, 0.f, 0.f}, acc1 = {0.f, 0.f, 0.f, 0.f};
  for (int off = 0; off < 27; ++off) {
    int kd = off / 9, r = off - kd * 9, kh = r / 3, kw = r - kh * 3;
    int rowb = ((d + kd) * 18 + h + kh) * 18 + kw + c;
#pragma unroll
    for (int kc = 0; kc < 2; ++kc) {
      short8 af = *(const short8*)(xpad + rowb * 64 + kc * 32 + 8 * g);
      int kidx = off * 64 + kc * 32 + 8 * g;
      short8 b0 = *(const short8*)(wt + (nb + c) * 1728 + kidx);
      short8 b1 = *(const short8*)(wt + (nb + 16 + c) * 1728 + kidx);
      acc0 = __builtin_amdgcn_mfma_f32_16x16x32_bf16(af, b0, acc0, 0, 0, 0);
      acc1 = __builtin_amdgcn_mfma_f32_16x16x32_bf16(af, b1, acc1, 0, 0, 0);
    }
  }
  int o0 = nb + c, o1 = nb + 16 + c;
  float bv0 = bias[o0], bv1 = bias[o1];
#pragma unroll
  for (int i = 0; i < 4; ++i) {
    int s = mt * 16 + 4 * g + i;
    h0[s * 256 + o0] = acc0[i] + bv0;
    h0[s * 256 + o1] = acc1[i] + bv1;
  }
}

// ---------- layernorm: fp32 + bf16 outputs ----------
__global__ __launch_bounds__(256) void k_layernorm(const float* __restrict__ in,
                                                   const float* __restrict__ g,
                                                   const float* __restrict__ b,
                                                   float* __restrict__ outf,
                                                   short* __restrict__ outb) {
  int s = blockIdx.x, tid = threadIdx.x;
  float xv = in[s * 256 + tid];
  float s1 = xv, s2 = xv * xv;
#pragma unroll
  for (int off = 32; off > 0; off >>= 1) {
    s1 += __shfl_down(s1, off);
    s2 += __shfl_down(s2, off);
  }
  __shared__ float w1[4], w2[4], mb[2];
  int wid = tid >> 6;
  if ((tid & 63) == 0) { w1[wid] = s1; w2[wid] = s2; }
  __syncthreads();
  if (tid == 0) {
    float t1 = w1[0] + w1[1] + w1[2] + w1[3];
    float t2 = w2[0] + w2[1] + w2[2] + w2[3];
    float m = t1 * (1.f / 256.f);
    float var = t2 * (1.f / 256.f) - m * m;
    mb[0] = m;
    mb[1] = rsqrtf(var + 1e-5f);
  }
  __syncthreads();
  float y = (xv - mb[0]) * mb[1] * g[tid] + b[tid];
  outf[s * 256 + tid] = y;
  outb[s * 256 + tid] = f2bf(y);
}

// ---------- fused QKV GEMM: 256 blocks x 3; 16 m-rows/block, 64 n-cols/wave ----------
__global__ __launch_bounds__(256) void k_gemm_qkv(const short* __restrict__ ab,
                                                  const short* __restrict__ wqb,
                                                  const short* __restrict__ wkb,
                                                  const short* __restrict__ wvb,
                                                  const float* __restrict__ qbi,
                                                  const float* __restrict__ kbi,
                                                  const float* __restrict__ vbi,
                                                  short* __restrict__ qb,
                                                  short* __restrict__ kb,
                                                  short* __restrict__ vt) {
  int y = blockIdx.y;
  const short* wb = (y == 0) ? wqb : ((y == 1) ? wkb : wvb);
  int tid = threadIdx.x, w = tid >> 6, lane = tid & 63, g = lane >> 4, c = lane & 15;
  int m0 = blockIdx.x * 16;
  int nb = w * 64;
  f32x4 acc[4];
#pragma unroll
  for (int n = 0; n < 4; ++n) acc[n] = {0.f, 0.f, 0.f, 0.f};
#pragma unroll 2
  for (int k0 = 0; k0 < 256; k0 += 32) {
    short8 af = *(const short8*)(ab + (m0 + c) * 256 + k0 + 8 * g);
#pragma unroll
    for (int n = 0; n < 4; ++n) {
      short8 bf = *(const short8*)(wb + (nb + 16 * n + c) * 256 + k0 + 8 * g);
      acc[n] = __builtin_amdgcn_mfma_f32_16x16x32_bf16(af, bf, acc[n], 0, 0, 0);
    }
  }
  if (y < 2) {
    const float* bi = (y == 0) ? qbi : kbi;
    float sc = (y == 0) ? QK_SCALE_LOG2E : 1.f;
    short* ob = (y == 0) ? qb : kb;
#pragma unroll
    for (int n = 0; n < 4; ++n) {
      int o = nb + 16 * n + c;
      float bv = bi[o];
      int hh = o >> 5, dj = o & 31;
#pragma unroll
      for (int i = 0; i < 4; ++i) {
        int s = m0 + 4 * g + i;
        ob[((size_t)hh * S + s) * 32 + dj] = f2bf((acc[n][i] + bv) * sc);
      }
    }
  } else {
#pragma unroll
    for (int n = 0; n < 4; ++n) {
      int o = nb + 16 * n + c;
      float bv = vbi[o];
      short4v st;
#pragma unroll
      for (int i = 0; i < 4; ++i) st[i] = f2bf(acc[n][i] + bv);
      *(short4v*)(vt + (size_t)o * S + m0 + 4 * g) = st;
    }
  }
}

// ---------- attn pass 1: partial lsum over a q-quarter ----------
__global__ __launch_bounds__(256) void k_attn1(const short* __restrict__ qb,
                                               const short* __restrict__ kb,
                                               float* __restrict__ lpart) {
  int b = blockIdx.x;  // 2048 = h(8) x kt(64) x qs(4)
  int qs = b & 3, kt = (b >> 2) & 63, h = b >> 8;
  int tid = threadIdx.x;
  int w = tid >> 6, lane = tid & 63, g = lane >> 4, c = lane & 15;
  int k0 = kt * 64 + w * 16;
  const size_t hb = (size_t)h * S;
  short8 af = *(const short8*)(kb + (hb + k0 + c) * 32 + 8 * g);
  const f32x4 z4 = {0.f, 0.f, 0.f, 0.f};
  float ls[4] = {0.f, 0.f, 0.f, 0.f};
  int qend = qs * 1024 + 1024;
  for (int q0 = qs * 1024; q0 < qend; q0 += 32) {
    short8 b0 = *(const short8*)(qb + (hb + q0 + c) * 32 + 8 * g);
    short8 b1 = *(const short8*)(qb + (hb + q0 + 16 + c) * 32 + 8 * g);
    f32x4 a0 = __builtin_amdgcn_mfma_f32_16x16x32_bf16(af, b0, z4, 0, 0, 0);
    f32x4 a1 = __builtin_amdgcn_mfma_f32_16x16x32_bf16(af, b1, z4, 0, 0, 0);
#pragma unroll
    for (int i = 0; i < 4; ++i) ls[i] += fexp2(a0[i]) + fexp2(a1[i]);
  }
#pragma unroll
  for (int i = 0; i < 4; ++i) {
    ls[i] += __shfl_xor(ls[i], 1);
    ls[i] += __shfl_xor(ls[i], 2);
    ls[i] += __shfl_xor(ls[i], 4);
    ls[i] += __shfl_xor(ls[i], 8);
  }
  if (c == 0) {
#pragma unroll
    for (int i = 0; i < 4; ++i)
      lpart[qs * 32768 + h * S + k0 + 4 * g + i] = ls[i];
  }
}

// linv = 1 / (sum of 4 q-quarter partials)
__global__ __launch_bounds__(256) void k_linv(const float* __restrict__ lpart,
                                              float* __restrict__ linv) {
  int i = blockIdx.x * 256 + threadIdx.x;  // 32768
  linv[i] = 1.0f / (lpart[i] + lpart[i + 32768] + lpart[i + 65536] + lpart[i + 98304]);
}

// vt[row][k] *= linv[h][k]  (fold 1/l into V)
__global__ __launch_bounds__(256) void k_scalevt(short* __restrict__ vt,
                                                 const float* __restrict__ linv) {
  int idx = blockIdx.x * 256 + threadIdx.x;  // 262144
  int row = idx >> 9;
  int col0 = (idx & 511) << 3;
  int h = row >> 5;
  const float* lp = linv + h * 4096 + col0;
  float4 l0 = *(const float4*)(lp);
  float4 l1 = *(const float4*)(lp + 4);
  short8 v = *(short8*)(vt + (size_t)row * S + col0);
  union { unsigned u[4]; short8 s8; } r;
  r.u[0] = cvt_pk_bf16(bf2f(v[0]) * l0.x, bf2f(v[1]) * l0.y);
  r.u[1] = cvt_pk_bf16(bf2f(v[2]) * l0.z, bf2f(v[3]) * l0.w);
  r.u[2] = cvt_pk_bf16(bf2f(v[4]) * l1.x, bf2f(v[5]) * l1.y);
  r.u[3] = cvt_pk_bf16(bf2f(v[6]) * l1.z, bf2f(v[7]) * l1.w);
  *(short8*)(vt + (size_t)row * S + col0) = r.s8;
}

// ---------- attn pass 2: partial out over a k-quarter ----------
__global__ __launch_bounds__(256) void k_attn2(const short* __restrict__ qb,
                                               const short* __restrict__ kb,
                                               const short* __restrict__ vt,
                                               float* __restrict__ parts) {
  __shared__ alignas(16) float pts[4][16 * 20];
  int b = blockIdx.x;  // 2048 = h(8) x qt(64) x ks(4)
  int ks = b & 3, qt = (b >> 2) & 63, h = b >> 8;
  int tid = threadIdx.x;
  int w = tid >> 6, lane = tid & 63, g = lane >> 4, c = lane & 15;
  int q0 = qt * 64 + w * 16;
  const size_t hb = (size_t)h * S;
  short8 qf = *(const short8*)(qb + (hb + q0 + c) * 32 + 8 * g);
  const f32x4 z4 = {0.f, 0.f, 0.f, 0.f};
  f32x4 acc0 = z4, acc1 = z4;
  float* pw = &pts[w][0];
  const short* vrow0 = vt + ((size_t)h * 32 + c) * S;
  const short* vrow1 = vt + ((size_t)h * 32 + 16 + c) * S;
  int kend = ks * 1024 + 1024;
  for (int k0 = ks * 1024; k0 < kend; k0 += 32) {
    short8 kf0 = *(const short8*)(kb + (hb + k0 + c) * 32 + 8 * g);
    short8 kf1 = *(const short8*)(kb + (hb + k0 + 16 + c) * 32 + 8 * g);
    f32x4 s0 = __builtin_amdgcn_mfma_f32_16x16x32_bf16(qf, kf0, z4, 0, 0, 0);
    f32x4 s1 = __builtin_amdgcn_mfma_f32_16x16x32_bf16(qf, kf1, z4, 0, 0, 0);
#pragma unroll
    for (int i = 0; i < 4; ++i) {
      pw[(4 * g + i) * 20 + c] = fexp2(s0[i]);
      pw[(4 * g + i) * 20 + 16 + c] = fexp2(s1[i]);
    }
    float4 p0 = *(const float4*)(pw + c * 20 + 8 * g);
    float4 p1 = *(const float4*)(pw + c * 20 + 8 * g + 4);
    union { unsigned u[4]; short8 s8; } pu;
    pu.u[0] = cvt_pk_bf16(p0.x, p0.y);
    pu.u[1] = cvt_pk_bf16(p0.z, p0.w);
    pu.u[2] = cvt_pk_bf16(p1.x, p1.y);
    pu.u[3] = cvt_pk_bf16(p1.z, p1.w);
    short8 vf0 = *(const short8*)(vrow0 + k0 + 8 * g);
    short8 vf1 = *(const short8*)(vrow1 + k0 + 8 * g);
    acc0 = __builtin_amdgcn_mfma_f32_16x16x32_bf16(pu.s8, vf0, acc0, 0, 0, 0);
    acc1 = __builtin_amdgcn_mfma_f32_16x16x32_bf16(pu.s8, vf1, acc1, 0, 0, 0);
  }
  float* part = parts + (size_t)ks * (S * DM);
#pragma unroll
  for (int i = 0; i < 4; ++i) {
    int row = q0 + 4 * g + i;
    int col = h * 32 + c;
    part[row * 256 + col] = acc0[i];
    part[row * 256 + col + 16] = acc1[i];
  }
}

// xt = hn + sum(parts); write xt (into parts[0] slot) + layernorm -> h2b
__global__ __launch_bounds__(256) void k_combine_ln(float* __restrict__ parts,
                                                    const float* __restrict__ hn,
                                                    const float* __restrict__ g,
                                                    const float* __restrict__ b,
                                                    short* __restrict__ h2b) {
  int s = blockIdx.x, tid = threadIdx.x;
  int i = s * 256 + tid;
  const int SD4 = S * DM;
  float xv = hn[i] + parts[i] + parts[i + SD4] + parts[i + 2 * SD4] + parts[i + 3 * SD4];
  parts[i] = xv;  // xt lives in parts[0]
  float s1 = xv, s2 = xv * xv;
#pragma unroll
  for (int off = 32; off > 0; off >>= 1) {
    s1 += __shfl_down(s1, off);
    s2 += __shfl_down(s2, off);
  }
  __shared__ float w1[4], w2[4], mb[2];
  int wid = tid >> 6;
  if ((tid & 63) == 0) { w1[wid] = s1; w2[wid] = s2; }
  __syncthreads();
  if (tid == 0) {
    float t1 = w1[0] + w1[1] + w1[2] + w1[3];
    float t2 = w2[0] + w2[1] + w2[2] + w2[3];
    float m = t1 * (1.f / 256.f);
    float var = t2 * (1.f / 256.f) - m * m;
    mb[0] = m;
    mb[1] = rsqrtf(var + 1e-5f);
  }
  __syncthreads();
  h2b[i] = f2bf((xv - mb[0]) * mb[1] * g[tid] + b[tid]);
}

// ---------- FFN GEMM: 256 blocks; relu+bias, +xt, -> hpad (padded bf16) ----------
__global__ __launch_bounds__(256) void k_gemm_ffn(const short* __restrict__ ab,
                                                  const short* __restrict__ wb,
                                                  const float* __restrict__ bi,
                                                  const float* __restrict__ xt,
                                                  short* __restrict__ hpad) {
  int tid = threadIdx.x, w = tid >> 6, lane = tid & 63, g = lane >> 4, c = lane & 15;
  int m0 = blockIdx.x * 16;
  int nb = w * 64;
  f32x4 acc[4];
#pragma unroll
  for (int n = 0; n < 4; ++n) acc[n] = {0.f, 0.f, 0.f, 0.f};
#pragma unroll 2
  for (int k0 = 0; k0 < 256; k0 += 32) {
    short8 af = *(const short8*)(ab + (m0 + c) * 256 + k0 + 8 * g);
#pragma unroll
    for (int n = 0; n < 4; ++n) {
      short8 bf = *(const short8*)(wb + (nb + 16 * n + c) * 256 + k0 + 8 * g);
      acc[n] = __builtin_amdgcn_mfma_f32_16x16x32_bf16(af, bf, acc[n], 0, 0, 0);
    }
  }
  int pr[4];
#pragma unroll
  for (int i = 0; i < 4; ++i) pr[i] = pad_idx(m0 + 4 * g + i) * 256;
#pragma unroll
  for (int n = 0; n < 4; ++n) {
    int o = nb + 16 * n + c;
    float bv = bi[o];
#pragma unroll
    for (int i = 0; i < 4; ++i) {
      int s = m0 + 4 * g + i;
      float v = acc[n][i] + bv;
      v = v > 0.f ? v : 0.f;
      hpad[pr[i] + o] = f2bf(v + xt[s * 256 + o]);
    }
  }
}

// ---------- conv2 via MFMA, K-split x2 across blocks ----------
__global__ __launch_bounds__(256) void k_conv2m(const short* __restrict__ hpad,
                                                const short* __restrict__ wt,
                                                float* __restrict__ p0,
                                                float* __restrict__ p1) {
  __shared__ float red[3][16][65];
  int bid = blockIdx.x;  // 512 = mt(256) x kh(2)
  int mt = bid >> 1, kh = bid & 1;
  int tid = threadIdx.x, w = tid >> 6, lane = tid & 63, g = lane >> 4, c = lane & 15;
  int d = mt >> 4, h = mt & 15;
  f32x4 acc[4];
#pragma unroll
  for (int n = 0; n < 4; ++n) acc[n] = {0.f, 0.f, 0.f, 0.f};
  int end = 14 + kh * 13;
  for (int off = kh * 14 + w; off < end; off += 4) {
    int kd = off / 9, rr = off - kd * 9, kkh = rr / 3, kw = rr - kkh * 3;
    int rowb = ((d + kd) * 18 + h + kkh) * 18 + kw + c;
    const short* arow = hpad + rowb * 256;
    const short* wrow = wt + off * 256;
#pragma unroll 2
    for (int kc = 0; kc < 8; ++kc) {
      short8 af = *(const short8*)(arow + kc * 32 + 8 * g);
#pragma unroll
      for (int n = 0; n < 4; ++n) {
        short8 bf = *(const short8*)(wrow + (16 * n + c) * 6912 + kc * 32 + 8 * g);
        acc[n] = __builtin_amdgcn_mfma_f32_16x16x32_bf16(af, bf, acc[n], 0, 0, 0);
      }
    }
  }
  if (w > 0) {
#pragma unroll
    for (int n = 0; n < 4; ++n)
#pragma unroll
      for (int i = 0; i < 4; ++i) red[w - 1][n * 4 + i][lane] = acc[n][i];
  }
  __syncthreads();
  if (w == 0) {
    float* pbuf = kh ? p1 : p0;
#pragma unroll
    for (int n = 0; n < 4; ++n) {
      int o = 16 * n + c;
      float4 st;
      st.x = acc[n][0] + red[0][n * 4 + 0][lane] + red[1][n * 4 + 0][lane] + red[2][n * 4 + 0][lane];
      st.y = acc[n][1] + red[0][n * 4 + 1][lane] + red[1][n * 4 + 1][lane] + red[2][n * 4 + 1][lane];
      st.z = acc[n][2] + red[0][n * 4 + 2][lane] + red[1][n * 4 + 2][lane] + red[2][n * 4 + 2][lane];
      st.w = acc[n][3] + red[0][n * 4 + 3][lane] + red[1][n * 4 + 3][lane] + red[2][n * 4 + 3][lane];
      *(float4*)(pbuf + o * 4096 + mt * 16 + 4 * g) = st;
    }
  }
}

__global__ __launch_bounds__(256) void k_conv2fin(const float* __restrict__ p0,
                                                  const float* __restrict__ p1,
                                                  const float* __restrict__ bias,
                                                  float* __restrict__ out) {
  int idx4 = (blockIdx.x * 256 + threadIdx.x) * 4;  // 262144 total
  int o = idx4 >> 12;
  float4 a = *(const float4*)(p0 + idx4);
  float4 b = *(const float4*)(p1 + idx4);
  float bv = bias[o];
  float4 r;
  r.x = a.x + b.x + bv;
  r.y = a.y + b.y + bv;
  r.z = a.z + b.z + bv;
  r.w = a.w + b.w + bv;
  *(float4*)(out + idx4) = r;
}

extern "C" void kernel_launch(void* const* d_in, const int* in_sizes, int n_in,
                              void* d_out, int out_size, void* d_ws, size_t ws_size,
                              hipStream_t stream) {
  const float* x   = (const float*)d_in[0];
  const float* c1w = (const float*)d_in[1];
  const float* c1b = (const float*)d_in[2];
  const float* lng = (const float*)d_in[3];
  const float* lnb = (const float*)d_in[4];
  const float* qw  = (const float*)d_in[5];
  const float* qbi = (const float*)d_in[6];
  const float* kw  = (const float*)d_in[7];
  const float* kbi = (const float*)d_in[8];
  const float* vw  = (const float*)d_in[9];
  const float* vbi = (const float*)d_in[10];
  const float* fw  = (const float*)d_in[11];
  const float* fbi = (const float*)d_in[12];
  const float* c2w = (const float*)d_in[13];
  const float* c2b = (const float*)d_in[14];
  float* out = (float*)d_out;
  float* ws = (float*)d_ws;

  const size_t SD = (size_t)S * DM;  // 1048576
  float* hn    = ws;                 // SD
  float* parts = hn + SD;            // 4*SD; part0 = xt, part1 = h0/c2p0, part2 = c2p1
  float* xt    = parts;
  float* h0    = parts + SD;
  float* c2p0  = parts + SD;
  float* c2p1  = parts + 2 * SD;
  float* lpart = parts + 4 * SD;     // 131072
  float* linv  = lpart + 131072;     // 32768
  short* hnb   = (short*)(linv + 32768);
  short* h2b   = hnb + SD;
  short* qb    = h2b + SD;
  short* kb    = qb + SD;
  short* vt    = kb + SD;
  short* xpad  = vt + SD;            // 373248
  short* hpad  = xpad + 373248;      // 1492992
  short* w1t   = hpad + 1492992;     // 442368
  short* w2t   = w1t + 442368;       // 442368
  short* wqb   = w2t + 442368;       // 4 x 65536 contiguous
  short* wkb   = wqb + 65536;
  short* wvb   = wkb + 65536;
  short* wfb   = wvb + 65536;

  k_fillz<<<183, 256, 0, stream>>>(xpad, 373248);
  k_fillz<<<729, 256, 0, stream>>>(hpad, 1492992);
  k_prepx<<<1024, 256, 0, stream>>>(x, xpad);
  k_prepw1<<<1728, 256, 0, stream>>>(c1w, w1t);
  k_prepw2<<<1728, 256, 0, stream>>>(c2w, w2t);
  k_castbf4<<<1024, 256, 0, stream>>>(qw, kw, vw, fw, wqb);

  k_conv1m<<<512, 256, 0, stream>>>(xpad, w1t, c1b, h0);
  k_layernorm<<<4096, 256, 0, stream>>>(h0, lng, lnb, hn, hnb);

  k_gemm_qkv<<<dim3(256, 3), 256, 0, stream>>>(hnb, wqb, wkb, wvb, qbi, kbi, vbi,
                                               qb, kb, vt);

  k_attn1<<<2048, 256, 0, stream>>>(qb, kb, lpart);
  k_linv<<<128, 256, 0, stream>>>(lpart, linv);
  k_scalevt<<<1024, 256, 0, stream>>>(vt, linv);
  k_attn2<<<2048, 256, 0, stream>>>(qb, kb, vt, parts);
  k_combine_ln<<<4096, 256, 0, stream>>>(parts, hn, lng, lnb, h2b);

  k_gemm_ffn<<<256, 256, 0, stream>>>(h2b, wfb, fbi, xt, hpad);
  k_conv2m<<<512, 256, 0, stream>>>(hpad, w2t, c2p0, c2p1);
  k_conv2fin<<<256, 256, 0, stream>>>(c2p0, c2p1, c2b, out);
}

// Round 5
// 221.869 us; speedup vs baseline: 5.0448x; 1.2278x over previous
//
#include <hip/hip_runtime.h>
#include <math.h>

#define S 4096
#define DM 256

using short8 = __attribute__((ext_vector_type(8))) short;
using short4v = __attribute__((ext_vector_type(4))) short;
using f32x4 = __attribute__((ext_vector_type(4))) float;
using f32x16 = __attribute__((ext_vector_type(16))) float;

// 1/sqrt(32) * log2(e): fold into q so scores feed v_exp_f32 (2^x) directly
static constexpr float QK_SCALE_LOG2E = 0.17677669529663687f * 1.4426950408889634f;

__device__ __forceinline__ short f2bf(float f) {
  union { float f; unsigned u; } v;
  v.f = f;
  unsigned r = (v.u + 0x7FFFu + ((v.u >> 16) & 1u)) >> 16;
  return (short)r;
}

__device__ __forceinline__ float bf2f(short s) {
  union { unsigned u; float f; } v;
  v.u = ((unsigned)(unsigned short)s) << 16;
  return v.f;
}

__device__ __forceinline__ unsigned cvt_pk_bf16(float lo, float hi) {
  unsigned r;
  asm("v_cvt_pk_bf16_f32 %0, %1, %2" : "=v"(r) : "v"(lo), "v"(hi));
  return r;
}

__device__ __forceinline__ float fexp2(float x) {
  float r;
  asm("v_exp_f32 %0, %1" : "=v"(r) : "v"(x));
  return r;
}

__device__ __forceinline__ int pad_idx(int s) {
  int d = s >> 8, h = (s >> 4) & 15, w = s & 15;
  return ((d + 1) * 18 + (h + 1)) * 18 + (w + 1);
}

// ---------- prep kernels ----------
__global__ __launch_bounds__(256) void k_fillz(short* __restrict__ p, int n) {
  int i = (blockIdx.x * 256 + threadIdx.x) * 8;
  if (i < n) {
    short8 z = {0, 0, 0, 0, 0, 0, 0, 0};
    *(short8*)(p + i) = z;
  }
}

// x[64][4096] -> xpad[pad(s)][64] bf16
__global__ __launch_bounds__(256) void k_prepx(const float* __restrict__ x,
                                               short* __restrict__ xpad) {
  int idx = blockIdx.x * 256 + threadIdx.x;  // 262144
  int s = idx >> 6, c = idx & 63;
  xpad[pad_idx(s) * 64 + c] = f2bf(x[c * 4096 + s]);
}

// c1w [256][64][27] -> w1t [256][27*64]  ([o][off][ic])
__global__ __launch_bounds__(256) void k_prepw1(const float* __restrict__ w,
                                                short* __restrict__ wt) {
  int idx = blockIdx.x * 256 + threadIdx.x;  // 442368
  int o = idx / 1728, r = idx - o * 1728;
  int off = r >> 6, ic = r & 63;
  wt[idx] = f2bf(w[(o * 64 + ic) * 27 + off]);
}

// c2w [64][256][27] -> w2t [64][27*256]
__global__ __launch_bounds__(256) void k_prepw2(const float* __restrict__ w,
                                                short* __restrict__ wt) {
  int idx = blockIdx.x * 256 + threadIdx.x;  // 442368
  int o = idx / 6912, r = idx - o * 6912;
  int off = r >> 8, ic = r & 255;
  wt[idx] = f2bf(w[(o * 256 + ic) * 27 + off]);
}

// 4 contiguous 256x256 weight casts in one launch
__global__ __launch_bounds__(256) void k_castbf4(const float* __restrict__ a,
                                                 const float* __restrict__ b,
                                                 const float* __restrict__ c,
                                                 const float* __restrict__ d,
                                                 short* __restrict__ out) {
  int idx = blockIdx.x * 256 + threadIdx.x;  // 262144
  int which = idx >> 16, r = idx & 65535;
  const float* src = (which == 0) ? a : (which == 1) ? b : (which == 2) ? c : d;
  out[idx] = f2bf(src[r]);
}

// ---------- conv1 via MFMA: xpad[5832][64] x w1t[256][1728] -> h0[4096][256] ----------
__global__ __launch_bounds__(256) void k_conv1m(const short* __restrict__ xpad,
                                                const short* __restrict__ wt,
                                                const float* __restrict__ bias,
                                                float* __restrict__ h0) {
  int bid = blockIdx.x;  // 512
  int mt = bid >> 1, ch = bid & 1;
  int tid = threadIdx.x, w = tid >> 6, lane = tid & 63, g = lane >> 4, c = lane & 15;
  int d = mt >> 4, h = mt & 15;
  int nb = ch * 128 + w * 32;
  f32x4 acc0 = {0.f, 0.f, 0.f, 0.f}, acc1 = {0.f, 0.f, 0.f, 0.f};
  for (int off = 0; off < 27; ++off) {
    int kd = off / 9, r = off - kd * 9, kh = r / 3, kw = r - kh * 3;
    int rowb = ((d + kd) * 18 + h + kh) * 18 + kw + c;
#pragma unroll
    for (int kc = 0; kc < 2; ++kc) {
      short8 af = *(const short8*)(xpad + rowb * 64 + kc * 32 + 8 * g);
      int kidx = off * 64 + kc * 32 + 8 * g;
      short8 b0 = *(const short8*)(wt + (nb + c) * 1728 + kidx);
      short8 b1 = *(const short8*)(wt + (nb + 16 + c) * 1728 + kidx);
      acc0 = __builtin_amdgcn_mfma_f32_16x16x32_bf16(af, b0, acc0, 0, 0, 0);
      acc1 = __builtin_amdgcn_mfma_f32_16x16x32_bf16(af, b1, acc1, 0, 0, 0);
    }
  }
  int o0 = nb + c, o1 = nb + 16 + c;
  float bv0 = bias[o0], bv1 = bias[o1];
#pragma unroll
  for (int i = 0; i < 4; ++i) {
    int s = mt * 16 + 4 * g + i;
    h0[s * 256 + o0] = acc0[i] + bv0;
    h0[s * 256 + o1] = acc1[i] + bv1;
  }
}

// ---------- layernorm: fp32 + bf16 outputs ----------
__global__ __launch_bounds__(256) void k_layernorm(const float* __restrict__ in,
                                                   const float* __restrict__ g,
                                                   const float* __restrict__ b,
                                                   float* __restrict__ outf,
                                                   short* __restrict__ outb) {
  int s = blockIdx.x, tid = threadIdx.x;
  float xv = in[s * 256 + tid];
  float s1 = xv, s2 = xv * xv;
#pragma unroll
  for (int off = 32; off > 0; off >>= 1) {
    s1 += __shfl_down(s1, off);
    s2 += __shfl_down(s2, off);
  }
  __shared__ float w1[4], w2[4], mb[2];
  int wid = tid >> 6;
  if ((tid & 63) == 0) { w1[wid] = s1; w2[wid] = s2; }
  __syncthreads();
  if (tid == 0) {
    float t1 = w1[0] + w1[1] + w1[2] + w1[3];
    float t2 = w2[0] + w2[1] + w2[2] + w2[3];
    float m = t1 * (1.f / 256.f);
    float var = t2 * (1.f / 256.f) - m * m;
    mb[0] = m;
    mb[1] = rsqrtf(var + 1e-5f);
  }
  __syncthreads();
  float y = (xv - mb[0]) * mb[1] * g[tid] + b[tid];
  outf[s * 256 + tid] = y;
  outb[s * 256 + tid] = f2bf(y);
}

// ---------- fused QKV GEMM: 256 blocks x 3; 16 m-rows/block, 64 n-cols/wave ----------
__global__ __launch_bounds__(256) void k_gemm_qkv(const short* __restrict__ ab,
                                                  const short* __restrict__ wqb,
                                                  const short* __restrict__ wkb,
                                                  const short* __restrict__ wvb,
                                                  const float* __restrict__ qbi,
                                                  const float* __restrict__ kbi,
                                                  const float* __restrict__ vbi,
                                                  short* __restrict__ qb,
                                                  short* __restrict__ kb,
                                                  short* __restrict__ vt) {
  int y = blockIdx.y;
  const short* wb = (y == 0) ? wqb : ((y == 1) ? wkb : wvb);
  int tid = threadIdx.x, w = tid >> 6, lane = tid & 63, g = lane >> 4, c = lane & 15;
  int m0 = blockIdx.x * 16;
  int nb = w * 64;
  f32x4 acc[4];
#pragma unroll
  for (int n = 0; n < 4; ++n) acc[n] = {0.f, 0.f, 0.f, 0.f};
#pragma unroll 2
  for (int k0 = 0; k0 < 256; k0 += 32) {
    short8 af = *(const short8*)(ab + (m0 + c) * 256 + k0 + 8 * g);
#pragma unroll
    for (int n = 0; n < 4; ++n) {
      short8 bf = *(const short8*)(wb + (nb + 16 * n + c) * 256 + k0 + 8 * g);
      acc[n] = __builtin_amdgcn_mfma_f32_16x16x32_bf16(af, bf, acc[n], 0, 0, 0);
    }
  }
  if (y < 2) {
    const float* bi = (y == 0) ? qbi : kbi;
    float sc = (y == 0) ? QK_SCALE_LOG2E : 1.f;
    short* ob = (y == 0) ? qb : kb;
#pragma unroll
    for (int n = 0; n < 4; ++n) {
      int o = nb + 16 * n + c;
      float bv = bi[o];
      int hh = o >> 5, dj = o & 31;
#pragma unroll
      for (int i = 0; i < 4; ++i) {
        int s = m0 + 4 * g + i;
        ob[((size_t)hh * S + s) * 32 + dj] = f2bf((acc[n][i] + bv) * sc);
      }
    }
  } else {
#pragma unroll
    for (int n = 0; n < 4; ++n) {
      int o = nb + 16 * n + c;
      float bv = vbi[o];
      short4v st;
#pragma unroll
      for (int i = 0; i < 4; ++i) st[i] = f2bf(acc[n][i] + bv);
      *(short4v*)(vt + (size_t)o * S + m0 + 4 * g) = st;
    }
  }
}

// ---------- attn pass 1: partial lsum over a q-quarter ----------
__global__ __launch_bounds__(256) void k_attn1(const short* __restrict__ qb,
                                               const short* __restrict__ kb,
                                               float* __restrict__ lpart) {
  int b = blockIdx.x;  // 2048 = h(8) x kt(64) x qs(4)
  int qs = b & 3, kt = (b >> 2) & 63, h = b >> 8;
  int tid = threadIdx.x;
  int w = tid >> 6, lane = tid & 63, g = lane >> 4, c = lane & 15;
  int k0 = kt * 64 + w * 16;
  const size_t hb = (size_t)h * S;
  short8 af = *(const short8*)(kb + (hb + k0 + c) * 32 + 8 * g);
  const f32x4 z4 = {0.f, 0.f, 0.f, 0.f};
  float ls[4] = {0.f, 0.f, 0.f, 0.f};
  int qend = qs * 1024 + 1024;
  for (int q0 = qs * 1024; q0 < qend; q0 += 32) {
    short8 b0 = *(const short8*)(qb + (hb + q0 + c) * 32 + 8 * g);
    short8 b1 = *(const short8*)(qb + (hb + q0 + 16 + c) * 32 + 8 * g);
    f32x4 a0 = __builtin_amdgcn_mfma_f32_16x16x32_bf16(af, b0, z4, 0, 0, 0);
    f32x4 a1 = __builtin_amdgcn_mfma_f32_16x16x32_bf16(af, b1, z4, 0, 0, 0);
#pragma unroll
    for (int i = 0; i < 4; ++i) ls[i] += fexp2(a0[i]) + fexp2(a1[i]);
  }
#pragma unroll
  for (int i = 0; i < 4; ++i) {
    ls[i] += __shfl_xor(ls[i], 1);
    ls[i] += __shfl_xor(ls[i], 2);
    ls[i] += __shfl_xor(ls[i], 4);
    ls[i] += __shfl_xor(ls[i], 8);
  }
  if (c == 0) {
#pragma unroll
    for (int i = 0; i < 4; ++i)
      lpart[qs * 32768 + h * S + k0 + 4 * g + i] = ls[i];
  }
}

// linv = 1 / (sum of 4 q-quarter partials)
__global__ __launch_bounds__(256) void k_linv(const float* __restrict__ lpart,
                                              float* __restrict__ linv) {
  int i = blockIdx.x * 256 + threadIdx.x;  // 32768
  linv[i] = 1.0f / (lpart[i] + lpart[i + 32768] + lpart[i + 65536] + lpart[i + 98304]);
}

// vt[row][k] *= linv[h][k]  (fold 1/l into V)
__global__ __launch_bounds__(256) void k_scalevt(short* __restrict__ vt,
                                                 const float* __restrict__ linv) {
  int idx = blockIdx.x * 256 + threadIdx.x;  // 262144
  int row = idx >> 9;
  int col0 = (idx & 511) << 3;
  int h = row >> 5;
  const float* lp = linv + h * 4096 + col0;
  float4 l0 = *(const float4*)(lp);
  float4 l1 = *(const float4*)(lp + 4);
  short8 v = *(short8*)(vt + (size_t)row * S + col0);
  union { unsigned u[4]; short8 s8; } r;
  r.u[0] = cvt_pk_bf16(bf2f(v[0]) * l0.x, bf2f(v[1]) * l0.y);
  r.u[1] = cvt_pk_bf16(bf2f(v[2]) * l0.z, bf2f(v[3]) * l0.w);
  r.u[2] = cvt_pk_bf16(bf2f(v[4]) * l1.x, bf2f(v[5]) * l1.y);
  r.u[3] = cvt_pk_bf16(bf2f(v[6]) * l1.z, bf2f(v[7]) * l1.w);
  *(short8*)(vt + (size_t)row * S + col0) = r.s8;
}

// ---------- attn pass 2: 32x32 MFMA, swapped QK, zero LDS ----------
// QK: A = K-rows (sigma-permuted), B = Q-rows -> D = P^T[k][q], q = lane&31.
// sigma folds the fragment permutation into K addressing so that after exp +
// cvt_pk the 16 regs ARE the two PV A-frags (k-halves). PV: B = Vt rows (d).
__global__ __launch_bounds__(256) void k_attn2(const short* __restrict__ qb,
                                               const short* __restrict__ kb,
                                               const short* __restrict__ vt,
                                               float* __restrict__ parts) {
  int b = blockIdx.x;  // 1024 = h(8) x qt(32) x ks(4)
  int ks = b & 3, qt = (b >> 2) & 31, h = b >> 7;
  int tid = threadIdx.x;
  int w = tid >> 6, lane = tid & 63;
  int lo = lane & 31, hi = lane >> 5;
  // sigma: swap quartets [4-7]<->[8-11] and [20-23]<->[24-27]
  int sl = lo ^ ((((lo >> 2) ^ (lo >> 3)) & 1) * 12);
  int q0 = qt * 128 + w * 32;
  const size_t hb = (size_t)h * S;
  short8 bq0 = *(const short8*)(qb + (hb + q0 + lo) * 32 + 8 * hi);
  short8 bq1 = *(const short8*)(qb + (hb + q0 + lo) * 32 + 16 + 8 * hi);
  f32x16 acc = {};
  const short* krow = kb + (hb + sl) * 32;
  const short* vrow = vt + ((size_t)(h * 32) + lo) * S;
  int kend = ks * 1024 + 1024;
  const f32x16 z16 = {};
  for (int k0 = ks * 1024; k0 < kend; k0 += 32) {
    short8 ak0 = *(const short8*)(krow + (size_t)k0 * 32 + 8 * hi);
    short8 ak1 = *(const short8*)(krow + (size_t)k0 * 32 + 16 + 8 * hi);
    f32x16 p = __builtin_amdgcn_mfma_f32_32x32x16_bf16(ak0, bq0, z16, 0, 0, 0);
    p = __builtin_amdgcn_mfma_f32_32x32x16_bf16(ak1, bq1, p, 0, 0, 0);
    union { unsigned u[4]; short8 s8; } f0, f1;
#pragma unroll
    for (int m = 0; m < 4; ++m)
      f0.u[m] = cvt_pk_bf16(fexp2(p[2 * m]), fexp2(p[2 * m + 1]));
#pragma unroll
    for (int m = 0; m < 4; ++m)
      f1.u[m] = cvt_pk_bf16(fexp2(p[8 + 2 * m]), fexp2(p[9 + 2 * m]));
    short8 bv0 = *(const short8*)(vrow + k0 + 8 * hi);
    short8 bv1 = *(const short8*)(vrow + k0 + 16 + 8 * hi);
    acc = __builtin_amdgcn_mfma_f32_32x32x16_bf16(f0.s8, bv0, acc, 0, 0, 0);
    acc = __builtin_amdgcn_mfma_f32_32x32x16_bf16(f1.s8, bv1, acc, 0, 0, 0);
  }
  float* part = parts + (size_t)ks * (S * DM);
  int col = h * 32 + lo;
#pragma unroll
  for (int r = 0; r < 16; ++r) {
    int qrel = (r & 3) + 8 * (r >> 2) + 4 * hi;
    part[(q0 + qrel) * 256 + col] = acc[r];
  }
}

// xt = hn + sum(parts); write xt (into parts[0] slot) + layernorm -> h2b
__global__ __launch_bounds__(256) void k_combine_ln(float* __restrict__ parts,
                                                    const float* __restrict__ hn,
                                                    const float* __restrict__ g,
                                                    const float* __restrict__ b,
                                                    short* __restrict__ h2b) {
  int s = blockIdx.x, tid = threadIdx.x;
  int i = s * 256 + tid;
  const int SD4 = S * DM;
  float xv = hn[i] + parts[i] + parts[i + SD4] + parts[i + 2 * SD4] + parts[i + 3 * SD4];
  parts[i] = xv;  // xt lives in parts[0]
  float s1 = xv, s2 = xv * xv;
#pragma unroll
  for (int off = 32; off > 0; off >>= 1) {
    s1 += __shfl_down(s1, off);
    s2 += __shfl_down(s2, off);
  }
  __shared__ float w1[4], w2[4], mb[2];
  int wid = tid >> 6;
  if ((tid & 63) == 0) { w1[wid] = s1; w2[wid] = s2; }
  __syncthreads();
  if (tid == 0) {
    float t1 = w1[0] + w1[1] + w1[2] + w1[3];
    float t2 = w2[0] + w2[1] + w2[2] + w2[3];
    float m = t1 * (1.f / 256.f);
    float var = t2 * (1.f / 256.f) - m * m;
    mb[0] = m;
    mb[1] = rsqrtf(var + 1e-5f);
  }
  __syncthreads();
  h2b[i] = f2bf((xv - mb[0]) * mb[1] * g[tid] + b[tid]);
}

// ---------- FFN GEMM: 256 blocks; relu+bias, +xt, -> hpad (padded bf16) ----------
__global__ __launch_bounds__(256) void k_gemm_ffn(const short* __restrict__ ab,
                                                  const short* __restrict__ wb,
                                                  const float* __restrict__ bi,
                                                  const float* __restrict__ xt,
                                                  short* __restrict__ hpad) {
  int tid = threadIdx.x, w = tid >> 6, lane = tid & 63, g = lane >> 4, c = lane & 15;
  int m0 = blockIdx.x * 16;
  int nb = w * 64;
  f32x4 acc[4];
#pragma unroll
  for (int n = 0; n < 4; ++n) acc[n] = {0.f, 0.f, 0.f, 0.f};
#pragma unroll 2
  for (int k0 = 0; k0 < 256; k0 += 32) {
    short8 af = *(const short8*)(ab + (m0 + c) * 256 + k0 + 8 * g);
#pragma unroll
    for (int n = 0; n < 4; ++n) {
      short8 bf = *(const short8*)(wb + (nb + 16 * n + c) * 256 + k0 + 8 * g);
      acc[n] = __builtin_amdgcn_mfma_f32_16x16x32_bf16(af, bf, acc[n], 0, 0, 0);
    }
  }
  int pr[4];
#pragma unroll
  for (int i = 0; i < 4; ++i) pr[i] = pad_idx(m0 + 4 * g + i) * 256;
#pragma unroll
  for (int n = 0; n < 4; ++n) {
    int o = nb + 16 * n + c;
    float bv = bi[o];
#pragma unroll
    for (int i = 0; i < 4; ++i) {
      int s = m0 + 4 * g + i;
      float v = acc[n][i] + bv;
      v = v > 0.f ? v : 0.f;
      hpad[pr[i] + o] = f2bf(v + xt[s * 256 + o]);
    }
  }
}

// ---------- conv2 via MFMA, K-split x2 across blocks ----------
__global__ __launch_bounds__(256) void k_conv2m(const short* __restrict__ hpad,
                                                const short* __restrict__ wt,
                                                float* __restrict__ p0,
                                                float* __restrict__ p1) {
  __shared__ float red[3][16][65];
  int bid = blockIdx.x;  // 512 = mt(256) x kh(2)
  int mt = bid >> 1, kh = bid & 1;
  int tid = threadIdx.x, w = tid >> 6, lane = tid & 63, g = lane >> 4, c = lane & 15;
  int d = mt >> 4, h = mt & 15;
  f32x4 acc[4];
#pragma unroll
  for (int n = 0; n < 4; ++n) acc[n] = {0.f, 0.f, 0.f, 0.f};
  int end = 14 + kh * 13;
  for (int off = kh * 14 + w; off < end; off += 4) {
    int kd = off / 9, rr = off - kd * 9, kkh = rr / 3, kw = rr - kkh * 3;
    int rowb = ((d + kd) * 18 + h + kkh) * 18 + kw + c;
    const short* arow = hpad + rowb * 256;
    const short* wrow = wt + off * 256;
#pragma unroll 2
    for (int kc = 0; kc < 8; ++kc) {
      short8 af = *(const short8*)(arow + kc * 32 + 8 * g);
#pragma unroll
      for (int n = 0; n < 4; ++n) {
        short8 bf = *(const short8*)(wrow + (16 * n + c) * 6912 + kc * 32 + 8 * g);
        acc[n] = __builtin_amdgcn_mfma_f32_16x16x32_bf16(af, bf, acc[n], 0, 0, 0);
      }
    }
  }
  if (w > 0) {
#pragma unroll
    for (int n = 0; n < 4; ++n)
#pragma unroll
      for (int i = 0; i < 4; ++i) red[w - 1][n * 4 + i][lane] = acc[n][i];
  }
  __syncthreads();
  if (w == 0) {
    float* pbuf = kh ? p1 : p0;
#pragma unroll
    for (int n = 0; n < 4; ++n) {
      int o = 16 * n + c;
      float4 st;
      st.x = acc[n][0] + red[0][n * 4 + 0][lane] + red[1][n * 4 + 0][lane] + red[2][n * 4 + 0][lane];
      st.y = acc[n][1] + red[0][n * 4 + 1][lane] + red[1][n * 4 + 1][lane] + red[2][n * 4 + 1][lane];
      st.z = acc[n][2] + red[0][n * 4 + 2][lane] + red[1][n * 4 + 2][lane] + red[2][n * 4 + 2][lane];
      st.w = acc[n][3] + red[0][n * 4 + 3][lane] + red[1][n * 4 + 3][lane] + red[2][n * 4 + 3][lane];
      *(float4*)(pbuf + o * 4096 + mt * 16 + 4 * g) = st;
    }
  }
}

__global__ __launch_bounds__(256) void k_conv2fin(const float* __restrict__ p0,
                                                  const float* __restrict__ p1,
                                                  const float* __restrict__ bias,
                                                  float* __restrict__ out) {
  int idx4 = (blockIdx.x * 256 + threadIdx.x) * 4;  // 262144 total
  int o = idx4 >> 12;
  float4 a = *(const float4*)(p0 + idx4);
  float4 b = *(const float4*)(p1 + idx4);
  float bv = bias[o];
  float4 r;
  r.x = a.x + b.x + bv;
  r.y = a.y + b.y + bv;
  r.z = a.z + b.z + bv;
  r.w = a.w + b.w + bv;
  *(float4*)(out + idx4) = r;
}

extern "C" void kernel_launch(void* const* d_in, const int* in_sizes, int n_in,
                              void* d_out, int out_size, void* d_ws, size_t ws_size,
                              hipStream_t stream) {
  const float* x   = (const float*)d_in[0];
  const float* c1w = (const float*)d_in[1];
  const float* c1b = (const float*)d_in[2];
  const float* lng = (const float*)d_in[3];
  const float* lnb = (const float*)d_in[4];
  const float* qw  = (const float*)d_in[5];
  const float* qbi = (const float*)d_in[6];
  const float* kw  = (const float*)d_in[7];
  const float* kbi = (const float*)d_in[8];
  const float* vw  = (const float*)d_in[9];
  const float* vbi = (const float*)d_in[10];
  const float* fw  = (const float*)d_in[11];
  const float* fbi = (const float*)d_in[12];
  const float* c2w = (const float*)d_in[13];
  const float* c2b = (const float*)d_in[14];
  float* out = (float*)d_out;
  float* ws = (float*)d_ws;

  const size_t SD = (size_t)S * DM;  // 1048576
  float* hn    = ws;                 // SD
  float* parts = hn + SD;            // 4*SD; part0 = xt, part1 = h0/c2p0, part2 = c2p1
  float* xt    = parts;
  float* h0    = parts + SD;
  float* c2p0  = parts + SD;
  float* c2p1  = parts + 2 * SD;
  float* lpart = parts + 4 * SD;     // 131072
  float* linv  = lpart + 131072;     // 32768
  short* hnb   = (short*)(linv + 32768);
  short* h2b   = hnb + SD;
  short* qb    = h2b + SD;
  short* kb    = qb + SD;
  short* vt    = kb + SD;
  short* xpad  = vt + SD;            // 373248
  short* hpad  = xpad + 373248;      // 1492992
  short* w1t   = hpad + 1492992;     // 442368
  short* w2t   = w1t + 442368;       // 442368
  short* wqb   = w2t + 442368;       // 4 x 65536 contiguous
  short* wkb   = wqb + 65536;
  short* wvb   = wkb + 65536;
  short* wfb   = wvb + 65536;

  k_fillz<<<183, 256, 0, stream>>>(xpad, 373248);
  k_fillz<<<729, 256, 0, stream>>>(hpad, 1492992);
  k_prepx<<<1024, 256, 0, stream>>>(x, xpad);
  k_prepw1<<<1728, 256, 0, stream>>>(c1w, w1t);
  k_prepw2<<<1728, 256, 0, stream>>>(c2w, w2t);
  k_castbf4<<<1024, 256, 0, stream>>>(qw, kw, vw, fw, wqb);

  k_conv1m<<<512, 256, 0, stream>>>(xpad, w1t, c1b, h0);
  k_layernorm<<<4096, 256, 0, stream>>>(h0, lng, lnb, hn, hnb);

  k_gemm_qkv<<<dim3(256, 3), 256, 0, stream>>>(hnb, wqb, wkb, wvb, qbi, kbi, vbi,
                                               qb, kb, vt);

  k_attn1<<<2048, 256, 0, stream>>>(qb, kb, lpart);
  k_linv<<<128, 256, 0, stream>>>(lpart, linv);
  k_scalevt<<<1024, 256, 0, stream>>>(vt, linv);
  k_attn2<<<1024, 256, 0, stream>>>(qb, kb, vt, parts);
  k_combine_ln<<<4096, 256, 0, stream>>>(parts, hn, lng, lnb, h2b);

  k_gemm_ffn<<<256, 256, 0, stream>>>(h2b, wfb, fbi, xt, hpad);
  k_conv2m<<<512, 256, 0, stream>>>(hpad, w2t, c2p0, c2p1);
  k_conv2fin<<<256, 256, 0, stream>>>(c2p0, c2p1, c2b, out);
}

// Round 6
// 218.800 us; speedup vs baseline: 5.1156x; 1.0140x over previous
//
#include <hip/hip_runtime.h>
#include <math.h>

#define S 4096
#define DM 256

using short8 = __attribute__((ext_vector_type(8))) short;
using short4v = __attribute__((ext_vector_type(4))) short;
using f32x4 = __attribute__((ext_vector_type(4))) float;
using f32x16 = __attribute__((ext_vector_type(16))) float;

// 1/sqrt(32) * log2(e): fold into q so scores feed v_exp_f32 (2^x) directly
static constexpr float QK_SCALE_LOG2E = 0.17677669529663687f * 1.4426950408889634f;

__device__ __forceinline__ short f2bf(float f) {
  union { float f; unsigned u; } v;
  v.f = f;
  unsigned r = (v.u + 0x7FFFu + ((v.u >> 16) & 1u)) >> 16;
  return (short)r;
}

__device__ __forceinline__ float bf2f(short s) {
  union { unsigned u; float f; } v;
  v.u = ((unsigned)(unsigned short)s) << 16;
  return v.f;
}

__device__ __forceinline__ unsigned cvt_pk_bf16(float lo, float hi) {
  unsigned r;
  asm("v_cvt_pk_bf16_f32 %0, %1, %2" : "=v"(r) : "v"(lo), "v"(hi));
  return r;
}

__device__ __forceinline__ float fexp2(float x) {
  float r;
  asm("v_exp_f32 %0, %1" : "=v"(r) : "v"(x));
  return r;
}

__device__ __forceinline__ int pad_idx(int s) {
  int d = s >> 8, h = (s >> 4) & 15, w = s & 15;
  return ((d + 1) * 18 + (h + 1)) * 18 + (w + 1);
}

// ---------- fused prep: xpad(full, pad+cast) | w1t | w2t | qkv/ffn casts | hpad halo zero ----------
__global__ __launch_bounds__(256) void k_prep(const float* __restrict__ x,
                                              const float* __restrict__ c1w,
                                              const float* __restrict__ c2w,
                                              const float* __restrict__ qw,
                                              const float* __restrict__ kw,
                                              const float* __restrict__ vw,
                                              const float* __restrict__ fw,
                                              short* __restrict__ xpad,
                                              short* __restrict__ w1t,
                                              short* __restrict__ w2t,
                                              short* __restrict__ wqkvf,
                                              short* __restrict__ hpad) {
  int bid = blockIdx.x, tid = threadIdx.x;
  if (bid < 1458) {                       // xpad: 5832*64
    int idx = bid * 256 + tid;
    int row = idx >> 6, c = idx & 63;
    int pd = row / 324, rem = row - pd * 324;
    int ph = rem / 18, pw = rem - ph * 18;
    short v = 0;
    if ((unsigned)(pd - 1) < 16u && (unsigned)(ph - 1) < 16u && (unsigned)(pw - 1) < 16u) {
      int s = (pd - 1) * 256 + (ph - 1) * 16 + (pw - 1);
      v = f2bf(x[c * 4096 + s]);
    }
    xpad[idx] = v;
  } else if (bid < 3186) {                // w1t [256][27*64]
    int idx = (bid - 1458) * 256 + tid;
    int o = idx / 1728, r = idx - o * 1728;
    int off = r >> 6, ic = r & 63;
    w1t[idx] = f2bf(c1w[(o * 64 + ic) * 27 + off]);
  } else if (bid < 4914) {                // w2t [64][27*256]
    int idx = (bid - 3186) * 256 + tid;
    int o = idx / 6912, r = idx - o * 6912;
    int off = r >> 8, ic = r & 255;
    w2t[idx] = f2bf(c2w[(o * 256 + ic) * 27 + off]);
  } else if (bid < 5938) {                // q,k,v,ffn weight casts (4 x 65536)
    int idx = (bid - 4914) * 256 + tid;
    int which = idx >> 16, r = idx & 65535;
    const float* src = (which == 0) ? qw : (which == 1) ? kw : (which == 2) ? vw : fw;
    wqkvf[idx] = f2bf(src[r]);
  } else {                                // hpad zero (full)
    int i = (bid - 5938) * 2048 + tid * 8;
    short8 z = {0, 0, 0, 0, 0, 0, 0, 0};
    *(short8*)(hpad + i) = z;
  }
}

// ---------- conv1 via MFMA: xpad[5832][64] x w1t[256][1728] -> h0[4096][256] ----------
__global__ __launch_bounds__(256) void k_conv1m(const short* __restrict__ xpad,
                                                const short* __restrict__ wt,
                                                const float* __restrict__ bias,
                                                float* __restrict__ h0) {
  int bid = blockIdx.x;  // 512
  int mt = bid >> 1, ch = bid & 1;
  int tid = threadIdx.x, w = tid >> 6, lane = tid & 63, g = lane >> 4, c = lane & 15;
  int d = mt >> 4, h = mt & 15;
  int nb = ch * 128 + w * 32;
  f32x4 acc0 = {0.f, 0.f, 0.f, 0.f}, acc1 = {0.f, 0.f, 0.f, 0.f};
  for (int off = 0; off < 27; ++off) {
    int kd = off / 9, r = off - kd * 9, kh = r / 3, kw = r - kh * 3;
    int rowb = ((d + kd) * 18 + h + kh) * 18 + kw + c;
#pragma unroll
    for (int kc = 0; kc < 2; ++kc) {
      short8 af = *(const short8*)(xpad + rowb * 64 + kc * 32 + 8 * g);
      int kidx = off * 64 + kc * 32 + 8 * g;
      short8 b0 = *(const short8*)(wt + (nb + c) * 1728 + kidx);
      short8 b1 = *(const short8*)(wt + (nb + 16 + c) * 1728 + kidx);
      acc0 = __builtin_amdgcn_mfma_f32_16x16x32_bf16(af, b0, acc0, 0, 0, 0);
      acc1 = __builtin_amdgcn_mfma_f32_16x16x32_bf16(af, b1, acc1, 0, 0, 0);
    }
  }
  int o0 = nb + c, o1 = nb + 16 + c;
  float bv0 = bias[o0], bv1 = bias[o1];
#pragma unroll
  for (int i = 0; i < 4; ++i) {
    int s = mt * 16 + 4 * g + i;
    h0[s * 256 + o0] = acc0[i] + bv0;
    h0[s * 256 + o1] = acc1[i] + bv1;
  }
}

// ---------- layernorm: fp32 + bf16 outputs ----------
__global__ __launch_bounds__(256) void k_layernorm(const float* __restrict__ in,
                                                   const float* __restrict__ g,
                                                   const float* __restrict__ b,
                                                   float* __restrict__ outf,
                                                   short* __restrict__ outb) {
  int s = blockIdx.x, tid = threadIdx.x;
  float xv = in[s * 256 + tid];
  float s1 = xv, s2 = xv * xv;
#pragma unroll
  for (int off = 32; off > 0; off >>= 1) {
    s1 += __shfl_down(s1, off);
    s2 += __shfl_down(s2, off);
  }
  __shared__ float w1[4], w2[4], mb[2];
  int wid = tid >> 6;
  if ((tid & 63) == 0) { w1[wid] = s1; w2[wid] = s2; }
  __syncthreads();
  if (tid == 0) {
    float t1 = w1[0] + w1[1] + w1[2] + w1[3];
    float t2 = w2[0] + w2[1] + w2[2] + w2[3];
    float m = t1 * (1.f / 256.f);
    float var = t2 * (1.f / 256.f) - m * m;
    mb[0] = m;
    mb[1] = rsqrtf(var + 1e-5f);
  }
  __syncthreads();
  float y = (xv - mb[0]) * mb[1] * g[tid] + b[tid];
  outf[s * 256 + tid] = y;
  outb[s * 256 + tid] = f2bf(y);
}

// ---------- fused QKV GEMM: 256 blocks x 3; 16 m-rows/block, 64 n-cols/wave ----------
__global__ __launch_bounds__(256) void k_gemm_qkv(const short* __restrict__ ab,
                                                  const short* __restrict__ wqb,
                                                  const short* __restrict__ wkb,
                                                  const short* __restrict__ wvb,
                                                  const float* __restrict__ qbi,
                                                  const float* __restrict__ kbi,
                                                  const float* __restrict__ vbi,
                                                  short* __restrict__ qb,
                                                  short* __restrict__ kb,
                                                  short* __restrict__ vt) {
  int y = blockIdx.y;
  const short* wb = (y == 0) ? wqb : ((y == 1) ? wkb : wvb);
  int tid = threadIdx.x, w = tid >> 6, lane = tid & 63, g = lane >> 4, c = lane & 15;
  int m0 = blockIdx.x * 16;
  int nb = w * 64;
  f32x4 acc[4];
#pragma unroll
  for (int n = 0; n < 4; ++n) acc[n] = {0.f, 0.f, 0.f, 0.f};
#pragma unroll 2
  for (int k0 = 0; k0 < 256; k0 += 32) {
    short8 af = *(const short8*)(ab + (m0 + c) * 256 + k0 + 8 * g);
#pragma unroll
    for (int n = 0; n < 4; ++n) {
      short8 bf = *(const short8*)(wb + (nb + 16 * n + c) * 256 + k0 + 8 * g);
      acc[n] = __builtin_amdgcn_mfma_f32_16x16x32_bf16(af, bf, acc[n], 0, 0, 0);
    }
  }
  if (y < 2) {
    const float* bi = (y == 0) ? qbi : kbi;
    float sc = (y == 0) ? QK_SCALE_LOG2E : 1.f;
    short* ob = (y == 0) ? qb : kb;
#pragma unroll
    for (int n = 0; n < 4; ++n) {
      int o = nb + 16 * n + c;
      float bv = bi[o];
      int hh = o >> 5, dj = o & 31;
#pragma unroll
      for (int i = 0; i < 4; ++i) {
        int s = m0 + 4 * g + i;
        ob[((size_t)hh * S + s) * 32 + dj] = f2bf((acc[n][i] + bv) * sc);
      }
    }
  } else {
#pragma unroll
    for (int n = 0; n < 4; ++n) {
      int o = nb + 16 * n + c;
      float bv = vbi[o];
      short4v st;
#pragma unroll
      for (int i = 0; i < 4; ++i) st[i] = f2bf(acc[n][i] + bv);
      *(short4v*)(vt + (size_t)o * S + m0 + 4 * g) = st;
    }
  }
}

// ---------- attn pass 1: partial lsum over a q-quarter ----------
__global__ __launch_bounds__(256) void k_attn1(const short* __restrict__ qb,
                                               const short* __restrict__ kb,
                                               float* __restrict__ lpart) {
  int b = blockIdx.x;  // 2048 = h(8) x kt(64) x qs(4)
  int qs = b & 3, kt = (b >> 2) & 63, h = b >> 8;
  int tid = threadIdx.x;
  int w = tid >> 6, lane = tid & 63, g = lane >> 4, c = lane & 15;
  int k0 = kt * 64 + w * 16;
  const size_t hb = (size_t)h * S;
  short8 af = *(const short8*)(kb + (hb + k0 + c) * 32 + 8 * g);
  const f32x4 z4 = {0.f, 0.f, 0.f, 0.f};
  float ls[4] = {0.f, 0.f, 0.f, 0.f};
  int qend = qs * 1024 + 1024;
  for (int q0 = qs * 1024; q0 < qend; q0 += 32) {
    short8 b0 = *(const short8*)(qb + (hb + q0 + c) * 32 + 8 * g);
    short8 b1 = *(const short8*)(qb + (hb + q0 + 16 + c) * 32 + 8 * g);
    f32x4 a0 = __builtin_amdgcn_mfma_f32_16x16x32_bf16(af, b0, z4, 0, 0, 0);
    f32x4 a1 = __builtin_amdgcn_mfma_f32_16x16x32_bf16(af, b1, z4, 0, 0, 0);
#pragma unroll
    for (int i = 0; i < 4; ++i) ls[i] += fexp2(a0[i]) + fexp2(a1[i]);
  }
#pragma unroll
  for (int i = 0; i < 4; ++i) {
    ls[i] += __shfl_xor(ls[i], 1);
    ls[i] += __shfl_xor(ls[i], 2);
    ls[i] += __shfl_xor(ls[i], 4);
    ls[i] += __shfl_xor(ls[i], 8);
  }
  if (c == 0) {
#pragma unroll
    for (int i = 0; i < 4; ++i)
      lpart[qs * 32768 + h * S + k0 + 4 * g + i] = ls[i];
  }
}

// linv = 1 / (sum of 4 q-quarter partials)
__global__ __launch_bounds__(256) void k_linv(const float* __restrict__ lpart,
                                              float* __restrict__ linv) {
  int i = blockIdx.x * 256 + threadIdx.x;  // 32768
  linv[i] = 1.0f / (lpart[i] + lpart[i + 32768] + lpart[i + 65536] + lpart[i + 98304]);
}

// vt[row][k] *= linv[h][k]  (fold 1/l into V)
__global__ __launch_bounds__(256) void k_scalevt(short* __restrict__ vt,
                                                 const float* __restrict__ linv) {
  int idx = blockIdx.x * 256 + threadIdx.x;  // 262144
  int row = idx >> 9;
  int col0 = (idx & 511) << 3;
  int h = row >> 5;
  const float* lp = linv + h * 4096 + col0;
  float4 l0 = *(const float4*)(lp);
  float4 l1 = *(const float4*)(lp + 4);
  short8 v = *(short8*)(vt + (size_t)row * S + col0);
  union { unsigned u[4]; short8 s8; } r;
  r.u[0] = cvt_pk_bf16(bf2f(v[0]) * l0.x, bf2f(v[1]) * l0.y);
  r.u[1] = cvt_pk_bf16(bf2f(v[2]) * l0.z, bf2f(v[3]) * l0.w);
  r.u[2] = cvt_pk_bf16(bf2f(v[4]) * l1.x, bf2f(v[5]) * l1.y);
  r.u[3] = cvt_pk_bf16(bf2f(v[6]) * l1.z, bf2f(v[7]) * l1.w);
  *(short8*)(vt + (size_t)row * S + col0) = r.s8;
}

// ---------- attn pass 2: 32x32 MFMA, swapped QK, zero LDS, k-split x8 ----------
// QK: A = K-rows (sigma-permuted), B = Q-rows -> D = P^T[k][q], q = lane&31.
// sigma folds the fragment permutation into K addressing so that after exp +
// cvt_pk the 16 regs ARE the two PV A-frags (k-halves). PV: B = Vt rows (d).
// Partial outputs in bf16 (magnitudes O(0.1); noise ~1e-3 << threshold).
__global__ __launch_bounds__(256) void k_attn2(const short* __restrict__ qb,
                                               const short* __restrict__ kb,
                                               const short* __restrict__ vt,
                                               short* __restrict__ parts) {
  int b = blockIdx.x;  // 2048 = h(8) x qt(32) x ks(8)
  int ks = b & 7, qt = (b >> 3) & 31, h = b >> 8;
  int tid = threadIdx.x;
  int w = tid >> 6, lane = tid & 63;
  int lo = lane & 31, hi = lane >> 5;
  // sigma: swap quartets [4-7]<->[8-11] and [20-23]<->[24-27]
  int sl = lo ^ ((((lo >> 2) ^ (lo >> 3)) & 1) * 12);
  int q0 = qt * 128 + w * 32;
  const size_t hb = (size_t)h * S;
  short8 bq0 = *(const short8*)(qb + (hb + q0 + lo) * 32 + 8 * hi);
  short8 bq1 = *(const short8*)(qb + (hb + q0 + lo) * 32 + 16 + 8 * hi);
  f32x16 acc = {};
  const short* krow = kb + (hb + sl) * 32;
  const short* vrow = vt + ((size_t)(h * 32) + lo) * S;
  int kend = ks * 512 + 512;
  const f32x16 z16 = {};
  for (int k0 = ks * 512; k0 < kend; k0 += 32) {
    short8 ak0 = *(const short8*)(krow + (size_t)k0 * 32 + 8 * hi);
    short8 ak1 = *(const short8*)(krow + (size_t)k0 * 32 + 16 + 8 * hi);
    f32x16 p = __builtin_amdgcn_mfma_f32_32x32x16_bf16(ak0, bq0, z16, 0, 0, 0);
    p = __builtin_amdgcn_mfma_f32_32x32x16_bf16(ak1, bq1, p, 0, 0, 0);
    union { unsigned u[4]; short8 s8; } f0, f1;
#pragma unroll
    for (int m = 0; m < 4; ++m)
      f0.u[m] = cvt_pk_bf16(fexp2(p[2 * m]), fexp2(p[2 * m + 1]));
#pragma unroll
    for (int m = 0; m < 4; ++m)
      f1.u[m] = cvt_pk_bf16(fexp2(p[8 + 2 * m]), fexp2(p[9 + 2 * m]));
    short8 bv0 = *(const short8*)(vrow + k0 + 8 * hi);
    short8 bv1 = *(const short8*)(vrow + k0 + 16 + 8 * hi);
    acc = __builtin_amdgcn_mfma_f32_32x32x16_bf16(f0.s8, bv0, acc, 0, 0, 0);
    acc = __builtin_amdgcn_mfma_f32_32x32x16_bf16(f1.s8, bv1, acc, 0, 0, 0);
  }
  short* part = parts + (size_t)ks * (S * DM);
  int col = h * 32 + lo;
#pragma unroll
  for (int r = 0; r < 16; ++r) {
    int qrel = (r & 3) + 8 * (r >> 2) + 4 * hi;
    part[(q0 + qrel) * 256 + col] = f2bf(acc[r]);
  }
}

// xt = hn + sum(8 bf16 parts); write xt + layernorm -> h2b
__global__ __launch_bounds__(256) void k_combine_ln(const short* __restrict__ parts,
                                                    const float* __restrict__ hn,
                                                    const float* __restrict__ g,
                                                    const float* __restrict__ b,
                                                    float* __restrict__ xt,
                                                    short* __restrict__ h2b) {
  int s = blockIdx.x, tid = threadIdx.x;
  int i = s * 256 + tid;
  const int SD4 = S * DM;
  float xv = hn[i];
#pragma unroll
  for (int j = 0; j < 8; ++j) xv += bf2f(parts[i + j * SD4]);
  xt[i] = xv;
  float s1 = xv, s2 = xv * xv;
#pragma unroll
  for (int off = 32; off > 0; off >>= 1) {
    s1 += __shfl_down(s1, off);
    s2 += __shfl_down(s2, off);
  }
  __shared__ float w1[4], w2[4], mb[2];
  int wid = tid >> 6;
  if ((tid & 63) == 0) { w1[wid] = s1; w2[wid] = s2; }
  __syncthreads();
  if (tid == 0) {
    float t1 = w1[0] + w1[1] + w1[2] + w1[3];
    float t2 = w2[0] + w2[1] + w2[2] + w2[3];
    float m = t1 * (1.f / 256.f);
    float var = t2 * (1.f / 256.f) - m * m;
    mb[0] = m;
    mb[1] = rsqrtf(var + 1e-5f);
  }
  __syncthreads();
  h2b[i] = f2bf((xv - mb[0]) * mb[1] * g[tid] + b[tid]);
}

// ---------- FFN GEMM: 256 blocks; relu+bias, +xt, -> hpad (padded bf16) ----------
__global__ __launch_bounds__(256) void k_gemm_ffn(const short* __restrict__ ab,
                                                  const short* __restrict__ wb,
                                                  const float* __restrict__ bi,
                                                  const float* __restrict__ xt,
                                                  short* __restrict__ hpad) {
  int tid = threadIdx.x, w = tid >> 6, lane = tid & 63, g = lane >> 4, c = lane & 15;
  int m0 = blockIdx.x * 16;
  int nb = w * 64;
  f32x4 acc[4];
#pragma unroll
  for (int n = 0; n < 4; ++n) acc[n] = {0.f, 0.f, 0.f, 0.f};
#pragma unroll 2
  for (int k0 = 0; k0 < 256; k0 += 32) {
    short8 af = *(const short8*)(ab + (m0 + c) * 256 + k0 + 8 * g);
#pragma unroll
    for (int n = 0; n < 4; ++n) {
      short8 bf = *(const short8*)(wb + (nb + 16 * n + c) * 256 + k0 + 8 * g);
      acc[n] = __builtin_amdgcn_mfma_f32_16x16x32_bf16(af, bf, acc[n], 0, 0, 0);
    }
  }
  int pr[4];
#pragma unroll
  for (int i = 0; i < 4; ++i) pr[i] = pad_idx(m0 + 4 * g + i) * 256;
#pragma unroll
  for (int n = 0; n < 4; ++n) {
    int o = nb + 16 * n + c;
    float bv = bi[o];
#pragma unroll
    for (int i = 0; i < 4; ++i) {
      int s = m0 + 4 * g + i;
      float v = acc[n][i] + bv;
      v = v > 0.f ? v : 0.f;
      hpad[pr[i] + o] = f2bf(v + xt[s * 256 + o]);
    }
  }
}

// ---------- conv2 via MFMA, K-split x4 across blocks ----------
__global__ __launch_bounds__(256) void k_conv2m(const short* __restrict__ hpad,
                                                const short* __restrict__ wt,
                                                float* __restrict__ pbase) {
  __shared__ float red[3][16][65];
  int bid = blockIdx.x;  // 1024 = mt(256) x kh(4)
  int mt = bid >> 2, kh = bid & 3;
  int tid = threadIdx.x, w = tid >> 6, lane = tid & 63, g = lane >> 4, c = lane & 15;
  int d = mt >> 4, h = mt & 15;
  f32x4 acc[4];
#pragma unroll
  for (int n = 0; n < 4; ++n) acc[n] = {0.f, 0.f, 0.f, 0.f};
  int off0 = kh * 7;
  int offn = (kh == 3) ? 6 : 7;
  for (int off = off0 + w; off < off0 + offn; off += 4) {
    int kd = off / 9, rr = off - kd * 9, kkh = rr / 3, kw = rr - kkh * 3;
    int rowb = ((d + kd) * 18 + h + kkh) * 18 + kw + c;
    const short* arow = hpad + rowb * 256;
    const short* wrow = wt + off * 256;
#pragma unroll 2
    for (int kc = 0; kc < 8; ++kc) {
      short8 af = *(const short8*)(arow + kc * 32 + 8 * g);
#pragma unroll
      for (int n = 0; n < 4; ++n) {
        short8 bf = *(const short8*)(wrow + (16 * n + c) * 6912 + kc * 32 + 8 * g);
        acc[n] = __builtin_amdgcn_mfma_f32_16x16x32_bf16(af, bf, acc[n], 0, 0, 0);
      }
    }
  }
  if (w > 0) {
#pragma unroll
    for (int n = 0; n < 4; ++n)
#pragma unroll
      for (int i = 0; i < 4; ++i) red[w - 1][n * 4 + i][lane] = acc[n][i];
  }
  __syncthreads();
  if (w == 0) {
    float* pbuf = pbase + (size_t)kh * (S * DM / 4);  // 64*4096 each
#pragma unroll
    for (int n = 0; n < 4; ++n) {
      int o = 16 * n + c;
      float4 st;
      st.x = acc[n][0] + red[0][n * 4 + 0][lane] + red[1][n * 4 + 0][lane] + red[2][n * 4 + 0][lane];
      st.y = acc[n][1] + red[0][n * 4 + 1][lane] + red[1][n * 4 + 1][lane] + red[2][n * 4 + 1][lane];
      st.z = acc[n][2] + red[0][n * 4 + 2][lane] + red[1][n * 4 + 2][lane] + red[2][n * 4 + 2][lane];
      st.w = acc[n][3] + red[0][n * 4 + 3][lane] + red[1][n * 4 + 3][lane] + red[2][n * 4 + 3][lane];
      *(float4*)(pbuf + o * 4096 + mt * 16 + 4 * g) = st;
    }
  }
}

__global__ __launch_bounds__(256) void k_conv2fin(const float* __restrict__ pbase,
                                                  const float* __restrict__ bias,
                                                  float* __restrict__ out) {
  int idx4 = (blockIdx.x * 256 + threadIdx.x) * 4;  // 262144 total
  int o = idx4 >> 12;
  const int PS = S * DM / 4;  // 262144
  float4 a = *(const float4*)(pbase + idx4);
  float4 b = *(const float4*)(pbase + PS + idx4);
  float4 c = *(const float4*)(pbase + 2 * PS + idx4);
  float4 d = *(const float4*)(pbase + 3 * PS + idx4);
  float bv = bias[o];
  float4 r;
  r.x = a.x + b.x + c.x + d.x + bv;
  r.y = a.y + b.y + c.y + d.y + bv;
  r.z = a.z + b.z + c.z + d.z + bv;
  r.w = a.w + b.w + c.w + d.w + bv;
  *(float4*)(out + idx4) = r;
}

extern "C" void kernel_launch(void* const* d_in, const int* in_sizes, int n_in,
                              void* d_out, int out_size, void* d_ws, size_t ws_size,
                              hipStream_t stream) {
  const float* x   = (const float*)d_in[0];
  const float* c1w = (const float*)d_in[1];
  const float* c1b = (const float*)d_in[2];
  const float* lng = (const float*)d_in[3];
  const float* lnb = (const float*)d_in[4];
  const float* qw  = (const float*)d_in[5];
  const float* qbi = (const float*)d_in[6];
  const float* kw  = (const float*)d_in[7];
  const float* kbi = (const float*)d_in[8];
  const float* vw  = (const float*)d_in[9];
  const float* vbi = (const float*)d_in[10];
  const float* fw  = (const float*)d_in[11];
  const float* fbi = (const float*)d_in[12];
  const float* c2w = (const float*)d_in[13];
  const float* c2b = (const float*)d_in[14];
  float* out = (float*)d_out;
  float* ws = (float*)d_ws;

  const size_t SD = (size_t)S * DM;  // 1048576
  float* hn     = ws;                  // SD floats
  float* xt     = hn + SD;             // SD floats
  short* partsb = (short*)(xt + SD);   // 8*SD shorts (16MB)
  float* h0     = (float*)partsb;      // alias: dead before attn2 writes parts
  float* c2p    = (float*)partsb;      // alias: conv2 partials (4*SD floats), after combine
  float* lpart  = (float*)(partsb + 8 * SD);  // 131072 floats
  float* linv   = lpart + 131072;      // 32768
  short* hnb    = (short*)(linv + 32768);
  short* h2b    = hnb + SD;
  short* qb     = h2b + SD;
  short* kb     = qb + SD;
  short* vt     = kb + SD;
  short* xpad   = vt + SD;             // 373248
  short* hpad   = xpad + 373248;       // 1492992
  short* w1t    = hpad + 1492992;      // 442368
  short* w2t    = w1t + 442368;        // 442368
  short* wqb    = w2t + 442368;        // 4 x 65536 contiguous
  short* wkb    = wqb + 65536;
  short* wvb    = wkb + 65536;
  short* wfb    = wvb + 65536;

  k_prep<<<6667, 256, 0, stream>>>(x, c1w, c2w, qw, kw, vw, fw,
                                   xpad, w1t, w2t, wqb, hpad);

  k_conv1m<<<512, 256, 0, stream>>>(xpad, w1t, c1b, h0);
  k_layernorm<<<4096, 256, 0, stream>>>(h0, lng, lnb, hn, hnb);

  k_gemm_qkv<<<dim3(256, 3), 256, 0, stream>>>(hnb, wqb, wkb, wvb, qbi, kbi, vbi,
                                               qb, kb, vt);

  k_attn1<<<2048, 256, 0, stream>>>(qb, kb, lpart);
  k_linv<<<128, 256, 0, stream>>>(lpart, linv);
  k_scalevt<<<1024, 256, 0, stream>>>(vt, linv);
  k_attn2<<<2048, 256, 0, stream>>>(qb, kb, vt, partsb);
  k_combine_ln<<<4096, 256, 0, stream>>>(partsb, hn, lng, lnb, xt, h2b);

  k_gemm_ffn<<<256, 256, 0, stream>>>(h2b, wfb, fbi, xt, hpad);
  k_conv2m<<<1024, 256, 0, stream>>>(hpad, w2t, c2p);
  k_conv2fin<<<256, 256, 0, stream>>>(c2p, c2b, out);
}

// Round 8
// 190.377 us; speedup vs baseline: 5.8793x; 1.1493x over previous
//
#include <hip/hip_runtime.h>
#include <math.h>

#define S 4096
#define DM 256

using short8 = __attribute__((ext_vector_type(8))) short;
using short4v = __attribute__((ext_vector_type(4))) short;
using f32x4 = __attribute__((ext_vector_type(4))) float;
using f32x16 = __attribute__((ext_vector_type(16))) float;

// 1/sqrt(32) * log2(e): fold into q so scores feed v_exp_f32 (2^x) directly
static constexpr float QK_SCALE_LOG2E = 0.17677669529663687f * 1.4426950408889634f;

__device__ __forceinline__ short f2bf(float f) {
  union { float f; unsigned u; } v;
  v.f = f;
  unsigned r = (v.u + 0x7FFFu + ((v.u >> 16) & 1u)) >> 16;
  return (short)r;
}

__device__ __forceinline__ float bf2f(short s) {
  union { unsigned u; float f; } v;
  v.u = ((unsigned)(unsigned short)s) << 16;
  return v.f;
}

__device__ __forceinline__ unsigned cvt_pk_bf16(float lo, float hi) {
  unsigned r;
  asm("v_cvt_pk_bf16_f32 %0, %1, %2" : "=v"(r) : "v"(lo), "v"(hi));
  return r;
}

__device__ __forceinline__ float fexp2(float x) {
  float r;
  asm("v_exp_f32 %0, %1" : "=v"(r) : "v"(x));
  return r;
}

__device__ __forceinline__ int pad_idx(int s) {
  int d = s >> 8, h = (s >> 4) & 15, w = s & 15;
  return ((d + 1) * 18 + (h + 1)) * 18 + (w + 1);
}

// ---------- fused prep: xpad(full, pad+cast) | w1t | w2t | qkv/ffn casts | hpad halo zero ----------
__global__ __launch_bounds__(256) void k_prep(const float* __restrict__ x,
                                              const float* __restrict__ c1w,
                                              const float* __restrict__ c2w,
                                              const float* __restrict__ qw,
                                              const float* __restrict__ kw,
                                              const float* __restrict__ vw,
                                              const float* __restrict__ fw,
                                              short* __restrict__ xpad,
                                              short* __restrict__ w1t,
                                              short* __restrict__ w2t,
                                              short* __restrict__ wqkvf,
                                              short* __restrict__ hpad) {
  int bid = blockIdx.x, tid = threadIdx.x;
  if (bid < 1458) {                       // xpad: 5832*64
    int idx = bid * 256 + tid;
    int row = idx >> 6, c = idx & 63;
    int pd = row / 324, rem = row - pd * 324;
    int ph = rem / 18, pw = rem - ph * 18;
    short v = 0;
    if ((unsigned)(pd - 1) < 16u && (unsigned)(ph - 1) < 16u && (unsigned)(pw - 1) < 16u) {
      int s = (pd - 1) * 256 + (ph - 1) * 16 + (pw - 1);
      v = f2bf(x[c * 4096 + s]);
    }
    xpad[idx] = v;
  } else if (bid < 3186) {                // w1t [256][27*64]
    int idx = (bid - 1458) * 256 + tid;
    int o = idx / 1728, r = idx - o * 1728;
    int off = r >> 6, ic = r & 63;
    w1t[idx] = f2bf(c1w[(o * 64 + ic) * 27 + off]);
  } else if (bid < 4914) {                // w2t [64][27*256]
    int idx = (bid - 3186) * 256 + tid;
    int o = idx / 6912, r = idx - o * 6912;
    int off = r >> 8, ic = r & 255;
    w2t[idx] = f2bf(c2w[(o * 256 + ic) * 27 + off]);
  } else if (bid < 5938) {                // q,k,v,ffn weight casts (4 x 65536)
    int idx = (bid - 4914) * 256 + tid;
    int which = idx >> 16, r = idx & 65535;
    const float* src = (which == 0) ? qw : (which == 1) ? kw : (which == 2) ? vw : fw;
    wqkvf[idx] = f2bf(src[r]);
  } else {                                // hpad zero (full)
    int i = (bid - 5938) * 2048 + tid * 8;
    short8 z = {0, 0, 0, 0, 0, 0, 0, 0};
    *(short8*)(hpad + i) = z;
  }
}

// ---------- conv1 via MFMA: xpad[5832][64] x w1t[256][1728] -> h0[4096][256] ----------
__global__ __launch_bounds__(256) void k_conv1m(const short* __restrict__ xpad,
                                                const short* __restrict__ wt,
                                                const float* __restrict__ bias,
                                                float* __restrict__ h0) {
  int bid = blockIdx.x;  // 512
  int mt = bid >> 1, ch = bid & 1;
  int tid = threadIdx.x, w = tid >> 6, lane = tid & 63, g = lane >> 4, c = lane & 15;
  int d = mt >> 4, h = mt & 15;
  int nb = ch * 128 + w * 32;
  f32x4 acc0 = {0.f, 0.f, 0.f, 0.f}, acc1 = {0.f, 0.f, 0.f, 0.f};
  for (int off = 0; off < 27; ++off) {
    int kd = off / 9, r = off - kd * 9, kh = r / 3, kw = r - kh * 3;
    int rowb = ((d + kd) * 18 + h + kh) * 18 + kw + c;
#pragma unroll
    for (int kc = 0; kc < 2; ++kc) {
      short8 af = *(const short8*)(xpad + rowb * 64 + kc * 32 + 8 * g);
      int kidx = off * 64 + kc * 32 + 8 * g;
      short8 b0 = *(const short8*)(wt + (nb + c) * 1728 + kidx);
      short8 b1 = *(const short8*)(wt + (nb + 16 + c) * 1728 + kidx);
      acc0 = __builtin_amdgcn_mfma_f32_16x16x32_bf16(af, b0, acc0, 0, 0, 0);
      acc1 = __builtin_amdgcn_mfma_f32_16x16x32_bf16(af, b1, acc1, 0, 0, 0);
    }
  }
  int o0 = nb + c, o1 = nb + 16 + c;
  float bv0 = bias[o0], bv1 = bias[o1];
#pragma unroll
  for (int i = 0; i < 4; ++i) {
    int s = mt * 16 + 4 * g + i;
    h0[s * 256 + o0] = acc0[i] + bv0;
    h0[s * 256 + o1] = acc1[i] + bv1;
  }
}

// ---------- layernorm: fp32 + bf16 outputs ----------
__global__ __launch_bounds__(256) void k_layernorm(const float* __restrict__ in,
                                                   const float* __restrict__ g,
                                                   const float* __restrict__ b,
                                                   float* __restrict__ outf,
                                                   short* __restrict__ outb) {
  int s = blockIdx.x, tid = threadIdx.x;
  float xv = in[s * 256 + tid];
  float s1 = xv, s2 = xv * xv;
#pragma unroll
  for (int off = 32; off > 0; off >>= 1) {
    s1 += __shfl_down(s1, off);
    s2 += __shfl_down(s2, off);
  }
  __shared__ float w1[4], w2[4], mb[2];
  int wid = tid >> 6;
  if ((tid & 63) == 0) { w1[wid] = s1; w2[wid] = s2; }
  __syncthreads();
  if (tid == 0) {
    float t1 = w1[0] + w1[1] + w1[2] + w1[3];
    float t2 = w2[0] + w2[1] + w2[2] + w2[3];
    float m = t1 * (1.f / 256.f);
    float var = t2 * (1.f / 256.f) - m * m;
    mb[0] = m;
    mb[1] = rsqrtf(var + 1e-5f);
  }
  __syncthreads();
  float y = (xv - mb[0]) * mb[1] * g[tid] + b[tid];
  outf[s * 256 + tid] = y;
  outb[s * 256 + tid] = f2bf(y);
}

// ---------- fused QKV GEMM: 256 blocks x 3; 16 m-rows/block, 64 n-cols/wave ----------
__global__ __launch_bounds__(256) void k_gemm_qkv(const short* __restrict__ ab,
                                                  const short* __restrict__ wqb,
                                                  const short* __restrict__ wkb,
                                                  const short* __restrict__ wvb,
                                                  const float* __restrict__ qbi,
                                                  const float* __restrict__ kbi,
                                                  const float* __restrict__ vbi,
                                                  short* __restrict__ qb,
                                                  short* __restrict__ kb,
                                                  short* __restrict__ vt) {
  int y = blockIdx.y;
  const short* wb = (y == 0) ? wqb : ((y == 1) ? wkb : wvb);
  int tid = threadIdx.x, w = tid >> 6, lane = tid & 63, g = lane >> 4, c = lane & 15;
  int m0 = blockIdx.x * 16;
  int nb = w * 64;
  f32x4 acc[4];
#pragma unroll
  for (int n = 0; n < 4; ++n) acc[n] = {0.f, 0.f, 0.f, 0.f};
#pragma unroll 2
  for (int k0 = 0; k0 < 256; k0 += 32) {
    short8 af = *(const short8*)(ab + (m0 + c) * 256 + k0 + 8 * g);
#pragma unroll
    for (int n = 0; n < 4; ++n) {
      short8 bf = *(const short8*)(wb + (nb + 16 * n + c) * 256 + k0 + 8 * g);
      acc[n] = __builtin_amdgcn_mfma_f32_16x16x32_bf16(af, bf, acc[n], 0, 0, 0);
    }
  }
  if (y < 2) {
    const float* bi = (y == 0) ? qbi : kbi;
    float sc = (y == 0) ? QK_SCALE_LOG2E : 1.f;
    short* ob = (y == 0) ? qb : kb;
#pragma unroll
    for (int n = 0; n < 4; ++n) {
      int o = nb + 16 * n + c;
      float bv = bi[o];
      int hh = o >> 5, dj = o & 31;
#pragma unroll
      for (int i = 0; i < 4; ++i) {
        int s = m0 + 4 * g + i;
        ob[((size_t)hh * S + s) * 32 + dj] = f2bf((acc[n][i] + bv) * sc);
      }
    }
  } else {
#pragma unroll
    for (int n = 0; n < 4; ++n) {
      int o = nb + 16 * n + c;
      float bv = vbi[o];
      short4v st;
#pragma unroll
      for (int i = 0; i < 4; ++i) st[i] = f2bf(acc[n][i] + bv);
      *(short4v*)(vt + (size_t)o * S + m0 + 4 * g) = st;
    }
  }
}

// ---------- attn pass 1: partial lsum over a q-quarter ----------
__global__ __launch_bounds__(256) void k_attn1(const short* __restrict__ qb,
                                               const short* __restrict__ kb,
                                               float* __restrict__ lpart) {
  int b = blockIdx.x;  // 2048 = h(8) x kt(64) x qs(4)
  int qs = b & 3, kt = (b >> 2) & 63, h = b >> 8;
  int tid = threadIdx.x;
  int w = tid >> 6, lane = tid & 63, g = lane >> 4, c = lane & 15;
  int k0 = kt * 64 + w * 16;
  const size_t hb = (size_t)h * S;
  short8 af = *(const short8*)(kb + (hb + k0 + c) * 32 + 8 * g);
  const f32x4 z4 = {0.f, 0.f, 0.f, 0.f};
  float ls[4] = {0.f, 0.f, 0.f, 0.f};
  int qend = qs * 1024 + 1024;
  for (int q0 = qs * 1024; q0 < qend; q0 += 32) {
    short8 b0 = *(const short8*)(qb + (hb + q0 + c) * 32 + 8 * g);
    short8 b1 = *(const short8*)(qb + (hb + q0 + 16 + c) * 32 + 8 * g);
    f32x4 a0 = __builtin_amdgcn_mfma_f32_16x16x32_bf16(af, b0, z4, 0, 0, 0);
    f32x4 a1 = __builtin_amdgcn_mfma_f32_16x16x32_bf16(af, b1, z4, 0, 0, 0);
#pragma unroll
    for (int i = 0; i < 4; ++i) ls[i] += fexp2(a0[i]) + fexp2(a1[i]);
  }
#pragma unroll
  for (int i = 0; i < 4; ++i) {
    ls[i] += __shfl_xor(ls[i], 1);
    ls[i] += __shfl_xor(ls[i], 2);
    ls[i] += __shfl_xor(ls[i], 4);
    ls[i] += __shfl_xor(ls[i], 8);
  }
  if (c == 0) {
#pragma unroll
    for (int i = 0; i < 4; ++i)
      lpart[qs * 32768 + h * S + k0 + 4 * g + i] = ls[i];
  }
}

// linv = 1 / (sum of 4 q-quarter partials)
__global__ __launch_bounds__(256) void k_linv(const float* __restrict__ lpart,
                                              float* __restrict__ linv) {
  int i = blockIdx.x * 256 + threadIdx.x;  // 32768
  linv[i] = 1.0f / (lpart[i] + lpart[i + 32768] + lpart[i + 65536] + lpart[i + 98304]);
}

// vt[row][k] *= linv[h][k]  (fold 1/l into V)
__global__ __launch_bounds__(256) void k_scalevt(short* __restrict__ vt,
                                                 const float* __restrict__ linv) {
  int idx = blockIdx.x * 256 + threadIdx.x;  // 262144
  int row = idx >> 9;
  int col0 = (idx & 511) << 3;
  int h = row >> 5;
  const float* lp = linv + h * 4096 + col0;
  float4 l0 = *(const float4*)(lp);
  float4 l1 = *(const float4*)(lp + 4);
  short8 v = *(short8*)(vt + (size_t)row * S + col0);
  union { unsigned u[4]; short8 s8; } r;
  r.u[0] = cvt_pk_bf16(bf2f(v[0]) * l0.x, bf2f(v[1]) * l0.y);
  r.u[1] = cvt_pk_bf16(bf2f(v[2]) * l0.z, bf2f(v[3]) * l0.w);
  r.u[2] = cvt_pk_bf16(bf2f(v[4]) * l1.x, bf2f(v[5]) * l1.y);
  r.u[3] = cvt_pk_bf16(bf2f(v[6]) * l1.z, bf2f(v[7]) * l1.w);
  *(short8*)(vt + (size_t)row * S + col0) = r.s8;
}

// ---------- attn pass 2: 32x32 MFMA, swapped QK, zero LDS, k-split x8,
// TWO q-tiles per wave (independent chains; K/V fragment loads shared) ----------
__global__ __launch_bounds__(256) void k_attn2(const short* __restrict__ qb,
                                               const short* __restrict__ kb,
                                               const short* __restrict__ vt,
                                               short* __restrict__ parts) {
  int b = blockIdx.x;  // 1024 = h(8) x qt(16) x ks(8)
  int ks = b & 7, qt = (b >> 3) & 15, h = b >> 7;
  int tid = threadIdx.x;
  int w = tid >> 6, lane = tid & 63;
  int lo = lane & 31, hi = lane >> 5;
  // sigma: swap quartets [4-7]<->[8-11] and [20-23]<->[24-27]
  int sl = lo ^ ((((lo >> 2) ^ (lo >> 3)) & 1) * 12);
  int q0a = qt * 256 + w * 64;
  int q0b = q0a + 32;
  const size_t hb = (size_t)h * S;
  short8 bqa0 = *(const short8*)(qb + (hb + q0a + lo) * 32 + 8 * hi);
  short8 bqa1 = *(const short8*)(qb + (hb + q0a + lo) * 32 + 16 + 8 * hi);
  short8 bqb0 = *(const short8*)(qb + (hb + q0b + lo) * 32 + 8 * hi);
  short8 bqb1 = *(const short8*)(qb + (hb + q0b + lo) * 32 + 16 + 8 * hi);
  f32x16 accA = {}, accB = {};
  const short* krow = kb + (hb + sl) * 32;
  const short* vrow = vt + ((size_t)(h * 32) + lo) * S;
  const f32x16 z16 = {};
  int kend = ks * 512 + 512;
#pragma unroll 1
  for (int k0 = ks * 512; k0 < kend; k0 += 32) {
    short8 ak0 = *(const short8*)(krow + (size_t)k0 * 32 + 8 * hi);
    short8 ak1 = *(const short8*)(krow + (size_t)k0 * 32 + 16 + 8 * hi);
    // two independent QK chains sharing the K fragments
    f32x16 pA = __builtin_amdgcn_mfma_f32_32x32x16_bf16(ak0, bqa0, z16, 0, 0, 0);
    f32x16 pB = __builtin_amdgcn_mfma_f32_32x32x16_bf16(ak0, bqb0, z16, 0, 0, 0);
    pA = __builtin_amdgcn_mfma_f32_32x32x16_bf16(ak1, bqa1, pA, 0, 0, 0);
    pB = __builtin_amdgcn_mfma_f32_32x32x16_bf16(ak1, bqb1, pB, 0, 0, 0);
    union { unsigned u[4]; short8 s8; } fA0, fA1, fB0, fB1;
#pragma unroll
    for (int m = 0; m < 4; ++m)
      fA0.u[m] = cvt_pk_bf16(fexp2(pA[2 * m]), fexp2(pA[2 * m + 1]));
#pragma unroll
    for (int m = 0; m < 4; ++m)
      fA1.u[m] = cvt_pk_bf16(fexp2(pA[8 + 2 * m]), fexp2(pA[9 + 2 * m]));
#pragma unroll
    for (int m = 0; m < 4; ++m)
      fB0.u[m] = cvt_pk_bf16(fexp2(pB[2 * m]), fexp2(pB[2 * m + 1]));
#pragma unroll
    for (int m = 0; m < 4; ++m)
      fB1.u[m] = cvt_pk_bf16(fexp2(pB[8 + 2 * m]), fexp2(pB[9 + 2 * m]));
    short8 bv0 = *(const short8*)(vrow + k0 + 8 * hi);
    short8 bv1 = *(const short8*)(vrow + k0 + 16 + 8 * hi);
    accA = __builtin_amdgcn_mfma_f32_32x32x16_bf16(fA0.s8, bv0, accA, 0, 0, 0);
    accB = __builtin_amdgcn_mfma_f32_32x32x16_bf16(fB0.s8, bv0, accB, 0, 0, 0);
    accA = __builtin_amdgcn_mfma_f32_32x32x16_bf16(fA1.s8, bv1, accA, 0, 0, 0);
    accB = __builtin_amdgcn_mfma_f32_32x32x16_bf16(fB1.s8, bv1, accB, 0, 0, 0);
  }
  short* part = parts + (size_t)ks * (S * DM);
  int col = h * 32 + lo;
#pragma unroll
  for (int r = 0; r < 16; ++r) {
    int qrel = (r & 3) + 8 * (r >> 2) + 4 * hi;
    part[(q0a + qrel) * 256 + col] = f2bf(accA[r]);
    part[(q0b + qrel) * 256 + col] = f2bf(accB[r]);
  }
}

// xt = hn + sum(8 bf16 parts); write xt + layernorm -> h2b
__global__ __launch_bounds__(256) void k_combine_ln(const short* __restrict__ parts,
                                                    const float* __restrict__ hn,
                                                    const float* __restrict__ g,
                                                    const float* __restrict__ b,
                                                    float* __restrict__ xt,
                                                    short* __restrict__ h2b) {
  int s = blockIdx.x, tid = threadIdx.x;
  int i = s * 256 + tid;
  const int SD4 = S * DM;
  float xv = hn[i];
#pragma unroll
  for (int j = 0; j < 8; ++j) xv += bf2f(parts[i + j * SD4]);
  xt[i] = xv;
  float s1 = xv, s2 = xv * xv;
#pragma unroll
  for (int off = 32; off > 0; off >>= 1) {
    s1 += __shfl_down(s1, off);
    s2 += __shfl_down(s2, off);
  }
  __shared__ float w1[4], w2[4], mb[2];
  int wid = tid >> 6;
  if ((tid & 63) == 0) { w1[wid] = s1; w2[wid] = s2; }
  __syncthreads();
  if (tid == 0) {
    float t1 = w1[0] + w1[1] + w1[2] + w1[3];
    float t2 = w2[0] + w2[1] + w2[2] + w2[3];
    float m = t1 * (1.f / 256.f);
    float var = t2 * (1.f / 256.f) - m * m;
    mb[0] = m;
    mb[1] = rsqrtf(var + 1e-5f);
  }
  __syncthreads();
  h2b[i] = f2bf((xv - mb[0]) * mb[1] * g[tid] + b[tid]);
}

// ---------- FFN GEMM: 256 blocks; relu+bias, +xt, -> hpad (padded bf16) ----------
__global__ __launch_bounds__(256) void k_gemm_ffn(const short* __restrict__ ab,
                                                  const short* __restrict__ wb,
                                                  const float* __restrict__ bi,
                                                  const float* __restrict__ xt,
                                                  short* __restrict__ hpad) {
  int tid = threadIdx.x, w = tid >> 6, lane = tid & 63, g = lane >> 4, c = lane & 15;
  int m0 = blockIdx.x * 16;
  int nb = w * 64;
  f32x4 acc[4];
#pragma unroll
  for (int n = 0; n < 4; ++n) acc[n] = {0.f, 0.f, 0.f, 0.f};
#pragma unroll 2
  for (int k0 = 0; k0 < 256; k0 += 32) {
    short8 af = *(const short8*)(ab + (m0 + c) * 256 + k0 + 8 * g);
#pragma unroll
    for (int n = 0; n < 4; ++n) {
      short8 bf = *(const short8*)(wb + (nb + 16 * n + c) * 256 + k0 + 8 * g);
      acc[n] = __builtin_amdgcn_mfma_f32_16x16x32_bf16(af, bf, acc[n], 0, 0, 0);
    }
  }
  int pr[4];
#pragma unroll
  for (int i = 0; i < 4; ++i) pr[i] = pad_idx(m0 + 4 * g + i) * 256;
#pragma unroll
  for (int n = 0; n < 4; ++n) {
    int o = nb + 16 * n + c;
    float bv = bi[o];
#pragma unroll
    for (int i = 0; i < 4; ++i) {
      int s = m0 + 4 * g + i;
      float v = acc[n][i] + bv;
      v = v > 0.f ? v : 0.f;
      hpad[pr[i] + o] = f2bf(v + xt[s * 256 + o]);
    }
  }
}

// ---------- conv2 via MFMA, K-split x4 across blocks ----------
__global__ __launch_bounds__(256) void k_conv2m(const short* __restrict__ hpad,
                                                const short* __restrict__ wt,
                                                float* __restrict__ pbase) {
  __shared__ float red[3][16][65];
  int bid = blockIdx.x;  // 1024 = mt(256) x kh(4)
  int mt = bid >> 2, kh = bid & 3;
  int tid = threadIdx.x, w = tid >> 6, lane = tid & 63, g = lane >> 4, c = lane & 15;
  int d = mt >> 4, h = mt & 15;
  f32x4 acc[4];
#pragma unroll
  for (int n = 0; n < 4; ++n) acc[n] = {0.f, 0.f, 0.f, 0.f};
  int off0 = kh * 7;
  int offn = (kh == 3) ? 6 : 7;
  for (int off = off0 + w; off < off0 + offn; off += 4) {
    int kd = off / 9, rr = off - kd * 9, kkh = rr / 3, kw = rr - kkh * 3;
    int rowb = ((d + kd) * 18 + h + kkh) * 18 + kw + c;
    const short* arow = hpad + rowb * 256;
    const short* wrow = wt + off * 256;
#pragma unroll 2
    for (int kc = 0; kc < 8; ++kc) {
      short8 af = *(const short8*)(arow + kc * 32 + 8 * g);
#pragma unroll
      for (int n = 0; n < 4; ++n) {
        short8 bf = *(const short8*)(wrow + (16 * n + c) * 6912 + kc * 32 + 8 * g);
        acc[n] = __builtin_amdgcn_mfma_f32_16x16x32_bf16(af, bf, acc[n], 0, 0, 0);
      }
    }
  }
  if (w > 0) {
#pragma unroll
    for (int n = 0; n < 4; ++n)
#pragma unroll
      for (int i = 0; i < 4; ++i) red[w - 1][n * 4 + i][lane] = acc[n][i];
  }
  __syncthreads();
  if (w == 0) {
    float* pbuf = pbase + (size_t)kh * (S * DM / 4);  // 64*4096 each
#pragma unroll
    for (int n = 0; n < 4; ++n) {
      int o = 16 * n + c;
      float4 st;
      st.x = acc[n][0] + red[0][n * 4 + 0][lane] + red[1][n * 4 + 0][lane] + red[2][n * 4 + 0][lane];
      st.y = acc[n][1] + red[0][n * 4 + 1][lane] + red[1][n * 4 + 1][lane] + red[2][n * 4 + 1][lane];
      st.z = acc[n][2] + red[0][n * 4 + 2][lane] + red[1][n * 4 + 2][lane] + red[2][n * 4 + 2][lane];
      st.w = acc[n][3] + red[0][n * 4 + 3][lane] + red[1][n * 4 + 3][lane] + red[2][n * 4 + 3][lane];
      *(float4*)(pbuf + o * 4096 + mt * 16 + 4 * g) = st;
    }
  }
}

__global__ __launch_bounds__(256) void k_conv2fin(const float* __restrict__ pbase,
                                                  const float* __restrict__ bias,
                                                  float* __restrict__ out) {
  int idx4 = (blockIdx.x * 256 + threadIdx.x) * 4;  // 262144 total
  int o = idx4 >> 12;
  const int PS = S * DM / 4;  // 262144
  float4 a = *(const float4*)(pbase + idx4);
  float4 b = *(const float4*)(pbase + PS + idx4);
  float4 c = *(const float4*)(pbase + 2 * PS + idx4);
  float4 d = *(const float4*)(pbase + 3 * PS + idx4);
  float bv = bias[o];
  float4 r;
  r.x = a.x + b.x + c.x + d.x + bv;
  r.y = a.y + b.y + c.y + d.y + bv;
  r.z = a.z + b.z + c.z + d.z + bv;
  r.w = a.w + b.w + c.w + d.w + bv;
  *(float4*)(out + idx4) = r;
}

extern "C" void kernel_launch(void* const* d_in, const int* in_sizes, int n_in,
                              void* d_out, int out_size, void* d_ws, size_t ws_size,
                              hipStream_t stream) {
  const float* x   = (const float*)d_in[0];
  const float* c1w = (const float*)d_in[1];
  const float* c1b = (const float*)d_in[2];
  const float* lng = (const float*)d_in[3];
  const float* lnb = (const float*)d_in[4];
  const float* qw  = (const float*)d_in[5];
  const float* qbi = (const float*)d_in[6];
  const float* kw  = (const float*)d_in[7];
  const float* kbi = (const float*)d_in[8];
  const float* vw  = (const float*)d_in[9];
  const float* vbi = (const float*)d_in[10];
  const float* fw  = (const float*)d_in[11];
  const float* fbi = (const float*)d_in[12];
  const float* c2w = (const float*)d_in[13];
  const float* c2b = (const float*)d_in[14];
  float* out = (float*)d_out;
  float* ws = (float*)d_ws;

  const size_t SD = (size_t)S * DM;  // 1048576
  float* hn     = ws;                  // SD floats
  float* xt     = hn + SD;             // SD floats
  short* partsb = (short*)(xt + SD);   // 8*SD shorts (16MB)
  float* h0     = (float*)partsb;      // alias: dead before attn2 writes parts
  float* c2p    = (float*)partsb;      // alias: conv2 partials (SD floats)
  float* lpart  = (float*)(partsb + 8 * SD);  // 131072 floats
  float* linv   = lpart + 131072;      // 32768
  short* hnb    = (short*)(linv + 32768);
  short* h2b    = hnb + SD;
  short* qb     = h2b + SD;
  short* kb     = qb + SD;
  short* vt     = kb + SD;
  short* xpad   = vt + SD;             // 373248
  short* hpad   = xpad + 373248;       // 1492992
  short* w1t    = hpad + 1492992;      // 442368
  short* w2t    = w1t + 442368;        // 442368
  short* wqb    = w2t + 442368;        // 4 x 65536 contiguous
  short* wkb    = wqb + 65536;
  short* wvb    = wkb + 65536;
  short* wfb    = wvb + 65536;

  k_prep<<<6667, 256, 0, stream>>>(x, c1w, c2w, qw, kw, vw, fw,
                                   xpad, w1t, w2t, wqb, hpad);

  k_conv1m<<<512, 256, 0, stream>>>(xpad, w1t, c1b, h0);
  k_layernorm<<<4096, 256, 0, stream>>>(h0, lng, lnb, hn, hnb);

  k_gemm_qkv<<<dim3(256, 3), 256, 0, stream>>>(hnb, wqb, wkb, wvb, qbi, kbi, vbi,
                                               qb, kb, vt);

  k_attn1<<<2048, 256, 0, stream>>>(qb, kb, lpart);
  k_linv<<<128, 256, 0, stream>>>(lpart, linv);
  k_scalevt<<<1024, 256, 0, stream>>>(vt, linv);
  k_attn2<<<1024, 256, 0, stream>>>(qb, kb, vt, partsb);
  k_combine_ln<<<4096, 256, 0, stream>>>(partsb, hn, lng, lnb, xt, h2b);

  k_gemm_ffn<<<256, 256, 0, stream>>>(h2b, wfb, fbi, xt, hpad);
  k_conv2m<<<1024, 256, 0, stream>>>(hpad, w2t, c2p);
  k_conv2fin<<<256, 256, 0, stream>>>(c2p, c2b, out);
}

// Round 9
// 178.168 us; speedup vs baseline: 6.2822x; 1.0685x over previous
//
#include <hip/hip_runtime.h>
#include <math.h>

#define S 4096
#define DM 256

using short8 = __attribute__((ext_vector_type(8))) short;
using short4v = __attribute__((ext_vector_type(4))) short;
using f32x4 = __attribute__((ext_vector_type(4))) float;
using f32x16 = __attribute__((ext_vector_type(16))) float;

// 1/sqrt(32) * log2(e): fold into q so scores feed v_exp_f32 (2^x) directly
static constexpr float QK_SCALE_LOG2E = 0.17677669529663687f * 1.4426950408889634f;

__device__ __forceinline__ short f2bf(float f) {
  union { float f; unsigned u; } v;
  v.f = f;
  unsigned r = (v.u + 0x7FFFu + ((v.u >> 16) & 1u)) >> 16;
  return (short)r;
}

__device__ __forceinline__ float bf2f(short s) {
  union { unsigned u; float f; } v;
  v.u = ((unsigned)(unsigned short)s) << 16;
  return v.f;
}

__device__ __forceinline__ unsigned cvt_pk_bf16(float lo, float hi) {
  unsigned r;
  asm("v_cvt_pk_bf16_f32 %0, %1, %2" : "=v"(r) : "v"(lo), "v"(hi));
  return r;
}

__device__ __forceinline__ float fexp2(float x) {
  float r;
  asm("v_exp_f32 %0, %1" : "=v"(r) : "v"(x));
  return r;
}

__device__ __forceinline__ int pad_idx(int s) {
  int d = s >> 8, h = (s >> 4) & 15, w = s & 15;
  return ((d + 1) * 18 + (h + 1)) * 18 + (w + 1);
}

// ---------- fused prep: xpad(full, pad+cast) | w1t | w2t | qkv/ffn casts | hpad halo zero ----------
__global__ __launch_bounds__(256) void k_prep(const float* __restrict__ x,
                                              const float* __restrict__ c1w,
                                              const float* __restrict__ c2w,
                                              const float* __restrict__ qw,
                                              const float* __restrict__ kw,
                                              const float* __restrict__ vw,
                                              const float* __restrict__ fw,
                                              short* __restrict__ xpad,
                                              short* __restrict__ w1t,
                                              short* __restrict__ w2t,
                                              short* __restrict__ wqkvf,
                                              short* __restrict__ hpad) {
  int bid = blockIdx.x, tid = threadIdx.x;
  if (bid < 1458) {                       // xpad: 5832*64
    int idx = bid * 256 + tid;
    int row = idx >> 6, c = idx & 63;
    int pd = row / 324, rem = row - pd * 324;
    int ph = rem / 18, pw = rem - ph * 18;
    short v = 0;
    if ((unsigned)(pd - 1) < 16u && (unsigned)(ph - 1) < 16u && (unsigned)(pw - 1) < 16u) {
      int s = (pd - 1) * 256 + (ph - 1) * 16 + (pw - 1);
      v = f2bf(x[c * 4096 + s]);
    }
    xpad[idx] = v;
  } else if (bid < 3186) {                // w1t [256][27*64]
    int idx = (bid - 1458) * 256 + tid;
    int o = idx / 1728, r = idx - o * 1728;
    int off = r >> 6, ic = r & 63;
    w1t[idx] = f2bf(c1w[(o * 64 + ic) * 27 + off]);
  } else if (bid < 4914) {                // w2t [64][27*256]
    int idx = (bid - 3186) * 256 + tid;
    int o = idx / 6912, r = idx - o * 6912;
    int off = r >> 8, ic = r & 255;
    w2t[idx] = f2bf(c2w[(o * 256 + ic) * 27 + off]);
  } else if (bid < 5938) {                // q,k,v,ffn weight casts (4 x 65536)
    int idx = (bid - 4914) * 256 + tid;
    int which = idx >> 16, r = idx & 65535;
    const float* src = (which == 0) ? qw : (which == 1) ? kw : (which == 2) ? vw : fw;
    wqkvf[idx] = f2bf(src[r]);
  } else {                                // hpad zero (full)
    int i = (bid - 5938) * 2048 + tid * 8;
    short8 z = {0, 0, 0, 0, 0, 0, 0, 0};
    *(short8*)(hpad + i) = z;
  }
}

// ---------- conv1 via MFMA: xpad[5832][64] x w1t[256][1728] -> h0[4096][256] ----------
__global__ __launch_bounds__(256) void k_conv1m(const short* __restrict__ xpad,
                                                const short* __restrict__ wt,
                                                const float* __restrict__ bias,
                                                float* __restrict__ h0) {
  int bid = blockIdx.x;  // 512
  int mt = bid >> 1, ch = bid & 1;
  int tid = threadIdx.x, w = tid >> 6, lane = tid & 63, g = lane >> 4, c = lane & 15;
  int d = mt >> 4, h = mt & 15;
  int nb = ch * 128 + w * 32;
  f32x4 acc0 = {0.f, 0.f, 0.f, 0.f}, acc1 = {0.f, 0.f, 0.f, 0.f};
  for (int off = 0; off < 27; ++off) {
    int kd = off / 9, r = off - kd * 9, kh = r / 3, kw = r - kh * 3;
    int rowb = ((d + kd) * 18 + h + kh) * 18 + kw + c;
#pragma unroll
    for (int kc = 0; kc < 2; ++kc) {
      short8 af = *(const short8*)(xpad + rowb * 64 + kc * 32 + 8 * g);
      int kidx = off * 64 + kc * 32 + 8 * g;
      short8 b0 = *(const short8*)(wt + (nb + c) * 1728 + kidx);
      short8 b1 = *(const short8*)(wt + (nb + 16 + c) * 1728 + kidx);
      acc0 = __builtin_amdgcn_mfma_f32_16x16x32_bf16(af, b0, acc0, 0, 0, 0);
      acc1 = __builtin_amdgcn_mfma_f32_16x16x32_bf16(af, b1, acc1, 0, 0, 0);
    }
  }
  int o0 = nb + c, o1 = nb + 16 + c;
  float bv0 = bias[o0], bv1 = bias[o1];
#pragma unroll
  for (int i = 0; i < 4; ++i) {
    int s = mt * 16 + 4 * g + i;
    h0[s * 256 + o0] = acc0[i] + bv0;
    h0[s * 256 + o1] = acc1[i] + bv1;
  }
}

// ---------- layernorm: fp32 + bf16 outputs ----------
__global__ __launch_bounds__(256) void k_layernorm(const float* __restrict__ in,
                                                   const float* __restrict__ g,
                                                   const float* __restrict__ b,
                                                   float* __restrict__ outf,
                                                   short* __restrict__ outb) {
  int s = blockIdx.x, tid = threadIdx.x;
  float xv = in[s * 256 + tid];
  float s1 = xv, s2 = xv * xv;
#pragma unroll
  for (int off = 32; off > 0; off >>= 1) {
    s1 += __shfl_down(s1, off);
    s2 += __shfl_down(s2, off);
  }
  __shared__ float w1[4], w2[4], mb[2];
  int wid = tid >> 6;
  if ((tid & 63) == 0) { w1[wid] = s1; w2[wid] = s2; }
  __syncthreads();
  if (tid == 0) {
    float t1 = w1[0] + w1[1] + w1[2] + w1[3];
    float t2 = w2[0] + w2[1] + w2[2] + w2[3];
    float m = t1 * (1.f / 256.f);
    float var = t2 * (1.f / 256.f) - m * m;
    mb[0] = m;
    mb[1] = rsqrtf(var + 1e-5f);
  }
  __syncthreads();
  float y = (xv - mb[0]) * mb[1] * g[tid] + b[tid];
  outf[s * 256 + tid] = y;
  outb[s * 256 + tid] = f2bf(y);
}

// ---------- fused QKV GEMM: 256 blocks x 3; 16 m-rows/block, 64 n-cols/wave ----------
__global__ __launch_bounds__(256) void k_gemm_qkv(const short* __restrict__ ab,
                                                  const short* __restrict__ wqb,
                                                  const short* __restrict__ wkb,
                                                  const short* __restrict__ wvb,
                                                  const float* __restrict__ qbi,
                                                  const float* __restrict__ kbi,
                                                  const float* __restrict__ vbi,
                                                  short* __restrict__ qb,
                                                  short* __restrict__ kb,
                                                  short* __restrict__ vt) {
  int y = blockIdx.y;
  const short* wb = (y == 0) ? wqb : ((y == 1) ? wkb : wvb);
  int tid = threadIdx.x, w = tid >> 6, lane = tid & 63, g = lane >> 4, c = lane & 15;
  int m0 = blockIdx.x * 16;
  int nb = w * 64;
  f32x4 acc[4];
#pragma unroll
  for (int n = 0; n < 4; ++n) acc[n] = {0.f, 0.f, 0.f, 0.f};
#pragma unroll 2
  for (int k0 = 0; k0 < 256; k0 += 32) {
    short8 af = *(const short8*)(ab + (m0 + c) * 256 + k0 + 8 * g);
#pragma unroll
    for (int n = 0; n < 4; ++n) {
      short8 bf = *(const short8*)(wb + (nb + 16 * n + c) * 256 + k0 + 8 * g);
      acc[n] = __builtin_amdgcn_mfma_f32_16x16x32_bf16(af, bf, acc[n], 0, 0, 0);
    }
  }
  if (y < 2) {
    const float* bi = (y == 0) ? qbi : kbi;
    float sc = (y == 0) ? QK_SCALE_LOG2E : 1.f;
    short* ob = (y == 0) ? qb : kb;
#pragma unroll
    for (int n = 0; n < 4; ++n) {
      int o = nb + 16 * n + c;
      float bv = bi[o];
      int hh = o >> 5, dj = o & 31;
#pragma unroll
      for (int i = 0; i < 4; ++i) {
        int s = m0 + 4 * g + i;
        ob[((size_t)hh * S + s) * 32 + dj] = f2bf((acc[n][i] + bv) * sc);
      }
    }
  } else {
#pragma unroll
    for (int n = 0; n < 4; ++n) {
      int o = nb + 16 * n + c;
      float bv = vbi[o];
      short4v st;
#pragma unroll
      for (int i = 0; i < 4; ++i) st[i] = f2bf(acc[n][i] + bv);
      *(short4v*)(vt + (size_t)o * S + m0 + 4 * g) = st;
    }
  }
}

// ---------- attn pass 1: 32x32 MFMA; partial lsum over a q-eighth ----------
// A = K rows, B = Q rows -> p[r] = S^T[k0 + (r&3)+8*(r>>2)+4*hi][q0 + lo].
// Accumulate exp2 into 16 per-k registers; 5-step shfl_xor column reduce once.
__global__ __launch_bounds__(256) void k_attn1(const short* __restrict__ qb,
                                               const short* __restrict__ kb,
                                               float* __restrict__ lpart) {
  int b = blockIdx.x;  // 2048 = h(8) x kt(32) x qs(8)
  int qs = b & 7, kt = (b >> 3) & 31, h = b >> 8;
  int tid = threadIdx.x;
  int w = tid >> 6, lane = tid & 63;
  int lo = lane & 31, hi = lane >> 5;
  int k0 = kt * 128 + w * 32;
  const size_t hb = (size_t)h * S;
  const short* krow = kb + (hb + k0 + lo) * 32;
  short8 ak0 = *(const short8*)(krow + 8 * hi);
  short8 ak1 = *(const short8*)(krow + 16 + 8 * hi);
  f32x16 ls = {};
  const f32x16 z16 = {};
  int qend = qs * 512 + 512;
  for (int q0 = qs * 512; q0 < qend; q0 += 32) {
    short8 bq0 = *(const short8*)(qb + (hb + q0 + lo) * 32 + 8 * hi);
    short8 bq1 = *(const short8*)(qb + (hb + q0 + lo) * 32 + 16 + 8 * hi);
    f32x16 p = __builtin_amdgcn_mfma_f32_32x32x16_bf16(ak0, bq0, z16, 0, 0, 0);
    p = __builtin_amdgcn_mfma_f32_32x32x16_bf16(ak1, bq1, p, 0, 0, 0);
#pragma unroll
    for (int r = 0; r < 16; ++r) ls[r] += fexp2(p[r]);
  }
#pragma unroll
  for (int r = 0; r < 16; ++r) {
    float v = ls[r];
    v += __shfl_xor(v, 1);
    v += __shfl_xor(v, 2);
    v += __shfl_xor(v, 4);
    v += __shfl_xor(v, 8);
    v += __shfl_xor(v, 16);
    ls[r] = v;
  }
  if (lo == 0) {
#pragma unroll
    for (int r = 0; r < 16; ++r)
      lpart[qs * 32768 + h * 4096 + k0 + (r & 3) + 8 * (r >> 2) + 4 * hi] = ls[r];
  }
}

// linv = 1 / (sum of 8 q-eighth partials)
__global__ __launch_bounds__(256) void k_linv(const float* __restrict__ lpart,
                                              float* __restrict__ linv) {
  int i = blockIdx.x * 256 + threadIdx.x;  // 32768
  float s = 0.f;
#pragma unroll
  for (int j = 0; j < 8; ++j) s += lpart[i + j * 32768];
  linv[i] = 1.0f / s;
}

// vt[row][k] *= linv[h][k]  (fold 1/l into V)
__global__ __launch_bounds__(256) void k_scalevt(short* __restrict__ vt,
                                                 const float* __restrict__ linv) {
  int idx = blockIdx.x * 256 + threadIdx.x;  // 262144
  int row = idx >> 9;
  int col0 = (idx & 511) << 3;
  int h = row >> 5;
  const float* lp = linv + h * 4096 + col0;
  float4 l0 = *(const float4*)(lp);
  float4 l1 = *(const float4*)(lp + 4);
  short8 v = *(short8*)(vt + (size_t)row * S + col0);
  union { unsigned u[4]; short8 s8; } r;
  r.u[0] = cvt_pk_bf16(bf2f(v[0]) * l0.x, bf2f(v[1]) * l0.y);
  r.u[1] = cvt_pk_bf16(bf2f(v[2]) * l0.z, bf2f(v[3]) * l0.w);
  r.u[2] = cvt_pk_bf16(bf2f(v[4]) * l1.x, bf2f(v[5]) * l1.y);
  r.u[3] = cvt_pk_bf16(bf2f(v[6]) * l1.z, bf2f(v[7]) * l1.w);
  *(short8*)(vt + (size_t)row * S + col0) = r.s8;
}

// ---------- attn pass 2: 32x32 MFMA, swapped QK, zero LDS, k-split x8,
// TWO q-tiles per wave (independent chains; K/V fragment loads shared) ----------
__global__ __launch_bounds__(256) void k_attn2(const short* __restrict__ qb,
                                               const short* __restrict__ kb,
                                               const short* __restrict__ vt,
                                               short* __restrict__ parts) {
  int b = blockIdx.x;  // 1024 = h(8) x qt(16) x ks(8)
  int ks = b & 7, qt = (b >> 3) & 15, h = b >> 7;
  int tid = threadIdx.x;
  int w = tid >> 6, lane = tid & 63;
  int lo = lane & 31, hi = lane >> 5;
  // sigma: swap quartets [4-7]<->[8-11] and [20-23]<->[24-27]
  int sl = lo ^ ((((lo >> 2) ^ (lo >> 3)) & 1) * 12);
  int q0a = qt * 256 + w * 64;
  int q0b = q0a + 32;
  const size_t hb = (size_t)h * S;
  short8 bqa0 = *(const short8*)(qb + (hb + q0a + lo) * 32 + 8 * hi);
  short8 bqa1 = *(const short8*)(qb + (hb + q0a + lo) * 32 + 16 + 8 * hi);
  short8 bqb0 = *(const short8*)(qb + (hb + q0b + lo) * 32 + 8 * hi);
  short8 bqb1 = *(const short8*)(qb + (hb + q0b + lo) * 32 + 16 + 8 * hi);
  f32x16 accA = {}, accB = {};
  const short* krow = kb + (hb + sl) * 32;
  const short* vrow = vt + ((size_t)(h * 32) + lo) * S;
  const f32x16 z16 = {};
  int kend = ks * 512 + 512;
#pragma unroll 1
  for (int k0 = ks * 512; k0 < kend; k0 += 32) {
    short8 ak0 = *(const short8*)(krow + (size_t)k0 * 32 + 8 * hi);
    short8 ak1 = *(const short8*)(krow + (size_t)k0 * 32 + 16 + 8 * hi);
    // two independent QK chains sharing the K fragments
    f32x16 pA = __builtin_amdgcn_mfma_f32_32x32x16_bf16(ak0, bqa0, z16, 0, 0, 0);
    f32x16 pB = __builtin_amdgcn_mfma_f32_32x32x16_bf16(ak0, bqb0, z16, 0, 0, 0);
    pA = __builtin_amdgcn_mfma_f32_32x32x16_bf16(ak1, bqa1, pA, 0, 0, 0);
    pB = __builtin_amdgcn_mfma_f32_32x32x16_bf16(ak1, bqb1, pB, 0, 0, 0);
    union { unsigned u[4]; short8 s8; } fA0, fA1, fB0, fB1;
#pragma unroll
    for (int m = 0; m < 4; ++m)
      fA0.u[m] = cvt_pk_bf16(fexp2(pA[2 * m]), fexp2(pA[2 * m + 1]));
#pragma unroll
    for (int m = 0; m < 4; ++m)
      fA1.u[m] = cvt_pk_bf16(fexp2(pA[8 + 2 * m]), fexp2(pA[9 + 2 * m]));
#pragma unroll
    for (int m = 0; m < 4; ++m)
      fB0.u[m] = cvt_pk_bf16(fexp2(pB[2 * m]), fexp2(pB[2 * m + 1]));
#pragma unroll
    for (int m = 0; m < 4; ++m)
      fB1.u[m] = cvt_pk_bf16(fexp2(pB[8 + 2 * m]), fexp2(pB[9 + 2 * m]));
    short8 bv0 = *(const short8*)(vrow + k0 + 8 * hi);
    short8 bv1 = *(const short8*)(vrow + k0 + 16 + 8 * hi);
    accA = __builtin_amdgcn_mfma_f32_32x32x16_bf16(fA0.s8, bv0, accA, 0, 0, 0);
    accB = __builtin_amdgcn_mfma_f32_32x32x16_bf16(fB0.s8, bv0, accB, 0, 0, 0);
    accA = __builtin_amdgcn_mfma_f32_32x32x16_bf16(fA1.s8, bv1, accA, 0, 0, 0);
    accB = __builtin_amdgcn_mfma_f32_32x32x16_bf16(fB1.s8, bv1, accB, 0, 0, 0);
  }
  short* part = parts + (size_t)ks * (S * DM);
  int col = h * 32 + lo;
#pragma unroll
  for (int r = 0; r < 16; ++r) {
    int qrel = (r & 3) + 8 * (r >> 2) + 4 * hi;
    part[(q0a + qrel) * 256 + col] = f2bf(accA[r]);
    part[(q0b + qrel) * 256 + col] = f2bf(accB[r]);
  }
}

// xt = hn + sum(8 bf16 parts); write xt + layernorm -> h2b
__global__ __launch_bounds__(256) void k_combine_ln(const short* __restrict__ parts,
                                                    const float* __restrict__ hn,
                                                    const float* __restrict__ g,
                                                    const float* __restrict__ b,
                                                    float* __restrict__ xt,
                                                    short* __restrict__ h2b) {
  int s = blockIdx.x, tid = threadIdx.x;
  int i = s * 256 + tid;
  const int SD4 = S * DM;
  float xv = hn[i];
#pragma unroll
  for (int j = 0; j < 8; ++j) xv += bf2f(parts[i + j * SD4]);
  xt[i] = xv;
  float s1 = xv, s2 = xv * xv;
#pragma unroll
  for (int off = 32; off > 0; off >>= 1) {
    s1 += __shfl_down(s1, off);
    s2 += __shfl_down(s2, off);
  }
  __shared__ float w1[4], w2[4], mb[2];
  int wid = tid >> 6;
  if ((tid & 63) == 0) { w1[wid] = s1; w2[wid] = s2; }
  __syncthreads();
  if (tid == 0) {
    float t1 = w1[0] + w1[1] + w1[2] + w1[3];
    float t2 = w2[0] + w2[1] + w2[2] + w2[3];
    float m = t1 * (1.f / 256.f);
    float var = t2 * (1.f / 256.f) - m * m;
    mb[0] = m;
    mb[1] = rsqrtf(var + 1e-5f);
  }
  __syncthreads();
  h2b[i] = f2bf((xv - mb[0]) * mb[1] * g[tid] + b[tid]);
}

// ---------- FFN GEMM: 256 blocks; relu+bias, +xt, -> hpad (padded bf16) ----------
__global__ __launch_bounds__(256) void k_gemm_ffn(const short* __restrict__ ab,
                                                  const short* __restrict__ wb,
                                                  const float* __restrict__ bi,
                                                  const float* __restrict__ xt,
                                                  short* __restrict__ hpad) {
  int tid = threadIdx.x, w = tid >> 6, lane = tid & 63, g = lane >> 4, c = lane & 15;
  int m0 = blockIdx.x * 16;
  int nb = w * 64;
  f32x4 acc[4];
#pragma unroll
  for (int n = 0; n < 4; ++n) acc[n] = {0.f, 0.f, 0.f, 0.f};
#pragma unroll 2
  for (int k0 = 0; k0 < 256; k0 += 32) {
    short8 af = *(const short8*)(ab + (m0 + c) * 256 + k0 + 8 * g);
#pragma unroll
    for (int n = 0; n < 4; ++n) {
      short8 bf = *(const short8*)(wb + (nb + 16 * n + c) * 256 + k0 + 8 * g);
      acc[n] = __builtin_amdgcn_mfma_f32_16x16x32_bf16(af, bf, acc[n], 0, 0, 0);
    }
  }
  int pr[4];
#pragma unroll
  for (int i = 0; i < 4; ++i) pr[i] = pad_idx(m0 + 4 * g + i) * 256;
#pragma unroll
  for (int n = 0; n < 4; ++n) {
    int o = nb + 16 * n + c;
    float bv = bi[o];
#pragma unroll
    for (int i = 0; i < 4; ++i) {
      int s = m0 + 4 * g + i;
      float v = acc[n][i] + bv;
      v = v > 0.f ? v : 0.f;
      hpad[pr[i] + o] = f2bf(v + xt[s * 256 + o]);
    }
  }
}

// ---------- conv2 via MFMA, K-split x4 across blocks ----------
__global__ __launch_bounds__(256) void k_conv2m(const short* __restrict__ hpad,
                                                const short* __restrict__ wt,
                                                float* __restrict__ pbase) {
  __shared__ float red[3][16][65];
  int bid = blockIdx.x;  // 1024 = mt(256) x kh(4)
  int mt = bid >> 2, kh = bid & 3;
  int tid = threadIdx.x, w = tid >> 6, lane = tid & 63, g = lane >> 4, c = lane & 15;
  int d = mt >> 4, h = mt & 15;
  f32x4 acc[4];
#pragma unroll
  for (int n = 0; n < 4; ++n) acc[n] = {0.f, 0.f, 0.f, 0.f};
  int off0 = kh * 7;
  int offn = (kh == 3) ? 6 : 7;
  for (int off = off0 + w; off < off0 + offn; off += 4) {
    int kd = off / 9, rr = off - kd * 9, kkh = rr / 3, kw = rr - kkh * 3;
    int rowb = ((d + kd) * 18 + h + kkh) * 18 + kw + c;
    const short* arow = hpad + rowb * 256;
    const short* wrow = wt + off * 256;
#pragma unroll 2
    for (int kc = 0; kc < 8; ++kc) {
      short8 af = *(const short8*)(arow + kc * 32 + 8 * g);
#pragma unroll
      for (int n = 0; n < 4; ++n) {
        short8 bf = *(const short8*)(wrow + (16 * n + c) * 6912 + kc * 32 + 8 * g);
        acc[n] = __builtin_amdgcn_mfma_f32_16x16x32_bf16(af, bf, acc[n], 0, 0, 0);
      }
    }
  }
  if (w > 0) {
#pragma unroll
    for (int n = 0; n < 4; ++n)
#pragma unroll
      for (int i = 0; i < 4; ++i) red[w - 1][n * 4 + i][lane] = acc[n][i];
  }
  __syncthreads();
  if (w == 0) {
    float* pbuf = pbase + (size_t)kh * (S * DM / 4);  // 64*4096 each
#pragma unroll
    for (int n = 0; n < 4; ++n) {
      int o = 16 * n + c;
      float4 st;
      st.x = acc[n][0] + red[0][n * 4 + 0][lane] + red[1][n * 4 + 0][lane] + red[2][n * 4 + 0][lane];
      st.y = acc[n][1] + red[0][n * 4 + 1][lane] + red[1][n * 4 + 1][lane] + red[2][n * 4 + 1][lane];
      st.z = acc[n][2] + red[0][n * 4 + 2][lane] + red[1][n * 4 + 2][lane] + red[2][n * 4 + 2][lane];
      st.w = acc[n][3] + red[0][n * 4 + 3][lane] + red[1][n * 4 + 3][lane] + red[2][n * 4 + 3][lane];
      *(float4*)(pbuf + o * 4096 + mt * 16 + 4 * g) = st;
    }
  }
}

__global__ __launch_bounds__(256) void k_conv2fin(const float* __restrict__ pbase,
                                                  const float* __restrict__ bias,
                                                  float* __restrict__ out) {
  int idx4 = (blockIdx.x * 256 + threadIdx.x) * 4;  // 262144 total
  int o = idx4 >> 12;
  const int PS = S * DM / 4;  // 262144
  float4 a = *(const float4*)(pbase + idx4);
  float4 b = *(const float4*)(pbase + PS + idx4);
  float4 c = *(const float4*)(pbase + 2 * PS + idx4);
  float4 d = *(const float4*)(pbase + 3 * PS + idx4);
  float bv = bias[o];
  float4 r;
  r.x = a.x + b.x + c.x + d.x + bv;
  r.y = a.y + b.y + c.y + d.y + bv;
  r.z = a.z + b.z + c.z + d.z + bv;
  r.w = a.w + b.w + c.w + d.w + bv;
  *(float4*)(out + idx4) = r;
}

extern "C" void kernel_launch(void* const* d_in, const int* in_sizes, int n_in,
                              void* d_out, int out_size, void* d_ws, size_t ws_size,
                              hipStream_t stream) {
  const float* x   = (const float*)d_in[0];
  const float* c1w = (const float*)d_in[1];
  const float* c1b = (const float*)d_in[2];
  const float* lng = (const float*)d_in[3];
  const float* lnb = (const float*)d_in[4];
  const float* qw  = (const float*)d_in[5];
  const float* qbi = (const float*)d_in[6];
  const float* kw  = (const float*)d_in[7];
  const float* kbi = (const float*)d_in[8];
  const float* vw  = (const float*)d_in[9];
  const float* vbi = (const float*)d_in[10];
  const float* fw  = (const float*)d_in[11];
  const float* fbi = (const float*)d_in[12];
  const float* c2w = (const float*)d_in[13];
  const float* c2b = (const float*)d_in[14];
  float* out = (float*)d_out;
  float* ws = (float*)d_ws;

  const size_t SD = (size_t)S * DM;  // 1048576
  float* hn     = ws;                  // SD floats
  float* xt     = hn + SD;             // SD floats
  short* partsb = (short*)(xt + SD);   // 8*SD shorts (16MB)
  float* h0     = (float*)partsb;      // alias: dead before attn2 writes parts
  float* c2p    = (float*)partsb;      // alias: conv2 partials (SD floats)
  float* lpart  = (float*)(partsb + 8 * SD);  // 262144 floats (8 q-eighth slices)
  float* linv   = lpart + 262144;      // 32768
  short* hnb    = (short*)(linv + 32768);
  short* h2b    = hnb + SD;
  short* qb     = h2b + SD;
  short* kb     = qb + SD;
  short* vt     = kb + SD;
  short* xpad   = vt + SD;             // 373248
  short* hpad   = xpad + 373248;       // 1492992
  short* w1t    = hpad + 1492992;      // 442368
  short* w2t    = w1t + 442368;        // 442368
  short* wqb    = w2t + 442368;        // 4 x 65536 contiguous
  short* wkb    = wqb + 65536;
  short* wvb    = wkb + 65536;
  short* wfb    = wvb + 65536;

  k_prep<<<6667, 256, 0, stream>>>(x, c1w, c2w, qw, kw, vw, fw,
                                   xpad, w1t, w2t, wqb, hpad);

  k_conv1m<<<512, 256, 0, stream>>>(xpad, w1t, c1b, h0);
  k_layernorm<<<4096, 256, 0, stream>>>(h0, lng, lnb, hn, hnb);

  k_gemm_qkv<<<dim3(256, 3), 256, 0, stream>>>(hnb, wqb, wkb, wvb, qbi, kbi, vbi,
                                               qb, kb, vt);

  k_attn1<<<2048, 256, 0, stream>>>(qb, kb, lpart);
  k_linv<<<128, 256, 0, stream>>>(lpart, linv);
  k_scalevt<<<1024, 256, 0, stream>>>(vt, linv);
  k_attn2<<<1024, 256, 0, stream>>>(qb, kb, vt, partsb);
  k_combine_ln<<<4096, 256, 0, stream>>>(partsb, hn, lng, lnb, xt, h2b);

  k_gemm_ffn<<<256, 256, 0, stream>>>(h2b, wfb, fbi, xt, hpad);
  k_conv2m<<<1024, 256, 0, stream>>>(hpad, w2t, c2p);
  k_conv2fin<<<256, 256, 0, stream>>>(c2p, c2b, out);
}

// Round 10
// 175.562 us; speedup vs baseline: 6.3754x; 1.0148x over previous
//
#include <hip/hip_runtime.h>
#include <math.h>

#define S 4096
#define DM 256

using short8 = __attribute__((ext_vector_type(8))) short;
using short4v = __attribute__((ext_vector_type(4))) short;
using f32x4 = __attribute__((ext_vector_type(4))) float;
using f32x16 = __attribute__((ext_vector_type(16))) float;

// 1/sqrt(32) * log2(e): fold into q so scores feed v_exp_f32 (2^x) directly
static constexpr float QK_SCALE_LOG2E = 0.17677669529663687f * 1.4426950408889634f;

__device__ __forceinline__ short f2bf(float f) {
  union { float f; unsigned u; } v;
  v.f = f;
  unsigned r = (v.u + 0x7FFFu + ((v.u >> 16) & 1u)) >> 16;
  return (short)r;
}

__device__ __forceinline__ float bf2f(short s) {
  union { unsigned u; float f; } v;
  v.u = ((unsigned)(unsigned short)s) << 16;
  return v.f;
}

__device__ __forceinline__ unsigned cvt_pk_bf16(float lo, float hi) {
  unsigned r;
  asm("v_cvt_pk_bf16_f32 %0, %1, %2" : "=v"(r) : "v"(lo), "v"(hi));
  return r;
}

__device__ __forceinline__ float fexp2(float x) {
  float r;
  asm("v_exp_f32 %0, %1" : "=v"(r) : "v"(x));
  return r;
}

__device__ __forceinline__ int pad_idx(int s) {
  int d = s >> 8, h = (s >> 4) & 15, w = s & 15;
  return ((d + 1) * 18 + (h + 1)) * 18 + (w + 1);
}

// ---------- fused prep: xpad(full, pad+cast) | w1t | w2t | qkv/ffn casts | hpad halo zero ----------
__global__ __launch_bounds__(256) void k_prep(const float* __restrict__ x,
                                              const float* __restrict__ c1w,
                                              const float* __restrict__ c2w,
                                              const float* __restrict__ qw,
                                              const float* __restrict__ kw,
                                              const float* __restrict__ vw,
                                              const float* __restrict__ fw,
                                              short* __restrict__ xpad,
                                              short* __restrict__ w1t,
                                              short* __restrict__ w2t,
                                              short* __restrict__ wqkvf,
                                              short* __restrict__ hpad) {
  int bid = blockIdx.x, tid = threadIdx.x;
  if (bid < 1458) {                       // xpad: 5832*64
    int idx = bid * 256 + tid;
    int row = idx >> 6, c = idx & 63;
    int pd = row / 324, rem = row - pd * 324;
    int ph = rem / 18, pw = rem - ph * 18;
    short v = 0;
    if ((unsigned)(pd - 1) < 16u && (unsigned)(ph - 1) < 16u && (unsigned)(pw - 1) < 16u) {
      int s = (pd - 1) * 256 + (ph - 1) * 16 + (pw - 1);
      v = f2bf(x[c * 4096 + s]);
    }
    xpad[idx] = v;
  } else if (bid < 3186) {                // w1t [256][27*64]
    int idx = (bid - 1458) * 256 + tid;
    int o = idx / 1728, r = idx - o * 1728;
    int off = r >> 6, ic = r & 63;
    w1t[idx] = f2bf(c1w[(o * 64 + ic) * 27 + off]);
  } else if (bid < 4914) {                // w2t [64][27*256]
    int idx = (bid - 3186) * 256 + tid;
    int o = idx / 6912, r = idx - o * 6912;
    int off = r >> 8, ic = r & 255;
    w2t[idx] = f2bf(c2w[(o * 256 + ic) * 27 + off]);
  } else if (bid < 5938) {                // q,k,v,ffn weight casts (4 x 65536)
    int idx = (bid - 4914) * 256 + tid;
    int which = idx >> 16, r = idx & 65535;
    const float* src = (which == 0) ? qw : (which == 1) ? kw : (which == 2) ? vw : fw;
    wqkvf[idx] = f2bf(src[r]);
  } else {                                // hpad zero (full)
    int i = (bid - 5938) * 2048 + tid * 8;
    short8 z = {0, 0, 0, 0, 0, 0, 0, 0};
    *(short8*)(hpad + i) = z;
  }
}

// ---------- conv1 via MFMA: xpad[5832][64] x w1t[256][1728] -> h0[4096][256] ----------
__global__ __launch_bounds__(256) void k_conv1m(const short* __restrict__ xpad,
                                                const short* __restrict__ wt,
                                                const float* __restrict__ bias,
                                                float* __restrict__ h0) {
  int bid = blockIdx.x;  // 512
  int mt = bid >> 1, ch = bid & 1;
  int tid = threadIdx.x, w = tid >> 6, lane = tid & 63, g = lane >> 4, c = lane & 15;
  int d = mt >> 4, h = mt & 15;
  int nb = ch * 128 + w * 32;
  f32x4 acc0 = {0.f, 0.f, 0.f, 0.f}, acc1 = {0.f, 0.f, 0.f, 0.f};
  for (int off = 0; off < 27; ++off) {
    int kd = off / 9, r = off - kd * 9, kh = r / 3, kw = r - kh * 3;
    int rowb = ((d + kd) * 18 + h + kh) * 18 + kw + c;
#pragma unroll
    for (int kc = 0; kc < 2; ++kc) {
      short8 af = *(const short8*)(xpad + rowb * 64 + kc * 32 + 8 * g);
      int kidx = off * 64 + kc * 32 + 8 * g;
      short8 b0 = *(const short8*)(wt + (nb + c) * 1728 + kidx);
      short8 b1 = *(const short8*)(wt + (nb + 16 + c) * 1728 + kidx);
      acc0 = __builtin_amdgcn_mfma_f32_16x16x32_bf16(af, b0, acc0, 0, 0, 0);
      acc1 = __builtin_amdgcn_mfma_f32_16x16x32_bf16(af, b1, acc1, 0, 0, 0);
    }
  }
  int o0 = nb + c, o1 = nb + 16 + c;
  float bv0 = bias[o0], bv1 = bias[o1];
#pragma unroll
  for (int i = 0; i < 4; ++i) {
    int s = mt * 16 + 4 * g + i;
    h0[s * 256 + o0] = acc0[i] + bv0;
    h0[s * 256 + o1] = acc1[i] + bv1;
  }
}

// ---------- layernorm: fp32 + bf16 outputs ----------
__global__ __launch_bounds__(256) void k_layernorm(const float* __restrict__ in,
                                                   const float* __restrict__ g,
                                                   const float* __restrict__ b,
                                                   float* __restrict__ outf,
                                                   short* __restrict__ outb) {
  int s = blockIdx.x, tid = threadIdx.x;
  float xv = in[s * 256 + tid];
  float s1 = xv, s2 = xv * xv;
#pragma unroll
  for (int off = 32; off > 0; off >>= 1) {
    s1 += __shfl_down(s1, off);
    s2 += __shfl_down(s2, off);
  }
  __shared__ float w1[4], w2[4], mb[2];
  int wid = tid >> 6;
  if ((tid & 63) == 0) { w1[wid] = s1; w2[wid] = s2; }
  __syncthreads();
  if (tid == 0) {
    float t1 = w1[0] + w1[1] + w1[2] + w1[3];
    float t2 = w2[0] + w2[1] + w2[2] + w2[3];
    float m = t1 * (1.f / 256.f);
    float var = t2 * (1.f / 256.f) - m * m;
    mb[0] = m;
    mb[1] = rsqrtf(var + 1e-5f);
  }
  __syncthreads();
  float y = (xv - mb[0]) * mb[1] * g[tid] + b[tid];
  outf[s * 256 + tid] = y;
  outb[s * 256 + tid] = f2bf(y);
}

// ---------- fused QKV GEMM: 256 blocks x 3; 16 m-rows/block, 64 n-cols/wave ----------
__global__ __launch_bounds__(256) void k_gemm_qkv(const short* __restrict__ ab,
                                                  const short* __restrict__ wqb,
                                                  const short* __restrict__ wkb,
                                                  const short* __restrict__ wvb,
                                                  const float* __restrict__ qbi,
                                                  const float* __restrict__ kbi,
                                                  const float* __restrict__ vbi,
                                                  short* __restrict__ qb,
                                                  short* __restrict__ kb,
                                                  short* __restrict__ vt) {
  int y = blockIdx.y;
  const short* wb = (y == 0) ? wqb : ((y == 1) ? wkb : wvb);
  int tid = threadIdx.x, w = tid >> 6, lane = tid & 63, g = lane >> 4, c = lane & 15;
  int m0 = blockIdx.x * 16;
  int nb = w * 64;
  f32x4 acc[4];
#pragma unroll
  for (int n = 0; n < 4; ++n) acc[n] = {0.f, 0.f, 0.f, 0.f};
#pragma unroll 2
  for (int k0 = 0; k0 < 256; k0 += 32) {
    short8 af = *(const short8*)(ab + (m0 + c) * 256 + k0 + 8 * g);
#pragma unroll
    for (int n = 0; n < 4; ++n) {
      short8 bf = *(const short8*)(wb + (nb + 16 * n + c) * 256 + k0 + 8 * g);
      acc[n] = __builtin_amdgcn_mfma_f32_16x16x32_bf16(af, bf, acc[n], 0, 0, 0);
    }
  }
  if (y < 2) {
    const float* bi = (y == 0) ? qbi : kbi;
    float sc = (y == 0) ? QK_SCALE_LOG2E : 1.f;
    short* ob = (y == 0) ? qb : kb;
#pragma unroll
    for (int n = 0; n < 4; ++n) {
      int o = nb + 16 * n + c;
      float bv = bi[o];
      int hh = o >> 5, dj = o & 31;
#pragma unroll
      for (int i = 0; i < 4; ++i) {
        int s = m0 + 4 * g + i;
        ob[((size_t)hh * S + s) * 32 + dj] = f2bf((acc[n][i] + bv) * sc);
      }
    }
  } else {
#pragma unroll
    for (int n = 0; n < 4; ++n) {
      int o = nb + 16 * n + c;
      float bv = vbi[o];
      short4v st;
#pragma unroll
      for (int i = 0; i < 4; ++i) st[i] = f2bf(acc[n][i] + bv);
      *(short4v*)(vt + (size_t)o * S + m0 + 4 * g) = st;
    }
  }
}

// ---------- attn pass 1: 32x32 MFMA; partial lsum over a q-eighth ----------
__global__ __launch_bounds__(256) void k_attn1(const short* __restrict__ qb,
                                               const short* __restrict__ kb,
                                               float* __restrict__ lpart) {
  int b = blockIdx.x;  // 2048 = h(8) x kt(32) x qs(8)
  int qs = b & 7, kt = (b >> 3) & 31, h = b >> 8;
  int tid = threadIdx.x;
  int w = tid >> 6, lane = tid & 63;
  int lo = lane & 31, hi = lane >> 5;
  int k0 = kt * 128 + w * 32;
  const size_t hb = (size_t)h * S;
  const short* krow = kb + (hb + k0 + lo) * 32;
  short8 ak0 = *(const short8*)(krow + 8 * hi);
  short8 ak1 = *(const short8*)(krow + 16 + 8 * hi);
  f32x16 ls = {};
  const f32x16 z16 = {};
  int qend = qs * 512 + 512;
  for (int q0 = qs * 512; q0 < qend; q0 += 32) {
    short8 bq0 = *(const short8*)(qb + (hb + q0 + lo) * 32 + 8 * hi);
    short8 bq1 = *(const short8*)(qb + (hb + q0 + lo) * 32 + 16 + 8 * hi);
    __builtin_amdgcn_s_setprio(1);
    f32x16 p = __builtin_amdgcn_mfma_f32_32x32x16_bf16(ak0, bq0, z16, 0, 0, 0);
    p = __builtin_amdgcn_mfma_f32_32x32x16_bf16(ak1, bq1, p, 0, 0, 0);
    __builtin_amdgcn_s_setprio(0);
#pragma unroll
    for (int r = 0; r < 16; ++r) ls[r] += fexp2(p[r]);
  }
#pragma unroll
  for (int r = 0; r < 16; ++r) {
    float v = ls[r];
    v += __shfl_xor(v, 1);
    v += __shfl_xor(v, 2);
    v += __shfl_xor(v, 4);
    v += __shfl_xor(v, 8);
    v += __shfl_xor(v, 16);
    ls[r] = v;
  }
  if (lo == 0) {
#pragma unroll
    for (int r = 0; r < 16; ++r)
      lpart[qs * 32768 + h * 4096 + k0 + (r & 3) + 8 * (r >> 2) + 4 * hi] = ls[r];
  }
}

// vt[row][k] *= 1/l[h][k], with l computed inline from the 8 lpart slices
__global__ __launch_bounds__(256) void k_scalevt(short* __restrict__ vt,
                                                 const float* __restrict__ lpart) {
  int idx = blockIdx.x * 256 + threadIdx.x;  // 262144
  int row = idx >> 9;
  int col0 = (idx & 511) << 3;
  int h = row >> 5;
  const float* lp = lpart + h * 4096 + col0;
  float4 s0 = {0.f, 0.f, 0.f, 0.f}, s1 = {0.f, 0.f, 0.f, 0.f};
#pragma unroll
  for (int j = 0; j < 8; ++j) {
    float4 a = *(const float4*)(lp + j * 32768);
    float4 b = *(const float4*)(lp + j * 32768 + 4);
    s0.x += a.x; s0.y += a.y; s0.z += a.z; s0.w += a.w;
    s1.x += b.x; s1.y += b.y; s1.z += b.z; s1.w += b.w;
  }
  float4 l0, l1;
  l0.x = 1.f / s0.x; l0.y = 1.f / s0.y; l0.z = 1.f / s0.z; l0.w = 1.f / s0.w;
  l1.x = 1.f / s1.x; l1.y = 1.f / s1.y; l1.z = 1.f / s1.z; l1.w = 1.f / s1.w;
  short8 v = *(short8*)(vt + (size_t)row * S + col0);
  union { unsigned u[4]; short8 s8; } r;
  r.u[0] = cvt_pk_bf16(bf2f(v[0]) * l0.x, bf2f(v[1]) * l0.y);
  r.u[1] = cvt_pk_bf16(bf2f(v[2]) * l0.z, bf2f(v[3]) * l0.w);
  r.u[2] = cvt_pk_bf16(bf2f(v[4]) * l1.x, bf2f(v[5]) * l1.y);
  r.u[3] = cvt_pk_bf16(bf2f(v[6]) * l1.z, bf2f(v[7]) * l1.w);
  *(short8*)(vt + (size_t)row * S + col0) = r.s8;
}

// ---------- attn pass 2: 32x32 MFMA, swapped QK, zero LDS, k-split x8,
// dual q-tiles per wave + K-prefetch software pipeline ----------
__global__ __launch_bounds__(256, 4) void k_attn2(const short* __restrict__ qb,
                                                  const short* __restrict__ kb,
                                                  const short* __restrict__ vt,
                                                  short* __restrict__ parts) {
  int b = blockIdx.x;  // 1024 = h(8) x qt(16) x ks(8)
  int ks = b & 7, qt = (b >> 3) & 15, h = b >> 7;
  int tid = threadIdx.x;
  int w = tid >> 6, lane = tid & 63;
  int lo = lane & 31, hi = lane >> 5;
  // sigma: swap quartets [4-7]<->[8-11] and [20-23]<->[24-27]
  int sl = lo ^ ((((lo >> 2) ^ (lo >> 3)) & 1) * 12);
  int q0a = qt * 256 + w * 64;
  int q0b = q0a + 32;
  const size_t hb = (size_t)h * S;
  short8 bqa0 = *(const short8*)(qb + (hb + q0a + lo) * 32 + 8 * hi);
  short8 bqa1 = *(const short8*)(qb + (hb + q0a + lo) * 32 + 16 + 8 * hi);
  short8 bqb0 = *(const short8*)(qb + (hb + q0b + lo) * 32 + 8 * hi);
  short8 bqb1 = *(const short8*)(qb + (hb + q0b + lo) * 32 + 16 + 8 * hi);
  f32x16 accA = {}, accB = {};
  const short* krow = kb + (hb + sl) * 32;
  const short* vrow = vt + ((size_t)(h * 32) + lo) * S;
  const f32x16 z16 = {};
  int k0 = ks * 512;
  // prologue: load first K frags
  short8 ak0 = *(const short8*)(krow + (size_t)k0 * 32 + 8 * hi);
  short8 ak1 = *(const short8*)(krow + (size_t)k0 * 32 + 16 + 8 * hi);
#pragma unroll 1
  for (int it = 0; it < 16; ++it) {
    int kn = k0 + 32;
    // prefetch next K (last iter overruns 64B into the adjacent ws buffer:
    // valid memory, values unused) + current V, all issued before the chain
    short8 nak0 = *(const short8*)(krow + (size_t)kn * 32 + 8 * hi);
    short8 nak1 = *(const short8*)(krow + (size_t)kn * 32 + 16 + 8 * hi);
    short8 bv0 = *(const short8*)(vrow + k0 + 8 * hi);
    short8 bv1 = *(const short8*)(vrow + k0 + 16 + 8 * hi);
    __builtin_amdgcn_s_setprio(1);
    f32x16 pA = __builtin_amdgcn_mfma_f32_32x32x16_bf16(ak0, bqa0, z16, 0, 0, 0);
    f32x16 pB = __builtin_amdgcn_mfma_f32_32x32x16_bf16(ak0, bqb0, z16, 0, 0, 0);
    pA = __builtin_amdgcn_mfma_f32_32x32x16_bf16(ak1, bqa1, pA, 0, 0, 0);
    pB = __builtin_amdgcn_mfma_f32_32x32x16_bf16(ak1, bqb1, pB, 0, 0, 0);
    __builtin_amdgcn_s_setprio(0);
    union { unsigned u[4]; short8 s8; } fA0, fA1, fB0, fB1;
#pragma unroll
    for (int m = 0; m < 4; ++m)
      fA0.u[m] = cvt_pk_bf16(fexp2(pA[2 * m]), fexp2(pA[2 * m + 1]));
#pragma unroll
    for (int m = 0; m < 4; ++m)
      fA1.u[m] = cvt_pk_bf16(fexp2(pA[8 + 2 * m]), fexp2(pA[9 + 2 * m]));
#pragma unroll
    for (int m = 0; m < 4; ++m)
      fB0.u[m] = cvt_pk_bf16(fexp2(pB[2 * m]), fexp2(pB[2 * m + 1]));
#pragma unroll
    for (int m = 0; m < 4; ++m)
      fB1.u[m] = cvt_pk_bf16(fexp2(pB[8 + 2 * m]), fexp2(pB[9 + 2 * m]));
    __builtin_amdgcn_s_setprio(1);
    accA = __builtin_amdgcn_mfma_f32_32x32x16_bf16(fA0.s8, bv0, accA, 0, 0, 0);
    accB = __builtin_amdgcn_mfma_f32_32x32x16_bf16(fB0.s8, bv0, accB, 0, 0, 0);
    accA = __builtin_amdgcn_mfma_f32_32x32x16_bf16(fA1.s8, bv1, accA, 0, 0, 0);
    accB = __builtin_amdgcn_mfma_f32_32x32x16_bf16(fB1.s8, bv1, accB, 0, 0, 0);
    __builtin_amdgcn_s_setprio(0);
    ak0 = nak0;
    ak1 = nak1;
    k0 = kn;
  }
  short* part = parts + (size_t)ks * (S * DM);
  int col = h * 32 + lo;
#pragma unroll
  for (int r = 0; r < 16; ++r) {
    int qrel = (r & 3) + 8 * (r >> 2) + 4 * hi;
    part[(q0a + qrel) * 256 + col] = f2bf(accA[r]);
    part[(q0b + qrel) * 256 + col] = f2bf(accB[r]);
  }
}

// xt = hn + sum(8 bf16 parts); write xt + layernorm -> h2b
__global__ __launch_bounds__(256) void k_combine_ln(const short* __restrict__ parts,
                                                    const float* __restrict__ hn,
                                                    const float* __restrict__ g,
                                                    const float* __restrict__ b,
                                                    float* __restrict__ xt,
                                                    short* __restrict__ h2b) {
  int s = blockIdx.x, tid = threadIdx.x;
  int i = s * 256 + tid;
  const int SD4 = S * DM;
  float xv = hn[i];
#pragma unroll
  for (int j = 0; j < 8; ++j) xv += bf2f(parts[i + j * SD4]);
  xt[i] = xv;
  float s1 = xv, s2 = xv * xv;
#pragma unroll
  for (int off = 32; off > 0; off >>= 1) {
    s1 += __shfl_down(s1, off);
    s2 += __shfl_down(s2, off);
  }
  __shared__ float w1[4], w2[4], mb[2];
  int wid = tid >> 6;
  if ((tid & 63) == 0) { w1[wid] = s1; w2[wid] = s2; }
  __syncthreads();
  if (tid == 0) {
    float t1 = w1[0] + w1[1] + w1[2] + w1[3];
    float t2 = w2[0] + w2[1] + w2[2] + w2[3];
    float m = t1 * (1.f / 256.f);
    float var = t2 * (1.f / 256.f) - m * m;
    mb[0] = m;
    mb[1] = rsqrtf(var + 1e-5f);
  }
  __syncthreads();
  h2b[i] = f2bf((xv - mb[0]) * mb[1] * g[tid] + b[tid]);
}

// ---------- FFN GEMM: 256 blocks; relu+bias, +xt, -> hpad (padded bf16) ----------
__global__ __launch_bounds__(256) void k_gemm_ffn(const short* __restrict__ ab,
                                                  const short* __restrict__ wb,
                                                  const float* __restrict__ bi,
                                                  const float* __restrict__ xt,
                                                  short* __restrict__ hpad) {
  int tid = threadIdx.x, w = tid >> 6, lane = tid & 63, g = lane >> 4, c = lane & 15;
  int m0 = blockIdx.x * 16;
  int nb = w * 64;
  f32x4 acc[4];
#pragma unroll
  for (int n = 0; n < 4; ++n) acc[n] = {0.f, 0.f, 0.f, 0.f};
#pragma unroll 2
  for (int k0 = 0; k0 < 256; k0 += 32) {
    short8 af = *(const short8*)(ab + (m0 + c) * 256 + k0 + 8 * g);
#pragma unroll
    for (int n = 0; n < 4; ++n) {
      short8 bf = *(const short8*)(wb + (nb + 16 * n + c) * 256 + k0 + 8 * g);
      acc[n] = __builtin_amdgcn_mfma_f32_16x16x32_bf16(af, bf, acc[n], 0, 0, 0);
    }
  }
  int pr[4];
#pragma unroll
  for (int i = 0; i < 4; ++i) pr[i] = pad_idx(m0 + 4 * g + i) * 256;
#pragma unroll
  for (int n = 0; n < 4; ++n) {
    int o = nb + 16 * n + c;
    float bv = bi[o];
#pragma unroll
    for (int i = 0; i < 4; ++i) {
      int s = m0 + 4 * g + i;
      float v = acc[n][i] + bv;
      v = v > 0.f ? v : 0.f;
      hpad[pr[i] + o] = f2bf(v + xt[s * 256 + o]);
    }
  }
}

// ---------- conv2 via MFMA, K-split x4 across blocks ----------
__global__ __launch_bounds__(256) void k_conv2m(const short* __restrict__ hpad,
                                                const short* __restrict__ wt,
                                                float* __restrict__ pbase) {
  __shared__ float red[3][16][65];
  int bid = blockIdx.x;  // 1024 = mt(256) x kh(4)
  int mt = bid >> 2, kh = bid & 3;
  int tid = threadIdx.x, w = tid >> 6, lane = tid & 63, g = lane >> 4, c = lane & 15;
  int d = mt >> 4, h = mt & 15;
  f32x4 acc[4];
#pragma unroll
  for (int n = 0; n < 4; ++n) acc[n] = {0.f, 0.f, 0.f, 0.f};
  int off0 = kh * 7;
  int offn = (kh == 3) ? 6 : 7;
  for (int off = off0 + w; off < off0 + offn; off += 4) {
    int kd = off / 9, rr = off - kd * 9, kkh = rr / 3, kw = rr - kkh * 3;
    int rowb = ((d + kd) * 18 + h + kkh) * 18 + kw + c;
    const short* arow = hpad + rowb * 256;
    const short* wrow = wt + off * 256;
#pragma unroll 2
    for (int kc = 0; kc < 8; ++kc) {
      short8 af = *(const short8*)(arow + kc * 32 + 8 * g);
#pragma unroll
      for (int n = 0; n < 4; ++n) {
        short8 bf = *(const short8*)(wrow + (16 * n + c) * 6912 + kc * 32 + 8 * g);
        acc[n] = __builtin_amdgcn_mfma_f32_16x16x32_bf16(af, bf, acc[n], 0, 0, 0);
      }
    }
  }
  if (w > 0) {
#pragma unroll
    for (int n = 0; n < 4; ++n)
#pragma unroll
      for (int i = 0; i < 4; ++i) red[w - 1][n * 4 + i][lane] = acc[n][i];
  }
  __syncthreads();
  if (w == 0) {
    float* pbuf = pbase + (size_t)kh * (S * DM / 4);  // 64*4096 each
#pragma unroll
    for (int n = 0; n < 4; ++n) {
      int o = 16 * n + c;
      float4 st;
      st.x = acc[n][0] + red[0][n * 4 + 0][lane] + red[1][n * 4 + 0][lane] + red[2][n * 4 + 0][lane];
      st.y = acc[n][1] + red[0][n * 4 + 1][lane] + red[1][n * 4 + 1][lane] + red[2][n * 4 + 1][lane];
      st.z = acc[n][2] + red[0][n * 4 + 2][lane] + red[1][n * 4 + 2][lane] + red[2][n * 4 + 2][lane];
      st.w = acc[n][3] + red[0][n * 4 + 3][lane] + red[1][n * 4 + 3][lane] + red[2][n * 4 + 3][lane];
      *(float4*)(pbuf + o * 4096 + mt * 16 + 4 * g) = st;
    }
  }
}

__global__ __launch_bounds__(256) void k_conv2fin(const float* __restrict__ pbase,
                                                  const float* __restrict__ bias,
                                                  float* __restrict__ out) {
  int idx4 = (blockIdx.x * 256 + threadIdx.x) * 4;  // 262144 total
  int o = idx4 >> 12;
  const int PS = S * DM / 4;  // 262144
  float4 a = *(const float4*)(pbase + idx4);
  float4 b = *(const float4*)(pbase + PS + idx4);
  float4 c = *(const float4*)(pbase + 2 * PS + idx4);
  float4 d = *(const float4*)(pbase + 3 * PS + idx4);
  float bv = bias[o];
  float4 r;
  r.x = a.x + b.x + c.x + d.x + bv;
  r.y = a.y + b.y + c.y + d.y + bv;
  r.z = a.z + b.z + c.z + d.z + bv;
  r.w = a.w + b.w + c.w + d.w + bv;
  *(float4*)(out + idx4) = r;
}

extern "C" void kernel_launch(void* const* d_in, const int* in_sizes, int n_in,
                              void* d_out, int out_size, void* d_ws, size_t ws_size,
                              hipStream_t stream) {
  const float* x   = (const float*)d_in[0];
  const float* c1w = (const float*)d_in[1];
  const float* c1b = (const float*)d_in[2];
  const float* lng = (const float*)d_in[3];
  const float* lnb = (const float*)d_in[4];
  const float* qw  = (const float*)d_in[5];
  const float* qbi = (const float*)d_in[6];
  const float* kw  = (const float*)d_in[7];
  const float* kbi = (const float*)d_in[8];
  const float* vw  = (const float*)d_in[9];
  const float* vbi = (const float*)d_in[10];
  const float* fw  = (const float*)d_in[11];
  const float* fbi = (const float*)d_in[12];
  const float* c2w = (const float*)d_in[13];
  const float* c2b = (const float*)d_in[14];
  float* out = (float*)d_out;
  float* ws = (float*)d_ws;

  const size_t SD = (size_t)S * DM;  // 1048576
  float* hn     = ws;                  // SD floats
  float* xt     = hn + SD;             // SD floats
  short* partsb = (short*)(xt + SD);   // 8*SD shorts (16MB)
  float* h0     = (float*)partsb;      // alias: dead before attn2 writes parts
  float* c2p    = (float*)partsb;      // alias: conv2 partials (SD floats)
  float* lpart  = (float*)(partsb + 8 * SD);  // 262144 floats (8 q-eighth slices)
  float* linv   = lpart + 262144;      // 32768 (unused, layout keep)
  short* hnb    = (short*)(linv + 32768);
  short* h2b    = hnb + SD;
  short* qb     = h2b + SD;
  short* kb     = qb + SD;
  short* vt     = kb + SD;
  short* xpad   = vt + SD;             // 373248
  short* hpad   = xpad + 373248;       // 1492992
  short* w1t    = hpad + 1492992;      // 442368
  short* w2t    = w1t + 442368;        // 442368
  short* wqb    = w2t + 442368;        // 4 x 65536 contiguous
  short* wkb    = wqb + 65536;
  short* wvb    = wkb + 65536;
  short* wfb    = wvb + 65536;

  k_prep<<<6667, 256, 0, stream>>>(x, c1w, c2w, qw, kw, vw, fw,
                                   xpad, w1t, w2t, wqb, hpad);

  k_conv1m<<<512, 256, 0, stream>>>(xpad, w1t, c1b, h0);
  k_layernorm<<<4096, 256, 0, stream>>>(h0, lng, lnb, hn, hnb);

  k_gemm_qkv<<<dim3(256, 3), 256, 0, stream>>>(hnb, wqb, wkb, wvb, qbi, kbi, vbi,
                                               qb, kb, vt);

  k_attn1<<<2048, 256, 0, stream>>>(qb, kb, lpart);
  k_scalevt<<<1024, 256, 0, stream>>>(vt, lpart);
  k_attn2<<<1024, 256, 0, stream>>>(qb, kb, vt, partsb);
  k_combine_ln<<<4096, 256, 0, stream>>>(partsb, hn, lng, lnb, xt, h2b);

  k_gemm_ffn<<<256, 256, 0, stream>>>(h2b, wfb, fbi, xt, hpad);
  k_conv2m<<<1024, 256, 0, stream>>>(hpad, w2t, c2p);
  k_conv2fin<<<256, 256, 0, stream>>>(c2p, c2b, out);
}

// Round 11
// 150.991 us; speedup vs baseline: 7.4129x; 1.1627x over previous
//
#include <hip/hip_runtime.h>
#include <math.h>

#define S 4096
#define DM 256

using short8 = __attribute__((ext_vector_type(8))) short;
using short4v = __attribute__((ext_vector_type(4))) short;
using f32x4 = __attribute__((ext_vector_type(4))) float;
using f32x16 = __attribute__((ext_vector_type(16))) float;

// 1/sqrt(32) * log2(e): fold into q so scores feed v_exp_f32 (2^x) directly
static constexpr float QK_SCALE_LOG2E = 0.17677669529663687f * 1.4426950408889634f;

__device__ __forceinline__ short f2bf(float f) {
  union { float f; unsigned u; } v;
  v.f = f;
  unsigned r = (v.u + 0x7FFFu + ((v.u >> 16) & 1u)) >> 16;
  return (short)r;
}

__device__ __forceinline__ float bf2f(short s) {
  union { unsigned u; float f; } v;
  v.u = ((unsigned)(unsigned short)s) << 16;
  return v.f;
}

__device__ __forceinline__ unsigned cvt_pk_bf16(float lo, float hi) {
  unsigned r;
  asm("v_cvt_pk_bf16_f32 %0, %1, %2" : "=v"(r) : "v"(lo), "v"(hi));
  return r;
}

__device__ __forceinline__ float fexp2(float x) {
  float r;
  asm("v_exp_f32 %0, %1" : "=v"(r) : "v"(x));
  return r;
}

__device__ __forceinline__ int pad_idx(int s) {
  int d = s >> 8, h = (s >> 4) & 15, w = s & 15;
  return ((d + 1) * 18 + (h + 1)) * 18 + (w + 1);
}

// ---------- fused prep: xpad(full, pad+cast) | w1t | w2t | qkv/ffn casts | hpad halo zero ----------
__global__ __launch_bounds__(256) void k_prep(const float* __restrict__ x,
                                              const float* __restrict__ c1w,
                                              const float* __restrict__ c2w,
                                              const float* __restrict__ qw,
                                              const float* __restrict__ kw,
                                              const float* __restrict__ vw,
                                              const float* __restrict__ fw,
                                              short* __restrict__ xpad,
                                              short* __restrict__ w1t,
                                              short* __restrict__ w2t,
                                              short* __restrict__ wqkvf,
                                              short* __restrict__ hpad) {
  int bid = blockIdx.x, tid = threadIdx.x;
  if (bid < 1458) {                       // xpad: 5832*64
    int idx = bid * 256 + tid;
    int row = idx >> 6, c = idx & 63;
    int pd = row / 324, rem = row - pd * 324;
    int ph = rem / 18, pw = rem - ph * 18;
    short v = 0;
    if ((unsigned)(pd - 1) < 16u && (unsigned)(ph - 1) < 16u && (unsigned)(pw - 1) < 16u) {
      int s = (pd - 1) * 256 + (ph - 1) * 16 + (pw - 1);
      v = f2bf(x[c * 4096 + s]);
    }
    xpad[idx] = v;
  } else if (bid < 3186) {                // w1t [256][27*64]
    int idx = (bid - 1458) * 256 + tid;
    int o = idx / 1728, r = idx - o * 1728;
    int off = r >> 6, ic = r & 63;
    w1t[idx] = f2bf(c1w[(o * 64 + ic) * 27 + off]);
  } else if (bid < 4914) {                // w2t [64][27*256]
    int idx = (bid - 3186) * 256 + tid;
    int o = idx / 6912, r = idx - o * 6912;
    int off = r >> 8, ic = r & 255;
    w2t[idx] = f2bf(c2w[(o * 256 + ic) * 27 + off]);
  } else if (bid < 5938) {                // q,k,v,ffn weight casts (4 x 65536)
    int idx = (bid - 4914) * 256 + tid;
    int which = idx >> 16, r = idx & 65535;
    const float* src = (which == 0) ? qw : (which == 1) ? kw : (which == 2) ? vw : fw;
    wqkvf[idx] = f2bf(src[r]);
  } else {                                // hpad zero (full)
    int i = (bid - 5938) * 2048 + tid * 8;
    short8 z = {0, 0, 0, 0, 0, 0, 0, 0};
    *(short8*)(hpad + i) = z;
  }
}

// ---------- conv1 via MFMA, 32 m-rows/block (2 tiles share every weight frag) ----------
__global__ __launch_bounds__(256) void k_conv1m(const short* __restrict__ xpad,
                                                const short* __restrict__ wt,
                                                const float* __restrict__ bias,
                                                float* __restrict__ h0) {
  int bid = blockIdx.x;  // 256 = mt2(128) x ch(2)
  int mt2 = bid >> 1, ch = bid & 1;
  int tid = threadIdx.x, w = tid >> 6, lane = tid & 63, g = lane >> 4, c = lane & 15;
  int d = mt2 >> 3, h = (mt2 & 7) * 2;
  int nb = ch * 128 + w * 32;
  f32x4 accA0 = {}, accA1 = {}, accB0 = {}, accB1 = {};
  for (int off = 0; off < 27; ++off) {
    int kd = off / 9, r = off - kd * 9, kh = r / 3, kw = r - kh * 3;
    int rowb = ((d + kd) * 18 + h + kh) * 18 + kw + c;
#pragma unroll
    for (int kc = 0; kc < 2; ++kc) {
      short8 afA = *(const short8*)(xpad + rowb * 64 + kc * 32 + 8 * g);
      short8 afB = *(const short8*)(xpad + (rowb + 18) * 64 + kc * 32 + 8 * g);
      int kidx = off * 64 + kc * 32 + 8 * g;
      short8 b0 = *(const short8*)(wt + (nb + c) * 1728 + kidx);
      short8 b1 = *(const short8*)(wt + (nb + 16 + c) * 1728 + kidx);
      accA0 = __builtin_amdgcn_mfma_f32_16x16x32_bf16(afA, b0, accA0, 0, 0, 0);
      accA1 = __builtin_amdgcn_mfma_f32_16x16x32_bf16(afA, b1, accA1, 0, 0, 0);
      accB0 = __builtin_amdgcn_mfma_f32_16x16x32_bf16(afB, b0, accB0, 0, 0, 0);
      accB1 = __builtin_amdgcn_mfma_f32_16x16x32_bf16(afB, b1, accB1, 0, 0, 0);
    }
  }
  int o0 = nb + c, o1 = nb + 16 + c;
  float bv0 = bias[o0], bv1 = bias[o1];
  int sA = mt2 * 32 + 4 * g;
#pragma unroll
  for (int i = 0; i < 4; ++i) {
    h0[(sA + i) * 256 + o0] = accA0[i] + bv0;
    h0[(sA + i) * 256 + o1] = accA1[i] + bv1;
    h0[(sA + 16 + i) * 256 + o0] = accB0[i] + bv0;
    h0[(sA + 16 + i) * 256 + o1] = accB1[i] + bv1;
  }
}

// ---------- layernorm: fp32 + bf16 outputs ----------
__global__ __launch_bounds__(256) void k_layernorm(const float* __restrict__ in,
                                                   const float* __restrict__ g,
                                                   const float* __restrict__ b,
                                                   float* __restrict__ outf,
                                                   short* __restrict__ outb) {
  int s = blockIdx.x, tid = threadIdx.x;
  float xv = in[s * 256 + tid];
  float s1 = xv, s2 = xv * xv;
#pragma unroll
  for (int off = 32; off > 0; off >>= 1) {
    s1 += __shfl_down(s1, off);
    s2 += __shfl_down(s2, off);
  }
  __shared__ float w1[4], w2[4], mb[2];
  int wid = tid >> 6;
  if ((tid & 63) == 0) { w1[wid] = s1; w2[wid] = s2; }
  __syncthreads();
  if (tid == 0) {
    float t1 = w1[0] + w1[1] + w1[2] + w1[3];
    float t2 = w2[0] + w2[1] + w2[2] + w2[3];
    float m = t1 * (1.f / 256.f);
    float var = t2 * (1.f / 256.f) - m * m;
    mb[0] = m;
    mb[1] = rsqrtf(var + 1e-5f);
  }
  __syncthreads();
  float y = (xv - mb[0]) * mb[1] * g[tid] + b[tid];
  outf[s * 256 + tid] = y;
  outb[s * 256 + tid] = f2bf(y);
}

// ---------- fused QKV GEMM: 256 blocks x 3; 16 m-rows/block, 64 n-cols/wave ----------
__global__ __launch_bounds__(256) void k_gemm_qkv(const short* __restrict__ ab,
                                                  const short* __restrict__ wqb,
                                                  const short* __restrict__ wkb,
                                                  const short* __restrict__ wvb,
                                                  const float* __restrict__ qbi,
                                                  const float* __restrict__ kbi,
                                                  const float* __restrict__ vbi,
                                                  short* __restrict__ qb,
                                                  short* __restrict__ kb,
                                                  short* __restrict__ vt) {
  int y = blockIdx.y;
  const short* wb = (y == 0) ? wqb : ((y == 1) ? wkb : wvb);
  int tid = threadIdx.x, w = tid >> 6, lane = tid & 63, g = lane >> 4, c = lane & 15;
  int m0 = blockIdx.x * 16;
  int nb = w * 64;
  f32x4 acc[4];
#pragma unroll
  for (int n = 0; n < 4; ++n) acc[n] = {0.f, 0.f, 0.f, 0.f};
#pragma unroll 2
  for (int k0 = 0; k0 < 256; k0 += 32) {
    short8 af = *(const short8*)(ab + (m0 + c) * 256 + k0 + 8 * g);
#pragma unroll
    for (int n = 0; n < 4; ++n) {
      short8 bf = *(const short8*)(wb + (nb + 16 * n + c) * 256 + k0 + 8 * g);
      acc[n] = __builtin_amdgcn_mfma_f32_16x16x32_bf16(af, bf, acc[n], 0, 0, 0);
    }
  }
  if (y < 2) {
    const float* bi = (y == 0) ? qbi : kbi;
    float sc = (y == 0) ? QK_SCALE_LOG2E : 1.f;
    short* ob = (y == 0) ? qb : kb;
#pragma unroll
    for (int n = 0; n < 4; ++n) {
      int o = nb + 16 * n + c;
      float bv = bi[o];
      int hh = o >> 5, dj = o & 31;
#pragma unroll
      for (int i = 0; i < 4; ++i) {
        int s = m0 + 4 * g + i;
        ob[((size_t)hh * S + s) * 32 + dj] = f2bf((acc[n][i] + bv) * sc);
      }
    }
  } else {
#pragma unroll
    for (int n = 0; n < 4; ++n) {
      int o = nb + 16 * n + c;
      float bv = vbi[o];
      short4v st;
#pragma unroll
      for (int i = 0; i < 4; ++i) st[i] = f2bf(acc[n][i] + bv);
      *(short4v*)(vt + (size_t)o * S + m0 + 4 * g) = st;
    }
  }
}

// ---------- attn pass 1: 32x32 MFMA; partial lsum over a q-eighth.
// XCD swizzle: h = bid & 7 so each head's blocks share one XCD's L2. ----------
__global__ __launch_bounds__(256) void k_attn1(const short* __restrict__ qb,
                                               const short* __restrict__ kb,
                                               float* __restrict__ lpart) {
  int bid = blockIdx.x;  // 2048
  int h = bid & 7;
  int rest = bid >> 3;       // 256 = kt(32) x qs(8)
  int kt = rest >> 3, qs = rest & 7;
  int tid = threadIdx.x;
  int w = tid >> 6, lane = tid & 63;
  int lo = lane & 31, hi = lane >> 5;
  int k0 = kt * 128 + w * 32;
  const size_t hb = (size_t)h * S;
  const short* krow = kb + (hb + k0 + lo) * 32;
  short8 ak0 = *(const short8*)(krow + 8 * hi);
  short8 ak1 = *(const short8*)(krow + 16 + 8 * hi);
  f32x16 ls = {};
  const f32x16 z16 = {};
  int qend = qs * 512 + 512;
  for (int q0 = qs * 512; q0 < qend; q0 += 32) {
    short8 bq0 = *(const short8*)(qb + (hb + q0 + lo) * 32 + 8 * hi);
    short8 bq1 = *(const short8*)(qb + (hb + q0 + lo) * 32 + 16 + 8 * hi);
    __builtin_amdgcn_s_setprio(1);
    f32x16 p = __builtin_amdgcn_mfma_f32_32x32x16_bf16(ak0, bq0, z16, 0, 0, 0);
    p = __builtin_amdgcn_mfma_f32_32x32x16_bf16(ak1, bq1, p, 0, 0, 0);
    __builtin_amdgcn_s_setprio(0);
#pragma unroll
    for (int r = 0; r < 16; ++r) ls[r] += fexp2(p[r]);
  }
#pragma unroll
  for (int r = 0; r < 16; ++r) {
    float v = ls[r];
    v += __shfl_xor(v, 1);
    v += __shfl_xor(v, 2);
    v += __shfl_xor(v, 4);
    v += __shfl_xor(v, 8);
    v += __shfl_xor(v, 16);
    ls[r] = v;
  }
  if (lo == 0) {
#pragma unroll
    for (int r = 0; r < 16; ++r)
      lpart[qs * 32768 + h * 4096 + k0 + (r & 3) + 8 * (r >> 2) + 4 * hi] = ls[r];
  }
}

// vt[row][k] *= 1/l[h][k], with l computed inline from the 8 lpart slices
__global__ __launch_bounds__(256) void k_scalevt(short* __restrict__ vt,
                                                 const float* __restrict__ lpart) {
  int idx = blockIdx.x * 256 + threadIdx.x;  // 262144
  int row = idx >> 9;
  int col0 = (idx & 511) << 3;
  int h = row >> 5;
  const float* lp = lpart + h * 4096 + col0;
  float4 s0 = {0.f, 0.f, 0.f, 0.f}, s1 = {0.f, 0.f, 0.f, 0.f};
#pragma unroll
  for (int j = 0; j < 8; ++j) {
    float4 a = *(const float4*)(lp + j * 32768);
    float4 b = *(const float4*)(lp + j * 32768 + 4);
    s0.x += a.x; s0.y += a.y; s0.z += a.z; s0.w += a.w;
    s1.x += b.x; s1.y += b.y; s1.z += b.z; s1.w += b.w;
  }
  float4 l0, l1;
  l0.x = 1.f / s0.x; l0.y = 1.f / s0.y; l0.z = 1.f / s0.z; l0.w = 1.f / s0.w;
  l1.x = 1.f / s1.x; l1.y = 1.f / s1.y; l1.z = 1.f / s1.z; l1.w = 1.f / s1.w;
  short8 v = *(short8*)(vt + (size_t)row * S + col0);
  union { unsigned u[4]; short8 s8; } r;
  r.u[0] = cvt_pk_bf16(bf2f(v[0]) * l0.x, bf2f(v[1]) * l0.y);
  r.u[1] = cvt_pk_bf16(bf2f(v[2]) * l0.z, bf2f(v[3]) * l0.w);
  r.u[2] = cvt_pk_bf16(bf2f(v[4]) * l1.x, bf2f(v[5]) * l1.y);
  r.u[3] = cvt_pk_bf16(bf2f(v[6]) * l1.z, bf2f(v[7]) * l1.w);
  *(short8*)(vt + (size_t)row * S + col0) = r.s8;
}

// ---------- attn pass 2: 32x32 MFMA, swapped QK, zero LDS, k-split x8,
// dual q-tiles + K-prefetch + XCD swizzle (head-per-XCD L2 locality) ----------
__global__ __launch_bounds__(256, 4) void k_attn2(const short* __restrict__ qb,
                                                  const short* __restrict__ kb,
                                                  const short* __restrict__ vt,
                                                  short* __restrict__ parts) {
  int bid = blockIdx.x;  // 1024
  int h = bid & 7;
  int rest = bid >> 3;       // 128 = qt(16) x ks(8)
  int qt = rest >> 3, ks = rest & 7;
  int tid = threadIdx.x;
  int w = tid >> 6, lane = tid & 63;
  int lo = lane & 31, hi = lane >> 5;
  // sigma: swap quartets [4-7]<->[8-11] and [20-23]<->[24-27]
  int sl = lo ^ ((((lo >> 2) ^ (lo >> 3)) & 1) * 12);
  int q0a = qt * 256 + w * 64;
  int q0b = q0a + 32;
  const size_t hb = (size_t)h * S;
  short8 bqa0 = *(const short8*)(qb + (hb + q0a + lo) * 32 + 8 * hi);
  short8 bqa1 = *(const short8*)(qb + (hb + q0a + lo) * 32 + 16 + 8 * hi);
  short8 bqb0 = *(const short8*)(qb + (hb + q0b + lo) * 32 + 8 * hi);
  short8 bqb1 = *(const short8*)(qb + (hb + q0b + lo) * 32 + 16 + 8 * hi);
  f32x16 accA = {}, accB = {};
  const short* krow = kb + (hb + sl) * 32;
  const short* vrow = vt + ((size_t)(h * 32) + lo) * S;
  const f32x16 z16 = {};
  int k0 = ks * 512;
  // prologue: load first K frags
  short8 ak0 = *(const short8*)(krow + (size_t)k0 * 32 + 8 * hi);
  short8 ak1 = *(const short8*)(krow + (size_t)k0 * 32 + 16 + 8 * hi);
#pragma unroll 1
  for (int it = 0; it < 16; ++it) {
    int kn = k0 + 32;
    // prefetch next K (last iter overruns 64B into the adjacent ws buffer:
    // valid memory, values unused) + current V, all issued before the chain
    short8 nak0 = *(const short8*)(krow + (size_t)kn * 32 + 8 * hi);
    short8 nak1 = *(const short8*)(krow + (size_t)kn * 32 + 16 + 8 * hi);
    short8 bv0 = *(const short8*)(vrow + k0 + 8 * hi);
    short8 bv1 = *(const short8*)(vrow + k0 + 16 + 8 * hi);
    __builtin_amdgcn_s_setprio(1);
    f32x16 pA = __builtin_amdgcn_mfma_f32_32x32x16_bf16(ak0, bqa0, z16, 0, 0, 0);
    f32x16 pB = __builtin_amdgcn_mfma_f32_32x32x16_bf16(ak0, bqb0, z16, 0, 0, 0);
    pA = __builtin_amdgcn_mfma_f32_32x32x16_bf16(ak1, bqa1, pA, 0, 0, 0);
    pB = __builtin_amdgcn_mfma_f32_32x32x16_bf16(ak1, bqb1, pB, 0, 0, 0);
    __builtin_amdgcn_s_setprio(0);
    union { unsigned u[4]; short8 s8; } fA0, fA1, fB0, fB1;
#pragma unroll
    for (int m = 0; m < 4; ++m)
      fA0.u[m] = cvt_pk_bf16(fexp2(pA[2 * m]), fexp2(pA[2 * m + 1]));
#pragma unroll
    for (int m = 0; m < 4; ++m)
      fA1.u[m] = cvt_pk_bf16(fexp2(pA[8 + 2 * m]), fexp2(pA[9 + 2 * m]));
#pragma unroll
    for (int m = 0; m < 4; ++m)
      fB0.u[m] = cvt_pk_bf16(fexp2(pB[2 * m]), fexp2(pB[2 * m + 1]));
#pragma unroll
    for (int m = 0; m < 4; ++m)
      fB1.u[m] = cvt_pk_bf16(fexp2(pB[8 + 2 * m]), fexp2(pB[9 + 2 * m]));
    __builtin_amdgcn_s_setprio(1);
    accA = __builtin_amdgcn_mfma_f32_32x32x16_bf16(fA0.s8, bv0, accA, 0, 0, 0);
    accB = __builtin_amdgcn_mfma_f32_32x32x16_bf16(fB0.s8, bv0, accB, 0, 0, 0);
    accA = __builtin_amdgcn_mfma_f32_32x32x16_bf16(fA1.s8, bv1, accA, 0, 0, 0);
    accB = __builtin_amdgcn_mfma_f32_32x32x16_bf16(fB1.s8, bv1, accB, 0, 0, 0);
    __builtin_amdgcn_s_setprio(0);
    ak0 = nak0;
    ak1 = nak1;
    k0 = kn;
  }
  short* part = parts + (size_t)ks * (S * DM);
  int col = h * 32 + lo;
#pragma unroll
  for (int r = 0; r < 16; ++r) {
    int qrel = (r & 3) + 8 * (r >> 2) + 4 * hi;
    part[(q0a + qrel) * 256 + col] = f2bf(accA[r]);
    part[(q0b + qrel) * 256 + col] = f2bf(accB[r]);
  }
}

// xt = hn + sum(8 bf16 parts); write xt + layernorm -> h2b
__global__ __launch_bounds__(256) void k_combine_ln(const short* __restrict__ parts,
                                                    const float* __restrict__ hn,
                                                    const float* __restrict__ g,
                                                    const float* __restrict__ b,
                                                    float* __restrict__ xt,
                                                    short* __restrict__ h2b) {
  int s = blockIdx.x, tid = threadIdx.x;
  int i = s * 256 + tid;
  const int SD4 = S * DM;
  float xv = hn[i];
#pragma unroll
  for (int j = 0; j < 8; ++j) xv += bf2f(parts[i + j * SD4]);
  xt[i] = xv;
  float s1 = xv, s2 = xv * xv;
#pragma unroll
  for (int off = 32; off > 0; off >>= 1) {
    s1 += __shfl_down(s1, off);
    s2 += __shfl_down(s2, off);
  }
  __shared__ float w1[4], w2[4], mb[2];
  int wid = tid >> 6;
  if ((tid & 63) == 0) { w1[wid] = s1; w2[wid] = s2; }
  __syncthreads();
  if (tid == 0) {
    float t1 = w1[0] + w1[1] + w1[2] + w1[3];
    float t2 = w2[0] + w2[1] + w2[2] + w2[3];
    float m = t1 * (1.f / 256.f);
    float var = t2 * (1.f / 256.f) - m * m;
    mb[0] = m;
    mb[1] = rsqrtf(var + 1e-5f);
  }
  __syncthreads();
  h2b[i] = f2bf((xv - mb[0]) * mb[1] * g[tid] + b[tid]);
}

// ---------- FFN GEMM: 256 blocks; relu+bias, +xt, -> hpad (padded bf16) ----------
__global__ __launch_bounds__(256) void k_gemm_ffn(const short* __restrict__ ab,
                                                  const short* __restrict__ wb,
                                                  const float* __restrict__ bi,
                                                  const float* __restrict__ xt,
                                                  short* __restrict__ hpad) {
  int tid = threadIdx.x, w = tid >> 6, lane = tid & 63, g = lane >> 4, c = lane & 15;
  int m0 = blockIdx.x * 16;
  int nb = w * 64;
  f32x4 acc[4];
#pragma unroll
  for (int n = 0; n < 4; ++n) acc[n] = {0.f, 0.f, 0.f, 0.f};
#pragma unroll 2
  for (int k0 = 0; k0 < 256; k0 += 32) {
    short8 af = *(const short8*)(ab + (m0 + c) * 256 + k0 + 8 * g);
#pragma unroll
    for (int n = 0; n < 4; ++n) {
      short8 bf = *(const short8*)(wb + (nb + 16 * n + c) * 256 + k0 + 8 * g);
      acc[n] = __builtin_amdgcn_mfma_f32_16x16x32_bf16(af, bf, acc[n], 0, 0, 0);
    }
  }
  int pr[4];
#pragma unroll
  for (int i = 0; i < 4; ++i) pr[i] = pad_idx(m0 + 4 * g + i) * 256;
#pragma unroll
  for (int n = 0; n < 4; ++n) {
    int o = nb + 16 * n + c;
    float bv = bi[o];
#pragma unroll
    for (int i = 0; i < 4; ++i) {
      int s = m0 + 4 * g + i;
      float v = acc[n][i] + bv;
      v = v > 0.f ? v : 0.f;
      hpad[pr[i] + o] = f2bf(v + xt[s * 256 + o]);
    }
  }
}

// ---------- conv2 via MFMA, K-split x4, 32 m-rows/block (B-frag reuse x2) ----------
__global__ __launch_bounds__(256) void k_conv2m(const short* __restrict__ hpad,
                                                const short* __restrict__ wt,
                                                float* __restrict__ pbase) {
  __shared__ float red[3][32][65];
  int bid = blockIdx.x;  // 512 = mt2(128) x kh(4)
  int mt2 = bid >> 2, kh = bid & 3;
  int tid = threadIdx.x, w = tid >> 6, lane = tid & 63, g = lane >> 4, c = lane & 15;
  int d = mt2 >> 3, h = (mt2 & 7) * 2;
  f32x4 accA[4], accB[4];
#pragma unroll
  for (int n = 0; n < 4; ++n) { accA[n] = {0.f, 0.f, 0.f, 0.f}; accB[n] = {0.f, 0.f, 0.f, 0.f}; }
  int off0 = kh * 7;
  int offn = (kh == 3) ? 6 : 7;
  for (int off = off0 + w; off < off0 + offn; off += 4) {
    int kd = off / 9, rr = off - kd * 9, kkh = rr / 3, kw = rr - kkh * 3;
    int rowb = ((d + kd) * 18 + h + kkh) * 18 + kw + c;
    const short* arowA = hpad + rowb * 256;
    const short* arowB = hpad + (rowb + 18) * 256;
    const short* wrow = wt + off * 256;
#pragma unroll 2
    for (int kc = 0; kc < 8; ++kc) {
      short8 afA = *(const short8*)(arowA + kc * 32 + 8 * g);
      short8 afB = *(const short8*)(arowB + kc * 32 + 8 * g);
#pragma unroll
      for (int n = 0; n < 4; ++n) {
        short8 bf = *(const short8*)(wrow + (16 * n + c) * 6912 + kc * 32 + 8 * g);
        accA[n] = __builtin_amdgcn_mfma_f32_16x16x32_bf16(afA, bf, accA[n], 0, 0, 0);
        accB[n] = __builtin_amdgcn_mfma_f32_16x16x32_bf16(afB, bf, accB[n], 0, 0, 0);
      }
    }
  }
  if (w > 0) {
#pragma unroll
    for (int n = 0; n < 4; ++n)
#pragma unroll
      for (int i = 0; i < 4; ++i) {
        red[w - 1][n * 4 + i][lane] = accA[n][i];
        red[w - 1][16 + n * 4 + i][lane] = accB[n][i];
      }
  }
  __syncthreads();
  if (w == 0) {
    float* pbuf = pbase + (size_t)kh * (S * DM / 4);  // 64*4096 each
#pragma unroll
    for (int n = 0; n < 4; ++n) {
      int o = 16 * n + c;
      float4 stA, stB;
#pragma unroll
      for (int i = 0; i < 4; ++i) {
        float a = accA[n][i] + red[0][n * 4 + i][lane] + red[1][n * 4 + i][lane] + red[2][n * 4 + i][lane];
        float bb = accB[n][i] + red[0][16 + n * 4 + i][lane] + red[1][16 + n * 4 + i][lane] + red[2][16 + n * 4 + i][lane];
        ((float*)&stA)[i] = a;
        ((float*)&stB)[i] = bb;
      }
      *(float4*)(pbuf + o * 4096 + mt2 * 32 + 4 * g) = stA;
      *(float4*)(pbuf + o * 4096 + mt2 * 32 + 16 + 4 * g) = stB;
    }
  }
}

__global__ __launch_bounds__(256) void k_conv2fin(const float* __restrict__ pbase,
                                                  const float* __restrict__ bias,
                                                  float* __restrict__ out) {
  int idx4 = (blockIdx.x * 256 + threadIdx.x) * 4;  // 262144 total
  int o = idx4 >> 12;
  const int PS = S * DM / 4;  // 262144
  float4 a = *(const float4*)(pbase + idx4);
  float4 b = *(const float4*)(pbase + PS + idx4);
  float4 c = *(const float4*)(pbase + 2 * PS + idx4);
  float4 d = *(const float4*)(pbase + 3 * PS + idx4);
  float bv = bias[o];
  float4 r;
  r.x = a.x + b.x + c.x + d.x + bv;
  r.y = a.y + b.y + c.y + d.y + bv;
  r.z = a.z + b.z + c.z + d.z + bv;
  r.w = a.w + b.w + c.w + d.w + bv;
  *(float4*)(out + idx4) = r;
}

extern "C" void kernel_launch(void* const* d_in, const int* in_sizes, int n_in,
                              void* d_out, int out_size, void* d_ws, size_t ws_size,
                              hipStream_t stream) {
  const float* x   = (const float*)d_in[0];
  const float* c1w = (const float*)d_in[1];
  const float* c1b = (const float*)d_in[2];
  const float* lng = (const float*)d_in[3];
  const float* lnb = (const float*)d_in[4];
  const float* qw  = (const float*)d_in[5];
  const float* qbi = (const float*)d_in[6];
  const float* kw  = (const float*)d_in[7];
  const float* kbi = (const float*)d_in[8];
  const float* vw  = (const float*)d_in[9];
  const float* vbi = (const float*)d_in[10];
  const float* fw  = (const float*)d_in[11];
  const float* fbi = (const float*)d_in[12];
  const float* c2w = (const float*)d_in[13];
  const float* c2b = (const float*)d_in[14];
  float* out = (float*)d_out;
  float* ws = (float*)d_ws;

  const size_t SD = (size_t)S * DM;  // 1048576
  float* hn     = ws;                  // SD floats
  float* xt     = hn + SD;             // SD floats
  short* partsb = (short*)(xt + SD);   // 8*SD shorts (16MB)
  float* h0     = (float*)partsb;      // alias: dead before attn2 writes parts
  float* c2p    = (float*)partsb;      // alias: conv2 partials (SD floats)
  float* lpart  = (float*)(partsb + 8 * SD);  // 262144 floats (8 q-eighth slices)
  float* linv   = lpart + 262144;      // 32768 (unused, layout keep)
  short* hnb    = (short*)(linv + 32768);
  short* h2b    = hnb + SD;
  short* qb     = h2b + SD;
  short* kb     = qb + SD;
  short* vt     = kb + SD;
  short* xpad   = vt + SD;             // 373248
  short* hpad   = xpad + 373248;       // 1492992
  short* w1t    = hpad + 1492992;      // 442368
  short* w2t    = w1t + 442368;        // 442368
  short* wqb    = w2t + 442368;        // 4 x 65536 contiguous
  short* wkb    = wqb + 65536;
  short* wvb    = wkb + 65536;
  short* wfb    = wvb + 65536;

  k_prep<<<6667, 256, 0, stream>>>(x, c1w, c2w, qw, kw, vw, fw,
                                   xpad, w1t, w2t, wqb, hpad);

  k_conv1m<<<256, 256, 0, stream>>>(xpad, w1t, c1b, h0);
  k_layernorm<<<4096, 256, 0, stream>>>(h0, lng, lnb, hn, hnb);

  k_gemm_qkv<<<dim3(256, 3), 256, 0, stream>>>(hnb, wqb, wkb, wvb, qbi, kbi, vbi,
                                               qb, kb, vt);

  k_attn1<<<2048, 256, 0, stream>>>(qb, kb, lpart);
  k_scalevt<<<1024, 256, 0, stream>>>(vt, lpart);
  k_attn2<<<1024, 256, 0, stream>>>(qb, kb, vt, partsb);
  k_combine_ln<<<4096, 256, 0, stream>>>(partsb, hn, lng, lnb, xt, h2b);

  k_gemm_ffn<<<256, 256, 0, stream>>>(h2b, wfb, fbi, xt, hpad);
  k_conv2m<<<512, 256, 0, stream>>>(hpad, w2t, c2p);
  k_conv2fin<<<256, 256, 0, stream>>>(c2p, c2b, out);
}